// Round 1
// baseline (2620.017 us; speedup 1.0000x reference)
//
#include <hip/hip_runtime.h>
#include <hip/hip_bf16.h>
#include <math.h>

#define B_ 4
#define N_ 2048
#define D_ 1024
#define H_ 16
#define HD_ 64
#define NC_ 32

// ---------- GEMM f32: C[M,Nn] = A[M,K] @ Bw[K,Nn]; mode 1 applies silu ----------
__global__ __launch_bounds__(256) void gemm_f32(const float* __restrict__ A,
    const float* __restrict__ Bw, float* __restrict__ C,
    int M, int K, int Nn, int mode) {
  __shared__ float As[16][68];  // [k][m], padded
  __shared__ float Bs[16][68];  // [k][n], padded
  const int tid = threadIdx.x;
  const int m0 = blockIdx.y * 64, n0 = blockIdx.x * 64;
  const int tm = (tid & 15) * 4, tn = (tid >> 4) * 4;
  const int la_m = tid >> 2, la_k = (tid & 3) * 4;
  const int lb_k = tid >> 4, lb_n = (tid & 15) * 4;
  float acc[4][4];
#pragma unroll
  for (int i = 0; i < 4; ++i)
#pragma unroll
    for (int j = 0; j < 4; ++j) acc[i][j] = 0.f;

  for (int kt = 0; kt < K; kt += 16) {
    float4 a4 = *(const float4*)&A[(size_t)(m0 + la_m) * K + kt + la_k];
    float4 b4 = *(const float4*)&Bw[(size_t)(kt + lb_k) * Nn + n0 + lb_n];
    As[la_k + 0][la_m] = a4.x;
    As[la_k + 1][la_m] = a4.y;
    As[la_k + 2][la_m] = a4.z;
    As[la_k + 3][la_m] = a4.w;
    *(float4*)&Bs[lb_k][lb_n] = b4;
    __syncthreads();
#pragma unroll
    for (int kk = 0; kk < 16; ++kk) {
      float4 av = *(const float4*)&As[kk][tm];
      float4 bv = *(const float4*)&Bs[kk][tn];
      float aa[4] = {av.x, av.y, av.z, av.w};
      float bb[4] = {bv.x, bv.y, bv.z, bv.w};
#pragma unroll
      for (int i = 0; i < 4; ++i)
#pragma unroll
        for (int j = 0; j < 4; ++j) acc[i][j] += aa[i] * bb[j];
    }
    __syncthreads();
  }
#pragma unroll
  for (int i = 0; i < 4; ++i) {
    float r[4];
#pragma unroll
    for (int j = 0; j < 4; ++j) {
      float vv = acc[i][j];
      if (mode == 1) vv = vv / (1.f + expf(-vv));  // silu
      r[j] = vv;
    }
    float4 outv;
    outv.x = r[0]; outv.y = r[1]; outv.z = r[2]; outv.w = r[3];
    *(float4*)&C[(size_t)(m0 + tm + i) * Nn + n0 + tn] = outv;
  }
}

// ---------- sequential cumlogsumexp scan; emits log_f (B,H,N,64) and LRPE'd k (B,H,N,128)
__global__ void scan_kernel(const float* __restrict__ k_raw,
                            float* __restrict__ log_f,
                            float* __restrict__ k_rot) {
  const int idx = blockIdx.x * 64 + threadIdx.x;  // 0..4095 = (b,h,hd)
  const int b = idx >> 10, h = (idx >> 6) & 15, hd = idx & 63;
  const float freq = expf((float)hd * -0.28782313662425575f);  // ln(1e4)/32
  const size_t in_off = (size_t)b * N_ * D_ + (size_t)h * HD_ + hd;
  const size_t lf_off = ((size_t)(b * H_ + h)) * N_ * 64 + hd;
  const size_t kr_off = ((size_t)(b * H_ + h)) * N_ * 128 + hd;
  float z = 0.f;
  float nxt = k_raw[in_off];
  for (int n = 0; n < N_; ++n) {
    float kr = nxt;
    if (n + 1 < N_) nxt = k_raw[in_off + (size_t)(n + 1) * D_];  // prefetch
    float mx = fmaxf(z, kr), mn = fminf(z, kr);
    float zn = mx + log1pf(expf(mn - mx));  // logaddexp
    log_f[lf_off + (size_t)n * 64] = z - zn;
    float kt = expf(kr - zn);
    float s, c;
    sincosf((float)n * freq, &s, &c);
    k_rot[kr_off + (size_t)n * 128] = kt * c;
    k_rot[kr_off + (size_t)n * 128 + 64] = kt * s;
    z = zn;
  }
}

// ---------- LRPE for q: (B,N,H,64) -> (B,H,N,128) ----------
__global__ void lrpe_q_kernel(const float* __restrict__ q_silu,
                              float* __restrict__ q_rot) {
  const int idx = blockIdx.x * 256 + threadIdx.x;  // over B*N*H*HD = 2^23
  const int hd = idx & 63;
  const int h = (idx >> 6) & 15;
  const int n = (idx >> 10) & (N_ - 1);
  const int b = idx >> 21;
  const float freq = expf((float)hd * -0.28782313662425575f);
  float s, c;
  sincosf((float)n * freq, &s, &c);
  const float vq = q_silu[idx];
  const size_t o = (((size_t)(b * H_ + h)) * N_ + n) * 128 + hd;
  q_rot[o] = vq * c;
  q_rot[o + 64] = vq * s;
}

// ---------- chunked GLA. grid = (b,h,dv-quarter) = 256 blocks ----------
__global__ __launch_bounds__(256) void gla_kernel(
    const float* __restrict__ q_rot, const float* __restrict__ k_rot,
    const float* __restrict__ log_f, const float* __restrict__ v,
    float* __restrict__ o) {
  __shared__ float Gs[64][68];   // cumsum G [c][j']; reused as masked A [c][s]
  __shared__ float qgT[64][64];  // [j][c]  (j within current half)
  __shared__ float kgT[64][68];  // [j][s]  padded (S-update reads kgT[jl][s])
  __shared__ float S_s[128][16];
  __shared__ float v_s[64][16];
  __shared__ float Glast[64];

  const int bid = blockIdx.x;
  const int b = bid >> 6, h = (bid >> 2) & 15, dq = bid & 3;
  const int dvo = dq * 16;
  const int tid = threadIdx.x;

  const size_t qk_base = ((size_t)(b * H_ + h)) * N_ * 128;
  const size_t lf_base = ((size_t)(b * H_ + h)) * N_ * 64;
  const size_t vo_base = (size_t)b * N_ * D_ + (size_t)h * HD_ + dvo;

  const int tm = (tid & 15) * 4, tn = (tid >> 4) * 4;  // A tile owner
  const int oc = tid >> 2, od = (tid & 3) * 4;         // o row / 4 cols; also S row/cols
  const int br = tid >> 2, bj0 = (tid & 3) * 16;       // build row / col group

  for (int i = tid; i < 128 * 16; i += 256) S_s[i >> 4][i & 15] = 0.f;
  __syncthreads();

  for (int ch = 0; ch < NC_; ++ch) {
    const int t0 = ch * 64;
    // step 1: wave0 does cumsum of log_f -> Gs, Glast; wave1 loads v tile
    if (tid < 64) {
      const int j = tid;
      float run = 0.f;
      for (int c = 0; c < 64; ++c) {
        run += log_f[lf_base + (size_t)(t0 + c) * 64 + j];
        Gs[c][j] = run;
      }
      Glast[j] = run;
    } else if (tid < 128) {
      const int r = tid - 64;
      const float* vp = &v[vo_base + (size_t)(t0 + r) * D_];
#pragma unroll
      for (int u = 0; u < 16; u += 4)
        *(float4*)&v_s[r][u] = *(const float4*)(vp + u);
    }
    __syncthreads();

    float accA[4][4];
#pragma unroll
    for (int i = 0; i < 4; ++i)
#pragma unroll
      for (int j = 0; j < 4; ++j) accA[i][j] = 0.f;
    float acco[4] = {0.f, 0.f, 0.f, 0.f};

#pragma unroll
    for (int ph = 0; ph < 2; ++ph) {
      const int jbase = ph * 64;
      // build qgT = (q*exp(G))^T, kgT = (k*exp(-G))^T for this j-half
      {
        const float* qp = &q_rot[qk_base + (size_t)(t0 + br) * 128 + jbase + bj0];
        const float* kp = &k_rot[qk_base + (size_t)(t0 + br) * 128 + jbase + bj0];
#pragma unroll
        for (int u = 0; u < 16; u += 4) {
          float4 q4 = *(const float4*)(qp + u);
          float4 k4 = *(const float4*)(kp + u);
          float4 g4 = *(const float4*)&Gs[br][bj0 + u];
          float qa[4] = {q4.x, q4.y, q4.z, q4.w};
          float ka[4] = {k4.x, k4.y, k4.z, k4.w};
          float ga[4] = {g4.x, g4.y, g4.z, g4.w};
#pragma unroll
          for (int e = 0; e < 4; ++e) {
            qgT[bj0 + u + e][br] = qa[e] * expf(ga[e]);
            kgT[bj0 + u + e][br] = ka[e] * expf(-ga[e]);
          }
        }
      }
      __syncthreads();
      // A += qg_half @ kg_half^T
      for (int j = 0; j < 64; ++j) {
        float4 qa4 = *(const float4*)&qgT[j][tm];
        float4 kb4 = *(const float4*)&kgT[j][tn];
        float qa[4] = {qa4.x, qa4.y, qa4.z, qa4.w};
        float kb[4] = {kb4.x, kb4.y, kb4.z, kb4.w};
#pragma unroll
        for (int i = 0; i < 4; ++i)
#pragma unroll
          for (int jj = 0; jj < 4; ++jj) accA[i][jj] += qa[i] * kb[jj];
      }
      // o_inter += qg_half @ S_old(half rows)
      for (int j = 0; j < 64; ++j) {
        float qv = qgT[j][oc];
        float4 s4 = *(const float4*)&S_s[jbase + j][od];
        acco[0] += qv * s4.x; acco[1] += qv * s4.y;
        acco[2] += qv * s4.z; acco[3] += qv * s4.w;
      }
      __syncthreads();
      // S(half rows) = exp(Glast) * (S + kg^T @ v)
      {
        float a0 = 0.f, a1 = 0.f, a2 = 0.f, a3 = 0.f;
        for (int s = 0; s < 64; ++s) {
          float kv = kgT[oc][s];
          float4 v4 = *(const float4*)&v_s[s][od];
          a0 += kv * v4.x; a1 += kv * v4.y; a2 += kv * v4.z; a3 += kv * v4.w;
        }
        float el = expf(Glast[oc]);
        float4 S4 = *(float4*)&S_s[jbase + oc][od];
        S4.x = (S4.x + a0) * el;
        S4.y = (S4.y + a1) * el;
        S4.z = (S4.z + a2) * el;
        S4.w = (S4.w + a3) * el;
        *(float4*)&S_s[jbase + oc][od] = S4;
      }
      __syncthreads();
    }
    // masked A into Gs buffer (cumsum no longer needed)
#pragma unroll
    for (int i = 0; i < 4; ++i)
#pragma unroll
      for (int jj = 0; jj < 4; ++jj) {
        const int c = tm + i, s = tn + jj;
        Gs[c][s] = (s <= c) ? accA[i][jj] : 0.f;
      }
    __syncthreads();
    // o_intra = A @ v ; write o
    for (int s = 0; s < 64; ++s) {
      float av = Gs[oc][s];
      float4 v4 = *(const float4*)&v_s[s][od];
      acco[0] += av * v4.x; acco[1] += av * v4.y;
      acco[2] += av * v4.z; acco[3] += av * v4.w;
    }
    float4 res;
    res.x = acco[0]; res.y = acco[1]; res.z = acco[2]; res.w = acco[3];
    *(float4*)&o[vo_base + (size_t)(t0 + oc) * D_ + od] = res;
    __syncthreads();
  }
}

// ---------- fused gate (sigmoid(x@Wg1@Wg2)) * o, then RMSNorm * norm_w, in place
__global__ __launch_bounds__(256) void gate_norm_kernel(
    const float* __restrict__ x, const float* __restrict__ Wg1,
    const float* __restrict__ Wg2, const float* __restrict__ nw,
    float* __restrict__ o) {
  const int row = blockIdx.x, tid = threadIdx.x;
  const int lane = tid & 63, wv = tid >> 6;
  __shared__ float redp[4][16];
  __shared__ float tg[16];
  __shared__ float rs[4];

  float4 xv = *(const float4*)&x[(size_t)row * D_ + tid * 4];
  float xa[4] = {xv.x, xv.y, xv.z, xv.w};
  float acc[16];
#pragma unroll
  for (int hh = 0; hh < 16; ++hh) acc[hh] = 0.f;
#pragma unroll
  for (int u = 0; u < 4; ++u) {
    const float* wr = &Wg1[(size_t)(tid * 4 + u) * 16];
    float wf[16];
    *(float4*)&wf[0]  = *(const float4*)(wr);
    *(float4*)&wf[4]  = *(const float4*)(wr + 4);
    *(float4*)&wf[8]  = *(const float4*)(wr + 8);
    *(float4*)&wf[12] = *(const float4*)(wr + 12);
#pragma unroll
    for (int hh = 0; hh < 16; ++hh) acc[hh] += xa[u] * wf[hh];
  }
#pragma unroll
  for (int hh = 0; hh < 16; ++hh) {
#pragma unroll
    for (int off = 32; off > 0; off >>= 1) acc[hh] += __shfl_xor(acc[hh], off);
  }
  if (lane == 0) {
#pragma unroll
    for (int hh = 0; hh < 16; ++hh) redp[wv][hh] = acc[hh];
  }
  __syncthreads();
  if (tid < 16) tg[tid] = redp[0][tid] + redp[1][tid] + redp[2][tid] + redp[3][tid];
  __syncthreads();

  float4 o4 = *(const float4*)&o[(size_t)row * D_ + tid * 4];
  float oa[4] = {o4.x, o4.y, o4.z, o4.w};
  float og[4];
  float ssq = 0.f;
#pragma unroll
  for (int u = 0; u < 4; ++u) {
    const int d = tid * 4 + u;
    float sg = 0.f;
#pragma unroll
    for (int hh = 0; hh < 16; ++hh) sg += tg[hh] * Wg2[hh * 1024 + d];
    float gate = 1.f / (1.f + expf(-sg));
    og[u] = oa[u] * gate;
    ssq += og[u] * og[u];
  }
#pragma unroll
  for (int off = 32; off > 0; off >>= 1) ssq += __shfl_xor(ssq, off);
  if (lane == 0) rs[wv] = ssq;
  __syncthreads();
  const float tot = rs[0] + rs[1] + rs[2] + rs[3];
  const float rinv = rsqrtf(tot * (1.f / 1024.f) + 1e-6f);
  float4 outv;
  float* op = (float*)&outv;
#pragma unroll
  for (int u = 0; u < 4; ++u) {
    const int d = tid * 4 + u;
    op[u] = og[u] * rinv * nw[d];
  }
  *(float4*)&o[(size_t)row * D_ + tid * 4] = outv;
}

extern "C" void kernel_launch(void* const* d_in, const int* in_sizes, int n_in,
                              void* d_out, int out_size, void* d_ws, size_t ws_size,
                              hipStream_t stream) {
  const float* x   = (const float*)d_in[0];
  const float* Wq  = (const float*)d_in[1];
  const float* Wk  = (const float*)d_in[2];
  const float* Wv  = (const float*)d_in[3];
  const float* Wo  = (const float*)d_in[4];
  const float* Wg1 = (const float*)d_in[5];
  const float* Wg2 = (const float*)d_in[6];
  const float* nw  = (const float*)d_in[7];
  float* out = (float*)d_out;
  float* ws  = (float*)d_ws;

  // workspace layout (floats); P = B*N*D = 8,388,608 -> total 8P floats = 268 MB
  const size_t P = (size_t)B_ * N_ * D_;
  float* k_raw = ws;            // (B,N,D)
  float* v_buf = ws + P;        // (B,N,H,64) == (B,N,D)
  float* log_f = ws + 2 * P;    // (B,H,N,64)
  float* q_rot = ws + 3 * P;    // (B,H,N,128)  [2P]
  float* k_rot = ws + 5 * P;    // (B,H,N,128)  [2P]
  float* qs_o  = ws + 7 * P;    // q_silu (B,N,D), later reused as GLA output o

  const int M = B_ * N_;
  dim3 ggrid(D_ / 64, M / 64);

  gemm_f32<<<ggrid, 256, 0, stream>>>(x, Wq, qs_o, M, D_, D_, 1);   // q = silu(x@Wq)
  gemm_f32<<<ggrid, 256, 0, stream>>>(x, Wk, k_raw, M, D_, D_, 0);  // k_raw
  gemm_f32<<<ggrid, 256, 0, stream>>>(x, Wv, v_buf, M, D_, D_, 0);  // v
  scan_kernel<<<64, 64, 0, stream>>>(k_raw, log_f, k_rot);
  lrpe_q_kernel<<<(int)(P / 256), 256, 0, stream>>>(qs_o, q_rot);
  gla_kernel<<<256, 256, 0, stream>>>(q_rot, k_rot, log_f, v_buf, qs_o);
  gate_norm_kernel<<<M, 256, 0, stream>>>(x, Wg1, Wg2, nw, qs_o);
  gemm_f32<<<ggrid, 256, 0, stream>>>(qs_o, Wo, out, M, D_, D_, 0); // final proj
}

// Round 2
// 1679.647 us; speedup vs baseline: 1.5599x; 1.5599x over previous
//
#include <hip/hip_runtime.h>
#include <hip/hip_bf16.h>
#include <math.h>

#define B_ 4
#define N_ 2048
#define D_ 1024
#define H_ 16
#define HD_ 64
#define NC_ 32

// ---------- GEMM f32: C[M,Nn] = A[M,K] @ Bw[K,Nn]; mode 1 applies silu ----------
__global__ __launch_bounds__(256) void gemm_f32(const float* __restrict__ A,
    const float* __restrict__ Bw, float* __restrict__ C,
    int M, int K, int Nn, int mode) {
  __shared__ float As[16][68];  // [k][m], padded
  __shared__ float Bs[16][68];  // [k][n], padded
  const int tid = threadIdx.x;
  const int m0 = blockIdx.y * 64, n0 = blockIdx.x * 64;
  const int tm = (tid & 15) * 4, tn = (tid >> 4) * 4;
  const int la_m = tid >> 2, la_k = (tid & 3) * 4;
  const int lb_k = tid >> 4, lb_n = (tid & 15) * 4;
  float acc[4][4];
#pragma unroll
  for (int i = 0; i < 4; ++i)
#pragma unroll
    for (int j = 0; j < 4; ++j) acc[i][j] = 0.f;

  for (int kt = 0; kt < K; kt += 16) {
    float4 a4 = *(const float4*)&A[(size_t)(m0 + la_m) * K + kt + la_k];
    float4 b4 = *(const float4*)&Bw[(size_t)(kt + lb_k) * Nn + n0 + lb_n];
    As[la_k + 0][la_m] = a4.x;
    As[la_k + 1][la_m] = a4.y;
    As[la_k + 2][la_m] = a4.z;
    As[la_k + 3][la_m] = a4.w;
    *(float4*)&Bs[lb_k][lb_n] = b4;
    __syncthreads();
#pragma unroll
    for (int kk = 0; kk < 16; ++kk) {
      float4 av = *(const float4*)&As[kk][tm];
      float4 bv = *(const float4*)&Bs[kk][tn];
      float aa[4] = {av.x, av.y, av.z, av.w};
      float bb[4] = {bv.x, bv.y, bv.z, bv.w};
#pragma unroll
      for (int i = 0; i < 4; ++i)
#pragma unroll
        for (int j = 0; j < 4; ++j) acc[i][j] += aa[i] * bb[j];
    }
    __syncthreads();
  }
#pragma unroll
  for (int i = 0; i < 4; ++i) {
    float r[4];
#pragma unroll
    for (int j = 0; j < 4; ++j) {
      float vv = acc[i][j];
      if (mode == 1) vv = vv / (1.f + expf(-vv));  // silu
      r[j] = vv;
    }
    float4 outv;
    outv.x = r[0]; outv.y = r[1]; outv.z = r[2]; outv.w = r[3];
    *(float4*)&C[(size_t)(m0 + tm + i) * Nn + n0 + tn] = outv;
  }
}

// ---------- 3-pass parallel cumlogsumexp scan (logaddexp is associative) ----------
// Pass A: per-(channel, chunk) local LSE totals.  131072 threads.
__global__ __launch_bounds__(256) void scan_pass_a(const float* __restrict__ k_raw,
                                                   float* __restrict__ T) {
  const int g = blockIdx.x * 256 + threadIdx.x;  // (bh, c, hd)
  const int hd = g & 63;
  const int c = (g >> 6) & 31;
  const int bh = g >> 11;  // 0..63
  const int b = bh >> 4, h = bh & 15;
  const size_t base = (size_t)b * N_ * D_ + (size_t)(c * 64) * D_ + h * HD_ + hd;
  float nxt = k_raw[base];
  float l = 0.f;
  for (int j = 0; j < 64; ++j) {
    float kr = nxt;
    if (j + 1 < 64) nxt = k_raw[base + (size_t)(j + 1) * D_];
    if (j == 0) {
      l = kr;
    } else {
      float mx = fmaxf(l, kr), mn = fminf(l, kr);
      l = mx + log1pf(expf(mn - mx));
    }
  }
  T[(size_t)(bh * 64 + hd) * 32 + c] = l;
}

// Pass B: per-channel scan of the 32 chunk totals, seeded with the f[0]=0 element.
__global__ void scan_pass_b(const float* __restrict__ T, float* __restrict__ Pf) {
  const int ch = blockIdx.x * 256 + threadIdx.x;  // 0..4095
  const float* t = &T[(size_t)ch * 32];
  float* p = &Pf[(size_t)ch * 32];
  float run = 0.f;  // z at chunk boundary; starts at LSE(0)=0
  for (int c = 0; c < 32; ++c) {
    p[c] = run;
    float tv = t[c];
    float mx = fmaxf(run, tv), mn = fminf(run, tv);
    run = mx + log1pf(expf(mn - mx));
  }
}

// Pass C: recompute local scan, combine with prefix, emit log_f + LRPE'd k.
__global__ __launch_bounds__(256) void scan_pass_c(const float* __restrict__ k_raw,
    const float* __restrict__ Pf, float* __restrict__ log_f, float* __restrict__ k_rot) {
  const int g = blockIdx.x * 256 + threadIdx.x;
  const int hd = g & 63;
  const int c = (g >> 6) & 31;
  const int bh = g >> 11;
  const int b = bh >> 4, h = bh & 15;
  const float freq = expf((float)hd * -0.28782313662425575f);  // 1e4^(-2*hd/64)
  const size_t base = (size_t)b * N_ * D_ + (size_t)(c * 64) * D_ + h * HD_ + hd;
  const size_t lf_off = (size_t)bh * N_ * 64 + (size_t)(c * 64) * 64 + hd;
  const size_t kr_off = (size_t)bh * N_ * 128 + (size_t)(c * 64) * 128 + hd;
  const float P = Pf[(size_t)(bh * 64 + hd) * 32 + c];
  float l = 0.f;
  float zprev = P;  // z at n = c*64 (global prefix)
  float nxt = k_raw[base];
  for (int j = 0; j < 64; ++j) {
    float kr = nxt;
    if (j + 1 < 64) nxt = k_raw[base + (size_t)(j + 1) * D_];
    if (j == 0) {
      l = kr;
    } else {
      float mx = fmaxf(l, kr), mn = fminf(l, kr);
      l = mx + log1pf(expf(mn - mx));
    }
    float mx2 = fmaxf(P, l), mn2 = fminf(P, l);
    float z = mx2 + log1pf(expf(mn2 - mx2));
    log_f[lf_off + (size_t)j * 64] = zprev - z;
    float kt = expf(kr - z);
    const int n = c * 64 + j;
    float s, cs;
    sincosf((float)n * freq, &s, &cs);
    k_rot[kr_off + (size_t)j * 128] = kt * cs;
    k_rot[kr_off + (size_t)j * 128 + 64] = kt * s;
    zprev = z;
  }
}

// ---------- LRPE for q: (B,N,H,64) -> (B,H,N,128) ----------
__global__ void lrpe_q_kernel(const float* __restrict__ q_silu,
                              float* __restrict__ q_rot) {
  const int idx = blockIdx.x * 256 + threadIdx.x;  // over B*N*H*HD = 2^23
  const int hd = idx & 63;
  const int h = (idx >> 6) & 15;
  const int n = (idx >> 10) & (N_ - 1);
  const int b = idx >> 21;
  const float freq = expf((float)hd * -0.28782313662425575f);
  float s, c;
  sincosf((float)n * freq, &s, &c);
  const float vq = q_silu[idx];
  const size_t o = (((size_t)(b * H_ + h)) * N_ + n) * 128 + hd;
  q_rot[o] = vq * c;
  q_rot[o + 64] = vq * s;
}

// ---------- chunked GLA. grid = (b,h,dv-quarter) = 256 blocks ----------
__global__ __launch_bounds__(256) void gla_kernel(
    const float* __restrict__ q_rot, const float* __restrict__ k_rot,
    const float* __restrict__ log_f, const float* __restrict__ v,
    float* __restrict__ o) {
  __shared__ float Gs[64][68];   // cumsum G [c][j']; reused as masked A [c][s]
  __shared__ float qgT[64][64];  // [j][c]  (j within current half)
  __shared__ float kgT[64][68];  // [j][s]  padded (S-update reads kgT[jl][s])
  __shared__ float S_s[128][16];
  __shared__ float v_s[64][16];
  __shared__ float Glast[64];

  const int bid = blockIdx.x;
  const int b = bid >> 6, h = (bid >> 2) & 15, dq = bid & 3;
  const int dvo = dq * 16;
  const int tid = threadIdx.x;

  const size_t qk_base = ((size_t)(b * H_ + h)) * N_ * 128;
  const size_t lf_base = ((size_t)(b * H_ + h)) * N_ * 64;
  const size_t vo_base = (size_t)b * N_ * D_ + (size_t)h * HD_ + dvo;

  const int tm = (tid & 15) * 4, tn = (tid >> 4) * 4;  // A tile owner
  const int oc = tid >> 2, od = (tid & 3) * 4;         // o row / 4 cols; also S row/cols
  const int br = tid >> 2, bj0 = (tid & 3) * 16;       // build row / col group

  for (int i = tid; i < 128 * 16; i += 256) S_s[i >> 4][i & 15] = 0.f;
  __syncthreads();

  for (int ch = 0; ch < NC_; ++ch) {
    const int t0 = ch * 64;
    // step 1: wave0 does cumsum of log_f -> Gs, Glast; wave1 loads v tile
    if (tid < 64) {
      const int j = tid;
      float run = 0.f;
      for (int c = 0; c < 64; ++c) {
        run += log_f[lf_base + (size_t)(t0 + c) * 64 + j];
        Gs[c][j] = run;
      }
      Glast[j] = run;
    } else if (tid < 128) {
      const int r = tid - 64;
      const float* vp = &v[vo_base + (size_t)(t0 + r) * D_];
#pragma unroll
      for (int u = 0; u < 16; u += 4)
        *(float4*)&v_s[r][u] = *(const float4*)(vp + u);
    }
    __syncthreads();

    float accA[4][4];
#pragma unroll
    for (int i = 0; i < 4; ++i)
#pragma unroll
      for (int j = 0; j < 4; ++j) accA[i][j] = 0.f;
    float acco[4] = {0.f, 0.f, 0.f, 0.f};

#pragma unroll
    for (int ph = 0; ph < 2; ++ph) {
      const int jbase = ph * 64;
      // build qgT = (q*exp(G))^T, kgT = (k*exp(-G))^T for this j-half
      {
        const float* qp = &q_rot[qk_base + (size_t)(t0 + br) * 128 + jbase + bj0];
        const float* kp = &k_rot[qk_base + (size_t)(t0 + br) * 128 + jbase + bj0];
#pragma unroll
        for (int u = 0; u < 16; u += 4) {
          float4 q4 = *(const float4*)(qp + u);
          float4 k4 = *(const float4*)(kp + u);
          float4 g4 = *(const float4*)&Gs[br][bj0 + u];
          float qa[4] = {q4.x, q4.y, q4.z, q4.w};
          float ka[4] = {k4.x, k4.y, k4.z, k4.w};
          float ga[4] = {g4.x, g4.y, g4.z, g4.w};
#pragma unroll
          for (int e = 0; e < 4; ++e) {
            qgT[bj0 + u + e][br] = qa[e] * expf(ga[e]);
            kgT[bj0 + u + e][br] = ka[e] * expf(-ga[e]);
          }
        }
      }
      __syncthreads();
      // A += qg_half @ kg_half^T
      for (int j = 0; j < 64; ++j) {
        float4 qa4 = *(const float4*)&qgT[j][tm];
        float4 kb4 = *(const float4*)&kgT[j][tn];
        float qa[4] = {qa4.x, qa4.y, qa4.z, qa4.w};
        float kb[4] = {kb4.x, kb4.y, kb4.z, kb4.w};
#pragma unroll
        for (int i = 0; i < 4; ++i)
#pragma unroll
          for (int jj = 0; jj < 4; ++jj) accA[i][jj] += qa[i] * kb[jj];
      }
      // o_inter += qg_half @ S_old(half rows)
      for (int j = 0; j < 64; ++j) {
        float qv = qgT[j][oc];
        float4 s4 = *(const float4*)&S_s[jbase + j][od];
        acco[0] += qv * s4.x; acco[1] += qv * s4.y;
        acco[2] += qv * s4.z; acco[3] += qv * s4.w;
      }
      __syncthreads();
      // S(half rows) = exp(Glast) * (S + kg^T @ v)
      {
        float a0 = 0.f, a1 = 0.f, a2 = 0.f, a3 = 0.f;
        for (int s = 0; s < 64; ++s) {
          float kv = kgT[oc][s];
          float4 v4 = *(const float4*)&v_s[s][od];
          a0 += kv * v4.x; a1 += kv * v4.y; a2 += kv * v4.z; a3 += kv * v4.w;
        }
        float el = expf(Glast[oc]);
        float4 S4 = *(float4*)&S_s[jbase + oc][od];
        S4.x = (S4.x + a0) * el;
        S4.y = (S4.y + a1) * el;
        S4.z = (S4.z + a2) * el;
        S4.w = (S4.w + a3) * el;
        *(float4*)&S_s[jbase + oc][od] = S4;
      }
      __syncthreads();
    }
    // masked A into Gs buffer (cumsum no longer needed)
#pragma unroll
    for (int i = 0; i < 4; ++i)
#pragma unroll
      for (int jj = 0; jj < 4; ++jj) {
        const int c = tm + i, s = tn + jj;
        Gs[c][s] = (s <= c) ? accA[i][jj] : 0.f;
      }
    __syncthreads();
    // o_intra = A @ v ; write o
    for (int s = 0; s < 64; ++s) {
      float av = Gs[oc][s];
      float4 v4 = *(const float4*)&v_s[s][od];
      acco[0] += av * v4.x; acco[1] += av * v4.y;
      acco[2] += av * v4.z; acco[3] += av * v4.w;
    }
    float4 res;
    res.x = acco[0]; res.y = acco[1]; res.z = acco[2]; res.w = acco[3];
    *(float4*)&o[vo_base + (size_t)(t0 + oc) * D_ + od] = res;
    __syncthreads();
  }
}

// ---------- fused gate (sigmoid(x@Wg1@Wg2)) * o, then RMSNorm * norm_w, in place
__global__ __launch_bounds__(256) void gate_norm_kernel(
    const float* __restrict__ x, const float* __restrict__ Wg1,
    const float* __restrict__ Wg2, const float* __restrict__ nw,
    float* __restrict__ o) {
  const int row = blockIdx.x, tid = threadIdx.x;
  const int lane = tid & 63, wv = tid >> 6;
  __shared__ float redp[4][16];
  __shared__ float tg[16];
  __shared__ float rs[4];

  float4 xv = *(const float4*)&x[(size_t)row * D_ + tid * 4];
  float xa[4] = {xv.x, xv.y, xv.z, xv.w};
  float acc[16];
#pragma unroll
  for (int hh = 0; hh < 16; ++hh) acc[hh] = 0.f;
#pragma unroll
  for (int u = 0; u < 4; ++u) {
    const float* wr = &Wg1[(size_t)(tid * 4 + u) * 16];
    float wf[16];
    *(float4*)&wf[0]  = *(const float4*)(wr);
    *(float4*)&wf[4]  = *(const float4*)(wr + 4);
    *(float4*)&wf[8]  = *(const float4*)(wr + 8);
    *(float4*)&wf[12] = *(const float4*)(wr + 12);
#pragma unroll
    for (int hh = 0; hh < 16; ++hh) acc[hh] += xa[u] * wf[hh];
  }
#pragma unroll
  for (int hh = 0; hh < 16; ++hh) {
#pragma unroll
    for (int off = 32; off > 0; off >>= 1) acc[hh] += __shfl_xor(acc[hh], off);
  }
  if (lane == 0) {
#pragma unroll
    for (int hh = 0; hh < 16; ++hh) redp[wv][hh] = acc[hh];
  }
  __syncthreads();
  if (tid < 16) tg[tid] = redp[0][tid] + redp[1][tid] + redp[2][tid] + redp[3][tid];
  __syncthreads();

  float4 o4 = *(const float4*)&o[(size_t)row * D_ + tid * 4];
  float oa[4] = {o4.x, o4.y, o4.z, o4.w};
  float og[4];
  float ssq = 0.f;
#pragma unroll
  for (int u = 0; u < 4; ++u) {
    const int d = tid * 4 + u;
    float sg = 0.f;
#pragma unroll
    for (int hh = 0; hh < 16; ++hh) sg += tg[hh] * Wg2[hh * 1024 + d];
    float gate = 1.f / (1.f + expf(-sg));
    og[u] = oa[u] * gate;
    ssq += og[u] * og[u];
  }
#pragma unroll
  for (int off = 32; off > 0; off >>= 1) ssq += __shfl_xor(ssq, off);
  if (lane == 0) rs[wv] = ssq;
  __syncthreads();
  const float tot = rs[0] + rs[1] + rs[2] + rs[3];
  const float rinv = rsqrtf(tot * (1.f / 1024.f) + 1e-6f);
  float4 outv;
  float* op = (float*)&outv;
#pragma unroll
  for (int u = 0; u < 4; ++u) {
    const int d = tid * 4 + u;
    op[u] = og[u] * rinv * nw[d];
  }
  *(float4*)&o[(size_t)row * D_ + tid * 4] = outv;
}

extern "C" void kernel_launch(void* const* d_in, const int* in_sizes, int n_in,
                              void* d_out, int out_size, void* d_ws, size_t ws_size,
                              hipStream_t stream) {
  const float* x   = (const float*)d_in[0];
  const float* Wq  = (const float*)d_in[1];
  const float* Wk  = (const float*)d_in[2];
  const float* Wv  = (const float*)d_in[3];
  const float* Wo  = (const float*)d_in[4];
  const float* Wg1 = (const float*)d_in[5];
  const float* Wg2 = (const float*)d_in[6];
  const float* nw  = (const float*)d_in[7];
  float* out = (float*)d_out;
  float* ws  = (float*)d_ws;

  // workspace layout (floats); P = B*N*D = 8,388,608 -> total 8P floats = 268 MB
  const size_t P = (size_t)B_ * N_ * D_;
  float* k_raw = ws;            // (B,N,D)
  float* v_buf = ws + P;        // (B,N,H,64) == (B,N,D)
  float* log_f = ws + 2 * P;    // (B,H,N,64)
  float* q_rot = ws + 3 * P;    // (B,H,N,128)  [2P]
  float* k_rot = ws + 5 * P;    // (B,H,N,128)  [2P]
  float* qs_o  = ws + 7 * P;    // q_silu (B,N,D), later reused as GLA output o

  // scan scratch: lives in the (not-yet-written) q_rot region
  float* T_buf = q_rot;                 // 4096 channels x 32 chunks
  float* P_buf = q_rot + 4096 * 32;     // 4096 channels x 32 prefixes

  const int M = B_ * N_;
  dim3 ggrid(D_ / 64, M / 64);

  gemm_f32<<<ggrid, 256, 0, stream>>>(x, Wq, qs_o, M, D_, D_, 1);   // q = silu(x@Wq)
  gemm_f32<<<ggrid, 256, 0, stream>>>(x, Wk, k_raw, M, D_, D_, 0);  // k_raw
  gemm_f32<<<ggrid, 256, 0, stream>>>(x, Wv, v_buf, M, D_, D_, 0);  // v
  scan_pass_a<<<512, 256, 0, stream>>>(k_raw, T_buf);
  scan_pass_b<<<16, 256, 0, stream>>>(T_buf, P_buf);
  scan_pass_c<<<512, 256, 0, stream>>>(k_raw, P_buf, log_f, k_rot);
  lrpe_q_kernel<<<(int)(P / 256), 256, 0, stream>>>(qs_o, q_rot);
  gla_kernel<<<256, 256, 0, stream>>>(q_rot, k_rot, log_f, v_buf, qs_o);
  gate_norm_kernel<<<M, 256, 0, stream>>>(x, Wg1, Wg2, nw, qs_o);
  gemm_f32<<<ggrid, 256, 0, stream>>>(qs_o, Wo, out, M, D_, D_, 0); // final proj
}

// Round 3
// 1351.386 us; speedup vs baseline: 1.9388x; 1.2429x over previous
//
#include <hip/hip_runtime.h>
#include <hip/hip_bf16.h>
#include <math.h>

#define B_ 4
#define N_ 2048
#define D_ 1024
#define H_ 16
#define HD_ 64
#define NC_ 32

__device__ inline float bf2f(unsigned short u) {
  return __uint_as_float(((unsigned)u) << 16);
}
__device__ inline unsigned short f2bf(float f) {
  unsigned u = __float_as_uint(f);
  unsigned r = (u + 0x7fffu + ((u >> 16) & 1u)) >> 16;
  return (unsigned short)r;
}

// ---------- GEMM f32: C[M,Nn] = A[M,K] @ Bw[K,Nn]; mode 1 applies silu ----------
__global__ __launch_bounds__(256) void gemm_f32(const float* __restrict__ A,
    const float* __restrict__ Bw, float* __restrict__ C,
    int M, int K, int Nn, int mode) {
  __shared__ float As[16][68];  // [k][m], padded
  __shared__ float Bs[16][68];  // [k][n], padded
  const int tid = threadIdx.x;
  const int m0 = blockIdx.y * 64, n0 = blockIdx.x * 64;
  const int tm = (tid & 15) * 4, tn = (tid >> 4) * 4;
  const int la_m = tid >> 2, la_k = (tid & 3) * 4;
  const int lb_k = tid >> 4, lb_n = (tid & 15) * 4;
  float acc[4][4];
#pragma unroll
  for (int i = 0; i < 4; ++i)
#pragma unroll
    for (int j = 0; j < 4; ++j) acc[i][j] = 0.f;

  for (int kt = 0; kt < K; kt += 16) {
    float4 a4 = *(const float4*)&A[(size_t)(m0 + la_m) * K + kt + la_k];
    float4 b4 = *(const float4*)&Bw[(size_t)(kt + lb_k) * Nn + n0 + lb_n];
    As[la_k + 0][la_m] = a4.x;
    As[la_k + 1][la_m] = a4.y;
    As[la_k + 2][la_m] = a4.z;
    As[la_k + 3][la_m] = a4.w;
    *(float4*)&Bs[lb_k][lb_n] = b4;
    __syncthreads();
#pragma unroll
    for (int kk = 0; kk < 16; ++kk) {
      float4 av = *(const float4*)&As[kk][tm];
      float4 bv = *(const float4*)&Bs[kk][tn];
      float aa[4] = {av.x, av.y, av.z, av.w};
      float bb[4] = {bv.x, bv.y, bv.z, bv.w};
#pragma unroll
      for (int i = 0; i < 4; ++i)
#pragma unroll
        for (int j = 0; j < 4; ++j) acc[i][j] += aa[i] * bb[j];
    }
    __syncthreads();
  }
#pragma unroll
  for (int i = 0; i < 4; ++i) {
    float r[4];
#pragma unroll
    for (int j = 0; j < 4; ++j) {
      float vv = acc[i][j];
      if (mode == 1) vv = vv / (1.f + expf(-vv));  // silu
      r[j] = vv;
    }
    float4 outv;
    outv.x = r[0]; outv.y = r[1]; outv.z = r[2]; outv.w = r[3];
    *(float4*)&C[(size_t)(m0 + tm + i) * Nn + n0 + tn] = outv;
  }
}

// ---------- 3-pass parallel cumlogsumexp scan ----------
__global__ __launch_bounds__(256) void scan_pass_a(const float* __restrict__ k_raw,
                                                   float* __restrict__ T) {
  const int g = blockIdx.x * 256 + threadIdx.x;  // (bh, c, hd)
  const int hd = g & 63;
  const int c = (g >> 6) & 31;
  const int bh = g >> 11;  // 0..63
  const int b = bh >> 4, h = bh & 15;
  const size_t base = (size_t)b * N_ * D_ + (size_t)(c * 64) * D_ + h * HD_ + hd;
  float nxt = k_raw[base];
  float l = 0.f;
  for (int j = 0; j < 64; ++j) {
    float kr = nxt;
    if (j + 1 < 64) nxt = k_raw[base + (size_t)(j + 1) * D_];
    if (j == 0) {
      l = kr;
    } else {
      float mx = fmaxf(l, kr), mn = fminf(l, kr);
      l = mx + log1pf(expf(mn - mx));
    }
  }
  T[(size_t)(bh * 64 + hd) * 32 + c] = l;
}

__global__ void scan_pass_b(const float* __restrict__ T, float* __restrict__ Pf) {
  const int ch = blockIdx.x * 256 + threadIdx.x;  // 0..4095
  const float* t = &T[(size_t)ch * 32];
  float* p = &Pf[(size_t)ch * 32];
  float run = 0.f;
  for (int c = 0; c < 32; ++c) {
    p[c] = run;
    float tv = t[c];
    float mx = fmaxf(run, tv), mn = fminf(run, tv);
    run = mx + log1pf(expf(mn - mx));
  }
}

__global__ __launch_bounds__(256) void scan_pass_c(const float* __restrict__ k_raw,
    const float* __restrict__ Pf, float* __restrict__ log_f, float* __restrict__ k_rot) {
  const int g = blockIdx.x * 256 + threadIdx.x;
  const int hd = g & 63;
  const int c = (g >> 6) & 31;
  const int bh = g >> 11;
  const int b = bh >> 4, h = bh & 15;
  const float freq = expf((float)hd * -0.28782313662425575f);  // 1e4^(-2*hd/64)
  const size_t base = (size_t)b * N_ * D_ + (size_t)(c * 64) * D_ + h * HD_ + hd;
  const size_t lf_off = (size_t)bh * N_ * 64 + (size_t)(c * 64) * 64 + hd;
  const size_t kr_off = (size_t)bh * N_ * 128 + (size_t)(c * 64) * 128 + hd;
  const float P = Pf[(size_t)(bh * 64 + hd) * 32 + c];
  float l = 0.f;
  float zprev = P;
  float nxt = k_raw[base];
  for (int j = 0; j < 64; ++j) {
    float kr = nxt;
    if (j + 1 < 64) nxt = k_raw[base + (size_t)(j + 1) * D_];
    if (j == 0) {
      l = kr;
    } else {
      float mx = fmaxf(l, kr), mn = fminf(l, kr);
      l = mx + log1pf(expf(mn - mx));
    }
    float mx2 = fmaxf(P, l), mn2 = fminf(P, l);
    float z = mx2 + log1pf(expf(mn2 - mx2));
    log_f[lf_off + (size_t)j * 64] = zprev - z;
    float kt = expf(kr - z);
    const int n = c * 64 + j;
    float s, cs;
    sincosf((float)n * freq, &s, &cs);
    k_rot[kr_off + (size_t)j * 128] = kt * cs;
    k_rot[kr_off + (size_t)j * 128 + 64] = kt * s;
    zprev = z;
  }
}

// ---------- GLA pass A: per-(bh,chunk) block. Computes G, qg (with q-LRPE folded),
// kg, A=masked(qg@kg^T), o_intra=A@v, U=(k*exp(Glast-G))^T@v (bf16), Glast.
__global__ __launch_bounds__(256) void gla_a(
    const float* __restrict__ q_silu, const float* __restrict__ k_rot,
    const float* __restrict__ log_f, const float* __restrict__ v,
    float* __restrict__ qg_out, unsigned short* __restrict__ U,
    float* __restrict__ o, float* __restrict__ glast_g) {
  __shared__ float Gs[64][68];    // G cumsum [c][j<64]; later masked A^T [s][c]
  __shared__ float qgT[64][68];   // per-phase qg^T [jl][row]; then kgN [s][jl]
  __shared__ float kgT[64][68];   // per-phase kg^T [jl][row]
  __shared__ unsigned short v_sb[64][64];  // v [s][d] bf16
  __shared__ float tot[4][68];
  __shared__ float glast_s[64];   // exp(Glast[j])

  const int bid = blockIdx.x;          // bh*32 + c
  const int bh = bid >> 5, c = bid & 31;
  const int b = bh >> 4, h = bh & 15;
  const int t0 = c * 64;
  const int tid = threadIdx.x;

  const size_t x_base = ((size_t)(b * N_ + t0) * H_ + h) * 64;  // q_silu/v/o rows
  const size_t kr_base = ((size_t)bh * N_ + t0) * 128;
  const size_t lf_base = ((size_t)bh * N_ + t0) * 64;

  // ---- load v tile -> bf16 LDS ----
  {
    const int r = tid >> 2, d0 = (tid & 3) * 16;
    const float* vp = &v[x_base + (size_t)r * 1024 + d0];
#pragma unroll
    for (int u = 0; u < 4; ++u) {
      float4 vv = *(const float4*)(vp + 4 * u);
      ushort4 pk;
      pk.x = f2bf(vv.x); pk.y = f2bf(vv.y); pk.z = f2bf(vv.z); pk.w = f2bf(vv.w);
      *(ushort4*)&v_sb[r][d0 + 4 * u] = pk;
    }
  }
  // ---- cumsum of log_f: 4 waves x 16 rows, two-level ----
  const int jc = tid & 63, qq = tid >> 6;
  {
    const float* lp = &log_f[lf_base + (size_t)(qq * 16) * 64 + jc];
    float run = 0.f;
#pragma unroll 4
    for (int cc = 0; cc < 16; ++cc) {
      run += lp[(size_t)cc * 64];
      Gs[qq * 16 + cc][jc] = run;
    }
    tot[qq][jc] = run;
  }
  __syncthreads();
  {
    float offv = 0.f;
    for (int p = 0; p < qq; ++p) offv += tot[p][jc];
    if (qq > 0) {
#pragma unroll 4
      for (int cc = 0; cc < 16; ++cc) Gs[qq * 16 + cc][jc] += offv;
    }
    if (qq == 3) {
      float gl = offv + tot[3][jc];
      glast_g[(size_t)bid * 64 + jc] = gl;
      glast_s[jc] = expf(gl);
    }
  }
  __syncthreads();

  const int br = tid >> 2, bj0 = (tid & 3) * 16;
  const int tm = (tid & 15) * 4, tn = (tid >> 4) * 4;
  const int nrow = t0 + br;
  float accA[4][4];
#pragma unroll
  for (int i = 0; i < 4; ++i)
#pragma unroll
    for (int j = 0; j < 4; ++j) accA[i][j] = 0.f;
  float sinv[16];

#pragma unroll
  for (int ph = 0; ph < 2; ++ph) {
    const int jb = ph * 64;
    // ---- build qgT/kgT for this j-half; write qg to global ----
    {
      const float* qp = &q_silu[x_base + (size_t)br * 1024 + bj0];
      const float* kp = &k_rot[kr_base + (size_t)br * 128 + jb + bj0];
      float* qgo = &qg_out[kr_base + (size_t)br * 128 + jb + bj0];
#pragma unroll
      for (int u = 0; u < 4; ++u) {
        float4 q4 = *(const float4*)(qp + 4 * u);
        float4 k4 = *(const float4*)(kp + 4 * u);
        float qa[4] = {q4.x, q4.y, q4.z, q4.w};
        float ka[4] = {k4.x, k4.y, k4.z, k4.w};
        float qo[4];
#pragma unroll
        for (int e = 0; e < 4; ++e) {
          const int jl = bj0 + 4 * u + e;
          float tr;
          if (ph == 0) {
            const float freq = expf((float)jl * -0.28782313662425575f);
            float sv, cv;
            sincosf((float)nrow * freq, &sv, &cv);
            sinv[4 * u + e] = sv;
            tr = cv;
          } else {
            tr = sinv[4 * u + e];
          }
          const float g = Gs[br][jl];
          const float qgv = qa[e] * tr * expf(g);
          const float kgv = ka[e] * expf(-g);
          qgT[jl][br] = qgv;
          kgT[jl][br] = kgv;
          qo[e] = qgv;
        }
        float4 qo4;
        qo4.x = qo[0]; qo4.y = qo[1]; qo4.z = qo[2]; qo4.w = qo[3];
        *(float4*)(qgo + 4 * u) = qo4;
      }
    }
    __syncthreads();
    // ---- A += qg_half @ kg_half^T  (contraction jl = LDS row, uniform) ----
#pragma unroll 4
    for (int jl = 0; jl < 64; ++jl) {
      float4 qa4 = *(const float4*)&qgT[jl][tm];
      float4 kb4 = *(const float4*)&kgT[jl][tn];
      float qa[4] = {qa4.x, qa4.y, qa4.z, qa4.w};
      float kb[4] = {kb4.x, kb4.y, kb4.z, kb4.w};
#pragma unroll
      for (int i = 0; i < 4; ++i)
#pragma unroll
        for (int jj = 0; jj < 4; ++jj) accA[i][jj] += qa[i] * kb[jj];
    }
    __syncthreads();
    // ---- transpose kgT -> kgN (into qgT buffer): kgN[s][jl] ----
    {
      const int ss = tid >> 2, jl0 = (tid & 3) * 16;
      float tv[16];
#pragma unroll
      for (int e = 0; e < 16; ++e) tv[e] = kgT[jl0 + e][ss];
#pragma unroll
      for (int w = 0; w < 4; ++w) {
        float4 t4;
        t4.x = tv[4 * w]; t4.y = tv[4 * w + 1]; t4.z = tv[4 * w + 2]; t4.w = tv[4 * w + 3];
        *(float4*)&qgT[ss][jl0 + 4 * w] = t4;
      }
    }
    __syncthreads();
    // ---- U^T: out[d=tm+i][jl=tn+jj] = sum_s v[s][d]*kgN[s][jl]; scale e^Glast ----
    {
      float accU[4][4];
#pragma unroll
      for (int i = 0; i < 4; ++i)
#pragma unroll
        for (int jj = 0; jj < 4; ++jj) accU[i][jj] = 0.f;
#pragma unroll 4
      for (int s = 0; s < 64; ++s) {
        ushort4 vv = *(const ushort4*)&v_sb[s][tm];
        float vf[4] = {bf2f(vv.x), bf2f(vv.y), bf2f(vv.z), bf2f(vv.w)};
        float4 kn4 = *(const float4*)&qgT[s][tn];
        float kn[4] = {kn4.x, kn4.y, kn4.z, kn4.w};
#pragma unroll
        for (int i = 0; i < 4; ++i)
#pragma unroll
          for (int jj = 0; jj < 4; ++jj) accU[i][jj] += vf[i] * kn[jj];
      }
      float es[4];
#pragma unroll
      for (int jj = 0; jj < 4; ++jj) es[jj] = glast_s[tn + jj];
#pragma unroll
      for (int i = 0; i < 4; ++i) {
        ushort4 pk;
        pk.x = f2bf(accU[i][0] * es[0]);
        pk.y = f2bf(accU[i][1] * es[1]);
        pk.z = f2bf(accU[i][2] * es[2]);
        pk.w = f2bf(accU[i][3] * es[3]);
        *(ushort4*)&U[((size_t)bid * 64 + tm + i) * 128 + jb + tn] = pk;
      }
    }
    __syncthreads();
  }
  // ---- masked A^T into Gs: AT[s][c] ----
#pragma unroll
  for (int i = 0; i < 4; ++i)
#pragma unroll
    for (int jj = 0; jj < 4; ++jj) {
      const int cr = tm + i, ss = tn + jj;
      Gs[ss][cr] = (ss <= cr) ? accA[i][jj] : 0.f;
    }
  __syncthreads();
  // ---- o_intra[c=tm+i][d=tn+jj] = sum_s AT[s][c]*v[s][d]; write o ----
  {
    float acco[4][4];
#pragma unroll
    for (int i = 0; i < 4; ++i)
#pragma unroll
      for (int jj = 0; jj < 4; ++jj) acco[i][jj] = 0.f;
#pragma unroll 4
    for (int s = 0; s < 64; ++s) {
      float4 a4 = *(const float4*)&Gs[s][tm];
      float aa[4] = {a4.x, a4.y, a4.z, a4.w};
      ushort4 vv = *(const ushort4*)&v_sb[s][tn];
      float vf[4] = {bf2f(vv.x), bf2f(vv.y), bf2f(vv.z), bf2f(vv.w)};
#pragma unroll
      for (int i = 0; i < 4; ++i)
#pragma unroll
        for (int jj = 0; jj < 4; ++jj) acco[i][jj] += aa[i] * vf[jj];
    }
#pragma unroll
    for (int i = 0; i < 4; ++i) {
      float4 ov;
      ov.x = acco[i][0]; ov.y = acco[i][1]; ov.z = acco[i][2]; ov.w = acco[i][3];
      *(float4*)&o[x_base + (size_t)(tm + i) * 1024 + tn] = ov;
    }
  }
}

// ---------- GLA pass B: in-place exclusive scan over chunks:
// slot c <- S_{c-1};  S_c = S_{c-1}*exp(glast_c) + U_c  (state in f32 regs)
__global__ __launch_bounds__(256) void gla_b(unsigned short* __restrict__ U,
                                             const float* __restrict__ glast_g) {
  const int t = blockIdx.x * 256 + threadIdx.x;  // 131072 = 64bh * 64d * 32j4
  const int j4 = t & 31;
  const int d = (t >> 5) & 63;
  const int bh = t >> 11;
  const int jj0 = (4 * j4) & 63;
  float s0 = 0.f, s1 = 0.f, s2 = 0.f, s3 = 0.f;
  for (int c = 0; c < 32; ++c) {
    const size_t ub = ((size_t)((bh * 32 + c) * 64 + d)) * 128 + 4 * j4;
    ushort4 uv = *(const ushort4*)&U[ub];
    float4 g4 = *(const float4*)&glast_g[(size_t)(bh * 32 + c) * 64 + jj0];
    ushort4 pv;
    pv.x = f2bf(s0); pv.y = f2bf(s1); pv.z = f2bf(s2); pv.w = f2bf(s3);
    *(ushort4*)&U[ub] = pv;
    s0 = s0 * expf(g4.x) + bf2f(uv.x);
    s1 = s1 * expf(g4.y) + bf2f(uv.y);
    s2 = s2 * expf(g4.z) + bf2f(uv.z);
    s3 = s3 * expf(g4.w) + bf2f(uv.w);
  }
}

// ---------- GLA pass C: o += qg @ S_{c-1} ----------
__global__ __launch_bounds__(256) void gla_c(const float* __restrict__ qg,
    const unsigned short* __restrict__ S, float* __restrict__ o) {
  __shared__ float qgT[64][68];           // [jl][row]
  __shared__ unsigned short sT[64][64];   // [jl][d] bf16
  const int bid = blockIdx.x;
  const int bh = bid >> 5, c = bid & 31;
  const int b = bh >> 4, h = bh & 15;
  const int t0 = c * 64;
  const int tid = threadIdx.x;
  const size_t qg_base = ((size_t)bh * N_ + t0) * 128;
  const size_t o_base = ((size_t)(b * N_ + t0) * H_ + h) * 64;
  const size_t s_base = (size_t)bid * 64 * 128;
  const int br = tid >> 2, bj0 = (tid & 3) * 16;
  const int tm = (tid & 15) * 4, tn = (tid >> 4) * 4;
  const int sd = tid & 63, sg = (tid >> 6) * 16;
  float acc[4][4];
#pragma unroll
  for (int i = 0; i < 4; ++i)
#pragma unroll
    for (int j = 0; j < 4; ++j) acc[i][j] = 0.f;

#pragma unroll
  for (int ph = 0; ph < 2; ++ph) {
    const int jb = ph * 64;
    {
      const float* qp = &qg[qg_base + (size_t)br * 128 + jb + bj0];
#pragma unroll
      for (int u = 0; u < 4; ++u) {
        float4 q4 = *(const float4*)(qp + 4 * u);
        qgT[bj0 + 4 * u + 0][br] = q4.x;
        qgT[bj0 + 4 * u + 1][br] = q4.y;
        qgT[bj0 + 4 * u + 2][br] = q4.z;
        qgT[bj0 + 4 * u + 3][br] = q4.w;
      }
      const unsigned short* sp = &S[s_base + (size_t)sd * 128 + jb + sg];
      unsigned short tv[16];
      *(uint4*)&tv[0] = *(const uint4*)sp;
      *(uint4*)&tv[8] = *(const uint4*)(sp + 8);
#pragma unroll
      for (int e = 0; e < 16; ++e) sT[sg + e][sd] = tv[e];
    }
    __syncthreads();
#pragma unroll 4
    for (int jl = 0; jl < 64; ++jl) {
      float4 q4 = *(const float4*)&qgT[jl][tm];
      float qa[4] = {q4.x, q4.y, q4.z, q4.w};
      ushort4 sv = *(const ushort4*)&sT[jl][tn];
      float sf[4] = {bf2f(sv.x), bf2f(sv.y), bf2f(sv.z), bf2f(sv.w)};
#pragma unroll
      for (int i = 0; i < 4; ++i)
#pragma unroll
        for (int jj = 0; jj < 4; ++jj) acc[i][jj] += qa[i] * sf[jj];
    }
    __syncthreads();
  }
#pragma unroll
  for (int i = 0; i < 4; ++i) {
    float* op = &o[o_base + (size_t)(tm + i) * 1024 + tn];
    float4 ov = *(float4*)op;
    ov.x += acc[i][0]; ov.y += acc[i][1]; ov.z += acc[i][2]; ov.w += acc[i][3];
    *(float4*)op = ov;
  }
}

// ---------- fused gate (sigmoid(x@Wg1@Wg2)) * o, then RMSNorm * norm_w, in place
__global__ __launch_bounds__(256) void gate_norm_kernel(
    const float* __restrict__ x, const float* __restrict__ Wg1,
    const float* __restrict__ Wg2, const float* __restrict__ nw,
    float* __restrict__ o) {
  const int row = blockIdx.x, tid = threadIdx.x;
  const int lane = tid & 63, wv = tid >> 6;
  __shared__ float redp[4][16];
  __shared__ float tg[16];
  __shared__ float rs[4];

  float4 xv = *(const float4*)&x[(size_t)row * D_ + tid * 4];
  float xa[4] = {xv.x, xv.y, xv.z, xv.w};
  float acc[16];
#pragma unroll
  for (int hh = 0; hh < 16; ++hh) acc[hh] = 0.f;
#pragma unroll
  for (int u = 0; u < 4; ++u) {
    const float* wr = &Wg1[(size_t)(tid * 4 + u) * 16];
    float wf[16];
    *(float4*)&wf[0]  = *(const float4*)(wr);
    *(float4*)&wf[4]  = *(const float4*)(wr + 4);
    *(float4*)&wf[8]  = *(const float4*)(wr + 8);
    *(float4*)&wf[12] = *(const float4*)(wr + 12);
#pragma unroll
    for (int hh = 0; hh < 16; ++hh) acc[hh] += xa[u] * wf[hh];
  }
#pragma unroll
  for (int hh = 0; hh < 16; ++hh) {
#pragma unroll
    for (int off = 32; off > 0; off >>= 1) acc[hh] += __shfl_xor(acc[hh], off);
  }
  if (lane == 0) {
#pragma unroll
    for (int hh = 0; hh < 16; ++hh) redp[wv][hh] = acc[hh];
  }
  __syncthreads();
  if (tid < 16) tg[tid] = redp[0][tid] + redp[1][tid] + redp[2][tid] + redp[3][tid];
  __syncthreads();

  float4 o4 = *(const float4*)&o[(size_t)row * D_ + tid * 4];
  float oa[4] = {o4.x, o4.y, o4.z, o4.w};
  float og[4];
  float ssq = 0.f;
#pragma unroll
  for (int u = 0; u < 4; ++u) {
    const int d = tid * 4 + u;
    float sg = 0.f;
#pragma unroll
    for (int hh = 0; hh < 16; ++hh) sg += tg[hh] * Wg2[hh * 1024 + d];
    float gate = 1.f / (1.f + expf(-sg));
    og[u] = oa[u] * gate;
    ssq += og[u] * og[u];
  }
#pragma unroll
  for (int off = 32; off > 0; off >>= 1) ssq += __shfl_xor(ssq, off);
  if (lane == 0) rs[wv] = ssq;
  __syncthreads();
  const float tot = rs[0] + rs[1] + rs[2] + rs[3];
  const float rinv = rsqrtf(tot * (1.f / 1024.f) + 1e-6f);
  float4 outv;
  float* op = (float*)&outv;
#pragma unroll
  for (int u = 0; u < 4; ++u) {
    const int d = tid * 4 + u;
    op[u] = og[u] * rinv * nw[d];
  }
  *(float4*)&o[(size_t)row * D_ + tid * 4] = outv;
}

extern "C" void kernel_launch(void* const* d_in, const int* in_sizes, int n_in,
                              void* d_out, int out_size, void* d_ws, size_t ws_size,
                              hipStream_t stream) {
  const float* x   = (const float*)d_in[0];
  const float* Wq  = (const float*)d_in[1];
  const float* Wk  = (const float*)d_in[2];
  const float* Wv  = (const float*)d_in[3];
  const float* Wo  = (const float*)d_in[4];
  const float* Wg1 = (const float*)d_in[5];
  const float* Wg2 = (const float*)d_in[6];
  const float* nw  = (const float*)d_in[7];
  float* out = (float*)d_out;
  float* ws  = (float*)d_ws;

  // workspace layout (floats); P = B*N*D = 8,388,608 -> total 8P floats = 268 MB
  const size_t P = (size_t)B_ * N_ * D_;
  float* k_raw = ws;            // (B,N,D); dead after scan -> U/S buffer (bf16, 2P elems)
  float* v_buf = ws + P;        // (B,N,H,64)
  float* log_f = ws + 2 * P;    // (B,H,N,64)
  float* qg_buf = ws + 3 * P;   // (B,H,N,128) qg [2P]; scan T/P scratch before gla_a
  float* k_rot = ws + 5 * P;    // (B,H,N,128)  [2P]
  float* qs_o  = ws + 7 * P;    // q_silu (B,N,H,64), overwritten in-place by GLA output o

  unsigned short* U_buf = (unsigned short*)k_raw;  // [bh][c][d=64][j=128] bf16 = 2P elems
  float* T_buf = qg_buf;                 // 4096 channels x 32 chunks
  float* P_buf = qg_buf + 4096 * 32;     // 4096 channels x 32 prefixes
  float* glast_g = (float*)d_out;        // [bh*32+c][64]; dead before final gemm writes d_out

  const int M = B_ * N_;
  dim3 ggrid(D_ / 64, M / 64);

  gemm_f32<<<ggrid, 256, 0, stream>>>(x, Wq, qs_o, M, D_, D_, 1);   // q = silu(x@Wq)
  gemm_f32<<<ggrid, 256, 0, stream>>>(x, Wk, k_raw, M, D_, D_, 0);  // k_raw
  gemm_f32<<<ggrid, 256, 0, stream>>>(x, Wv, v_buf, M, D_, D_, 0);  // v
  scan_pass_a<<<512, 256, 0, stream>>>(k_raw, T_buf);
  scan_pass_b<<<16, 256, 0, stream>>>(T_buf, P_buf);
  scan_pass_c<<<512, 256, 0, stream>>>(k_raw, P_buf, log_f, k_rot);
  gla_a<<<2048, 256, 0, stream>>>(qs_o, k_rot, log_f, v_buf, qg_buf, U_buf, qs_o, glast_g);
  gla_b<<<512, 256, 0, stream>>>(U_buf, glast_g);
  gla_c<<<2048, 256, 0, stream>>>(qg_buf, U_buf, qs_o);
  gate_norm_kernel<<<M, 256, 0, stream>>>(x, Wg1, Wg2, nw, qs_o);
  gemm_f32<<<ggrid, 256, 0, stream>>>(qs_o, Wo, out, M, D_, D_, 0); // final proj
}

// Round 4
// 575.926 us; speedup vs baseline: 4.5492x; 2.3465x over previous
//
#include <hip/hip_runtime.h>
#include <hip/hip_bf16.h>
#include <math.h>

#define B_ 4
#define N_ 2048
#define D_ 1024
#define H_ 16
#define HD_ 64
#define NC_ 32

typedef __attribute__((ext_vector_type(8))) short bf16x8;
typedef __attribute__((ext_vector_type(4))) float f32x4;

#define AS1(p) ((const __attribute__((address_space(1))) void*)(p))
#define AS3(p) ((__attribute__((address_space(3))) void*)(p))

__device__ inline float bf2f(unsigned short u) {
  return __uint_as_float(((unsigned)u) << 16);
}
__device__ inline unsigned short f2bf(float f) {
  unsigned u = __float_as_uint(f);
  unsigned r = (u + 0x7fffu + ((u >> 16) & 1u)) >> 16;
  return (unsigned short)r;
}

// ---------- cast x (f32) -> bf16 row-major ----------
__global__ __launch_bounds__(256) void cast_x_bf16(const float* __restrict__ x,
                                                   unsigned short* __restrict__ xb) {
  const int t = blockIdx.x * 256 + threadIdx.x;  // one per 8 elems
  float4 a = ((const float4*)x)[(size_t)t * 2];
  float4 b = ((const float4*)x)[(size_t)t * 2 + 1];
  union { unsigned short u[8]; uint4 q; } pk;
  pk.u[0] = f2bf(a.x); pk.u[1] = f2bf(a.y); pk.u[2] = f2bf(a.z); pk.u[3] = f2bf(a.w);
  pk.u[4] = f2bf(b.x); pk.u[5] = f2bf(b.y); pk.u[6] = f2bf(b.z); pk.u[7] = f2bf(b.w);
  ((uint4*)xb)[t] = pk.q;
}

// ---------- cast W (f32 [1024][1024]) -> bf16 k-packed [(K/8)][N][8] ----------
__global__ __launch_bounds__(256) void cast_w_pack(const float* __restrict__ W,
                                                   unsigned short* __restrict__ Wp) {
  const int t = blockIdx.x * 256 + threadIdx.x;  // 131072 = 128 kg * 1024 n
  const int kg = t >> 10, n = t & 1023;
  union { unsigned short u[8]; uint4 q; } pk;
#pragma unroll
  for (int r = 0; r < 8; ++r)
    pk.u[r] = f2bf(W[(size_t)(kg * 8 + r) * 1024 + n]);
  *(uint4*)&Wp[((size_t)kg * 1024 + n) * 8] = pk.q;
}

// ---------- MFMA bf16 GEMM: C[M,Nn](f32) = A[M,K](bf16 rowmajor) @ Wp(k-packed)
// mode 1 applies silu. 128x128 tile, BK=32, 4 waves, m97 structure.
__global__ __launch_bounds__(256) void gemm_bf16(
    const unsigned short* __restrict__ A, const unsigned short* __restrict__ Wp,
    float* __restrict__ C, int M, int K, int Nn, int mode) {
  __shared__ unsigned short Asm[128 * 32];   // [row][slot'^swz][8]
  __shared__ unsigned short Bsm[4 * 128 * 8];  // [g][n_local][8]

  const int tid = threadIdx.x;
  const int lane = tid & 63;
  const int w = tid >> 6;
  const int nb = Nn >> 7;
  const int nwg = gridDim.x;
  const int cpx = nwg >> 3;
  int bid = blockIdx.x;
  bid = (bid & 7) * cpx + (bid >> 3);          // XCD swizzle (nwg % 8 == 0)
  const int by = bid / nb, bx = bid % nb;
  const int m0 = by * 128, n0 = bx * 128;
  const int wr = w >> 1, wc = w & 1;

  f32x4 acc[4][4];
#pragma unroll
  for (int i = 0; i < 4; ++i)
#pragma unroll
    for (int j = 0; j < 4; ++j) acc[i][j] = (f32x4){0.f, 0.f, 0.f, 0.f};

  // staging addresses (elements). A chunks w and w+4 (16 rows each);
  // swizzle: data slot stored at (row, slotp) is slotp ^ ((row>>1)&3).
  const int rA0 = w * 16 + (lane >> 2);
  const int rA1 = (w + 4) * 16 + (lane >> 2);
  const int sA0 = (lane & 3) ^ ((rA0 >> 1) & 3);
  const int sA1 = (lane & 3) ^ ((rA1 >> 1) & 3);
  const unsigned short* gA0 = A + (size_t)(m0 + rA0) * K + sA0 * 8;
  const unsigned short* gA1 = A + (size_t)(m0 + rA1) * K + sA1 * 8;
  // B chunks w, w+4: g = ch>>1, nhalf = ch&1
  const unsigned short* gB0 = Wp + (size_t)(w >> 1) * Nn * 8 +
                              (size_t)(n0 + (w & 1) * 64 + lane) * 8;
  const unsigned short* gB1 = Wp + (size_t)((w + 4) >> 1) * Nn * 8 +
                              (size_t)(n0 + ((w + 4) & 1) * 64 + lane) * 8;

  // fragment read offsets (elements), invariant
  int offA[4], offB[4];
#pragma unroll
  for (int m = 0; m < 4; ++m) {
    const int rowf = wr * 64 + m * 16 + (lane & 15);
    const int sp = (lane >> 4) ^ ((rowf >> 1) & 3);
    offA[m] = rowf * 32 + sp * 8;
  }
#pragma unroll
  for (int n = 0; n < 4; ++n) {
    const int colf = wc * 64 + n * 16 + (lane & 15);
    offB[n] = (lane >> 4) * 1024 + colf * 8;
  }

  for (int kt = 0; kt < K; kt += 32) {
    const size_t kB = (size_t)(kt >> 3) * Nn * 8;
    __builtin_amdgcn_global_load_lds(AS1(gA0 + kt), AS3(&Asm[w * 512]), 16, 0, 0);
    __builtin_amdgcn_global_load_lds(AS1(gA1 + kt), AS3(&Asm[(w + 4) * 512]), 16, 0, 0);
    __builtin_amdgcn_global_load_lds(AS1(gB0 + kB), AS3(&Bsm[w * 512]), 16, 0, 0);
    __builtin_amdgcn_global_load_lds(AS1(gB1 + kB), AS3(&Bsm[(w + 4) * 512]), 16, 0, 0);
    __syncthreads();
    bf16x8 af[4], bfr[4];
#pragma unroll
    for (int m = 0; m < 4; ++m) af[m] = *(const bf16x8*)&Asm[offA[m]];
#pragma unroll
    for (int n = 0; n < 4; ++n) bfr[n] = *(const bf16x8*)&Bsm[offB[n]];
#pragma unroll
    for (int m = 0; m < 4; ++m)
#pragma unroll
      for (int n = 0; n < 4; ++n)
        acc[m][n] = __builtin_amdgcn_mfma_f32_16x16x32_bf16(af[m], bfr[n], acc[m][n], 0, 0, 0);
    __syncthreads();
  }

  const int crow = (lane >> 4) * 4;
  const int ccol = lane & 15;
#pragma unroll
  for (int m = 0; m < 4; ++m)
#pragma unroll
    for (int n = 0; n < 4; ++n) {
#pragma unroll
      for (int r = 0; r < 4; ++r) {
        float vv = acc[m][n][r];
        if (mode == 1) vv = vv / (1.f + expf(-vv));
        C[(size_t)(m0 + wr * 64 + m * 16 + crow + r) * Nn +
          n0 + wc * 64 + n * 16 + ccol] = vv;
      }
    }
}

// ---------- 3-pass parallel cumlogsumexp scan ----------
__global__ __launch_bounds__(256) void scan_pass_a(const float* __restrict__ k_raw,
                                                   float* __restrict__ T) {
  const int g = blockIdx.x * 256 + threadIdx.x;  // (bh, c, hd)
  const int hd = g & 63;
  const int c = (g >> 6) & 31;
  const int bh = g >> 11;  // 0..63
  const int b = bh >> 4, h = bh & 15;
  const size_t base = (size_t)b * N_ * D_ + (size_t)(c * 64) * D_ + h * HD_ + hd;
  float nxt = k_raw[base];
  float l = 0.f;
  for (int j = 0; j < 64; ++j) {
    float kr = nxt;
    if (j + 1 < 64) nxt = k_raw[base + (size_t)(j + 1) * D_];
    if (j == 0) {
      l = kr;
    } else {
      float mx = fmaxf(l, kr), mn = fminf(l, kr);
      l = mx + log1pf(expf(mn - mx));
    }
  }
  T[(size_t)(bh * 64 + hd) * 32 + c] = l;
}

__global__ void scan_pass_b(const float* __restrict__ T, float* __restrict__ Pf) {
  const int ch = blockIdx.x * 256 + threadIdx.x;  // 0..4095
  const float* t = &T[(size_t)ch * 32];
  float* p = &Pf[(size_t)ch * 32];
  float run = 0.f;
  for (int c = 0; c < 32; ++c) {
    p[c] = run;
    float tv = t[c];
    float mx = fmaxf(run, tv), mn = fminf(run, tv);
    run = mx + log1pf(expf(mn - mx));
  }
}

__global__ __launch_bounds__(256) void scan_pass_c(const float* __restrict__ k_raw,
    const float* __restrict__ Pf, float* __restrict__ log_f, float* __restrict__ k_rot) {
  const int g = blockIdx.x * 256 + threadIdx.x;
  const int hd = g & 63;
  const int c = (g >> 6) & 31;
  const int bh = g >> 11;
  const int b = bh >> 4, h = bh & 15;
  const float freq = expf((float)hd * -0.28782313662425575f);  // 1e4^(-2*hd/64)
  const size_t base = (size_t)b * N_ * D_ + (size_t)(c * 64) * D_ + h * HD_ + hd;
  const size_t lf_off = (size_t)bh * N_ * 64 + (size_t)(c * 64) * 64 + hd;
  const size_t kr_off = (size_t)bh * N_ * 128 + (size_t)(c * 64) * 128 + hd;
  const float P = Pf[(size_t)(bh * 64 + hd) * 32 + c];
  float l = 0.f;
  float zprev = P;
  float nxt = k_raw[base];
  for (int j = 0; j < 64; ++j) {
    float kr = nxt;
    if (j + 1 < 64) nxt = k_raw[base + (size_t)(j + 1) * D_];
    if (j == 0) {
      l = kr;
    } else {
      float mx = fmaxf(l, kr), mn = fminf(l, kr);
      l = mx + log1pf(expf(mn - mx));
    }
    float mx2 = fmaxf(P, l), mn2 = fminf(P, l);
    float z = mx2 + log1pf(expf(mn2 - mx2));
    log_f[lf_off + (size_t)j * 64] = zprev - z;
    float kt = expf(kr - z);
    const int n = c * 64 + j;
    float s, cs;
    sincosf((float)n * freq, &s, &cs);
    k_rot[kr_off + (size_t)j * 128] = kt * cs;
    k_rot[kr_off + (size_t)j * 128 + 64] = kt * s;
    zprev = z;
  }
}

// ---------- GLA pass A ----------
__global__ __launch_bounds__(256) void gla_a(
    const float* __restrict__ q_silu, const float* __restrict__ k_rot,
    const float* __restrict__ log_f, const float* __restrict__ v,
    float* __restrict__ qg_out, unsigned short* __restrict__ U,
    float* __restrict__ o, float* __restrict__ glast_g) {
  __shared__ float Gs[64][68];    // G cumsum [c][j<64]; later masked A^T [s][c]
  __shared__ float qgT[64][68];   // per-phase qg^T [jl][row]; then kgN [s][jl]
  __shared__ float kgT[64][68];   // per-phase kg^T [jl][row]
  __shared__ unsigned short v_sb[64][64];  // v [s][d] bf16
  __shared__ float tot[4][68];
  __shared__ float glast_s[64];   // exp(Glast[j])

  const int bid = blockIdx.x;          // bh*32 + c
  const int bh = bid >> 5, c = bid & 31;
  const int b = bh >> 4, h = bh & 15;
  const int t0 = c * 64;
  const int tid = threadIdx.x;

  const size_t x_base = ((size_t)(b * N_ + t0) * H_ + h) * 64;  // q_silu/v/o rows
  const size_t kr_base = ((size_t)bh * N_ + t0) * 128;
  const size_t lf_base = ((size_t)bh * N_ + t0) * 64;

  {
    const int r = tid >> 2, d0 = (tid & 3) * 16;
    const float* vp = &v[x_base + (size_t)r * 1024 + d0];
#pragma unroll
    for (int u = 0; u < 4; ++u) {
      float4 vv = *(const float4*)(vp + 4 * u);
      ushort4 pk;
      pk.x = f2bf(vv.x); pk.y = f2bf(vv.y); pk.z = f2bf(vv.z); pk.w = f2bf(vv.w);
      *(ushort4*)&v_sb[r][d0 + 4 * u] = pk;
    }
  }
  const int jc = tid & 63, qq = tid >> 6;
  {
    const float* lp = &log_f[lf_base + (size_t)(qq * 16) * 64 + jc];
    float run = 0.f;
#pragma unroll 4
    for (int cc = 0; cc < 16; ++cc) {
      run += lp[(size_t)cc * 64];
      Gs[qq * 16 + cc][jc] = run;
    }
    tot[qq][jc] = run;
  }
  __syncthreads();
  {
    float offv = 0.f;
    for (int p = 0; p < qq; ++p) offv += tot[p][jc];
    if (qq > 0) {
#pragma unroll 4
      for (int cc = 0; cc < 16; ++cc) Gs[qq * 16 + cc][jc] += offv;
    }
    if (qq == 3) {
      float gl = offv + tot[3][jc];
      glast_g[(size_t)bid * 64 + jc] = gl;
      glast_s[jc] = expf(gl);
    }
  }
  __syncthreads();

  const int br = tid >> 2, bj0 = (tid & 3) * 16;
  const int tm = (tid & 15) * 4, tn = (tid >> 4) * 4;
  const int nrow = t0 + br;
  float accA[4][4];
#pragma unroll
  for (int i = 0; i < 4; ++i)
#pragma unroll
    for (int j = 0; j < 4; ++j) accA[i][j] = 0.f;
  float sinv[16];

#pragma unroll
  for (int ph = 0; ph < 2; ++ph) {
    const int jb = ph * 64;
    {
      const float* qp = &q_silu[x_base + (size_t)br * 1024 + bj0];
      const float* kp = &k_rot[kr_base + (size_t)br * 128 + jb + bj0];
      float* qgo = &qg_out[kr_base + (size_t)br * 128 + jb + bj0];
#pragma unroll
      for (int u = 0; u < 4; ++u) {
        float4 q4 = *(const float4*)(qp + 4 * u);
        float4 k4 = *(const float4*)(kp + 4 * u);
        float qa[4] = {q4.x, q4.y, q4.z, q4.w};
        float ka[4] = {k4.x, k4.y, k4.z, k4.w};
        float qo[4];
#pragma unroll
        for (int e = 0; e < 4; ++e) {
          const int jl = bj0 + 4 * u + e;
          float tr;
          if (ph == 0) {
            const float freq = expf((float)jl * -0.28782313662425575f);
            float sv, cv;
            sincosf((float)nrow * freq, &sv, &cv);
            sinv[4 * u + e] = sv;
            tr = cv;
          } else {
            tr = sinv[4 * u + e];
          }
          const float g = Gs[br][jl];
          const float qgv = qa[e] * tr * expf(g);
          const float kgv = ka[e] * expf(-g);
          qgT[jl][br] = qgv;
          kgT[jl][br] = kgv;
          qo[e] = qgv;
        }
        float4 qo4;
        qo4.x = qo[0]; qo4.y = qo[1]; qo4.z = qo[2]; qo4.w = qo[3];
        *(float4*)(qgo + 4 * u) = qo4;
      }
    }
    __syncthreads();
#pragma unroll 4
    for (int jl = 0; jl < 64; ++jl) {
      float4 qa4 = *(const float4*)&qgT[jl][tm];
      float4 kb4 = *(const float4*)&kgT[jl][tn];
      float qa[4] = {qa4.x, qa4.y, qa4.z, qa4.w};
      float kb[4] = {kb4.x, kb4.y, kb4.z, kb4.w};
#pragma unroll
      for (int i = 0; i < 4; ++i)
#pragma unroll
        for (int jj = 0; jj < 4; ++jj) accA[i][jj] += qa[i] * kb[jj];
    }
    __syncthreads();
    {
      const int ss = tid >> 2, jl0 = (tid & 3) * 16;
      float tv[16];
#pragma unroll
      for (int e = 0; e < 16; ++e) tv[e] = kgT[jl0 + e][ss];
#pragma unroll
      for (int wv = 0; wv < 4; ++wv) {
        float4 t4;
        t4.x = tv[4 * wv]; t4.y = tv[4 * wv + 1]; t4.z = tv[4 * wv + 2]; t4.w = tv[4 * wv + 3];
        *(float4*)&qgT[ss][jl0 + 4 * wv] = t4;
      }
    }
    __syncthreads();
    {
      float accU[4][4];
#pragma unroll
      for (int i = 0; i < 4; ++i)
#pragma unroll
        for (int jj = 0; jj < 4; ++jj) accU[i][jj] = 0.f;
#pragma unroll 4
      for (int s = 0; s < 64; ++s) {
        ushort4 vv = *(const ushort4*)&v_sb[s][tm];
        float vf[4] = {bf2f(vv.x), bf2f(vv.y), bf2f(vv.z), bf2f(vv.w)};
        float4 kn4 = *(const float4*)&qgT[s][tn];
        float kn[4] = {kn4.x, kn4.y, kn4.z, kn4.w};
#pragma unroll
        for (int i = 0; i < 4; ++i)
#pragma unroll
          for (int jj = 0; jj < 4; ++jj) accU[i][jj] += vf[i] * kn[jj];
      }
      float es[4];
#pragma unroll
      for (int jj = 0; jj < 4; ++jj) es[jj] = glast_s[tn + jj];
#pragma unroll
      for (int i = 0; i < 4; ++i) {
        ushort4 pk;
        pk.x = f2bf(accU[i][0] * es[0]);
        pk.y = f2bf(accU[i][1] * es[1]);
        pk.z = f2bf(accU[i][2] * es[2]);
        pk.w = f2bf(accU[i][3] * es[3]);
        *(ushort4*)&U[((size_t)bid * 64 + tm + i) * 128 + jb + tn] = pk;
      }
    }
    __syncthreads();
  }
#pragma unroll
  for (int i = 0; i < 4; ++i)
#pragma unroll
    for (int jj = 0; jj < 4; ++jj) {
      const int cr = tm + i, ss = tn + jj;
      Gs[ss][cr] = (ss <= cr) ? accA[i][jj] : 0.f;
    }
  __syncthreads();
  {
    float acco[4][4];
#pragma unroll
    for (int i = 0; i < 4; ++i)
#pragma unroll
      for (int jj = 0; jj < 4; ++jj) acco[i][jj] = 0.f;
#pragma unroll 4
    for (int s = 0; s < 64; ++s) {
      float4 a4 = *(const float4*)&Gs[s][tm];
      float aa[4] = {a4.x, a4.y, a4.z, a4.w};
      ushort4 vv = *(const ushort4*)&v_sb[s][tn];
      float vf[4] = {bf2f(vv.x), bf2f(vv.y), bf2f(vv.z), bf2f(vv.w)};
#pragma unroll
      for (int i = 0; i < 4; ++i)
#pragma unroll
        for (int jj = 0; jj < 4; ++jj) acco[i][jj] += aa[i] * vf[jj];
    }
#pragma unroll
    for (int i = 0; i < 4; ++i) {
      float4 ov;
      ov.x = acco[i][0]; ov.y = acco[i][1]; ov.z = acco[i][2]; ov.w = acco[i][3];
      *(float4*)&o[x_base + (size_t)(tm + i) * 1024 + tn] = ov;
    }
  }
}

// ---------- GLA pass B ----------
__global__ __launch_bounds__(256) void gla_b(unsigned short* __restrict__ U,
                                             const float* __restrict__ glast_g) {
  const int t = blockIdx.x * 256 + threadIdx.x;
  const int j4 = t & 31;
  const int d = (t >> 5) & 63;
  const int bh = t >> 11;
  const int jj0 = (4 * j4) & 63;
  float s0 = 0.f, s1 = 0.f, s2 = 0.f, s3 = 0.f;
  for (int c = 0; c < 32; ++c) {
    const size_t ub = ((size_t)((bh * 32 + c) * 64 + d)) * 128 + 4 * j4;
    ushort4 uv = *(const ushort4*)&U[ub];
    float4 g4 = *(const float4*)&glast_g[(size_t)(bh * 32 + c) * 64 + jj0];
    ushort4 pv;
    pv.x = f2bf(s0); pv.y = f2bf(s1); pv.z = f2bf(s2); pv.w = f2bf(s3);
    *(ushort4*)&U[ub] = pv;
    s0 = s0 * expf(g4.x) + bf2f(uv.x);
    s1 = s1 * expf(g4.y) + bf2f(uv.y);
    s2 = s2 * expf(g4.z) + bf2f(uv.z);
    s3 = s3 * expf(g4.w) + bf2f(uv.w);
  }
}

// ---------- GLA pass C ----------
__global__ __launch_bounds__(256) void gla_c(const float* __restrict__ qg,
    const unsigned short* __restrict__ S, float* __restrict__ o) {
  __shared__ float qgT[64][68];
  __shared__ unsigned short sT[64][64];
  const int bid = blockIdx.x;
  const int bh = bid >> 5, c = bid & 31;
  const int b = bh >> 4, h = bh & 15;
  const int t0 = c * 64;
  const int tid = threadIdx.x;
  const size_t qg_base = ((size_t)bh * N_ + t0) * 128;
  const size_t o_base = ((size_t)(b * N_ + t0) * H_ + h) * 64;
  const size_t s_base = (size_t)bid * 64 * 128;
  const int br = tid >> 2, bj0 = (tid & 3) * 16;
  const int tm = (tid & 15) * 4, tn = (tid >> 4) * 4;
  const int sd = tid & 63, sg = (tid >> 6) * 16;
  float acc[4][4];
#pragma unroll
  for (int i = 0; i < 4; ++i)
#pragma unroll
    for (int j = 0; j < 4; ++j) acc[i][j] = 0.f;

#pragma unroll
  for (int ph = 0; ph < 2; ++ph) {
    const int jb = ph * 64;
    {
      const float* qp = &qg[qg_base + (size_t)br * 128 + jb + bj0];
#pragma unroll
      for (int u = 0; u < 4; ++u) {
        float4 q4 = *(const float4*)(qp + 4 * u);
        qgT[bj0 + 4 * u + 0][br] = q4.x;
        qgT[bj0 + 4 * u + 1][br] = q4.y;
        qgT[bj0 + 4 * u + 2][br] = q4.z;
        qgT[bj0 + 4 * u + 3][br] = q4.w;
      }
      const unsigned short* sp = &S[s_base + (size_t)sd * 128 + jb + sg];
      unsigned short tv[16];
      *(uint4*)&tv[0] = *(const uint4*)sp;
      *(uint4*)&tv[8] = *(const uint4*)(sp + 8);
#pragma unroll
      for (int e = 0; e < 16; ++e) sT[sg + e][sd] = tv[e];
    }
    __syncthreads();
#pragma unroll 4
    for (int jl = 0; jl < 64; ++jl) {
      float4 q4 = *(const float4*)&qgT[jl][tm];
      float qa[4] = {q4.x, q4.y, q4.z, q4.w};
      ushort4 sv = *(const ushort4*)&sT[jl][tn];
      float sf[4] = {bf2f(sv.x), bf2f(sv.y), bf2f(sv.z), bf2f(sv.w)};
#pragma unroll
      for (int i = 0; i < 4; ++i)
#pragma unroll
        for (int jj = 0; jj < 4; ++jj) acc[i][jj] += qa[i] * sf[jj];
    }
    __syncthreads();
  }
#pragma unroll
  for (int i = 0; i < 4; ++i) {
    float* op = &o[o_base + (size_t)(tm + i) * 1024 + tn];
    float4 ov = *(float4*)op;
    ov.x += acc[i][0]; ov.y += acc[i][1]; ov.z += acc[i][2]; ov.w += acc[i][3];
    *(float4*)op = ov;
  }
}

// ---------- fused gate * o + RMSNorm; writes bf16 for the final MFMA GEMM ----------
__global__ __launch_bounds__(256) void gate_norm_kernel(
    const float* __restrict__ x, const float* __restrict__ Wg1,
    const float* __restrict__ Wg2, const float* __restrict__ nw,
    const float* __restrict__ o, unsigned short* __restrict__ og) {
  const int row = blockIdx.x, tid = threadIdx.x;
  const int lane = tid & 63, wv = tid >> 6;
  __shared__ float redp[4][16];
  __shared__ float tg[16];
  __shared__ float rs[4];

  float4 xv = *(const float4*)&x[(size_t)row * D_ + tid * 4];
  float xa[4] = {xv.x, xv.y, xv.z, xv.w};
  float acc[16];
#pragma unroll
  for (int hh = 0; hh < 16; ++hh) acc[hh] = 0.f;
#pragma unroll
  for (int u = 0; u < 4; ++u) {
    const float* wr = &Wg1[(size_t)(tid * 4 + u) * 16];
    float wf[16];
    *(float4*)&wf[0]  = *(const float4*)(wr);
    *(float4*)&wf[4]  = *(const float4*)(wr + 4);
    *(float4*)&wf[8]  = *(const float4*)(wr + 8);
    *(float4*)&wf[12] = *(const float4*)(wr + 12);
#pragma unroll
    for (int hh = 0; hh < 16; ++hh) acc[hh] += xa[u] * wf[hh];
  }
#pragma unroll
  for (int hh = 0; hh < 16; ++hh) {
#pragma unroll
    for (int off = 32; off > 0; off >>= 1) acc[hh] += __shfl_xor(acc[hh], off);
  }
  if (lane == 0) {
#pragma unroll
    for (int hh = 0; hh < 16; ++hh) redp[wv][hh] = acc[hh];
  }
  __syncthreads();
  if (tid < 16) tg[tid] = redp[0][tid] + redp[1][tid] + redp[2][tid] + redp[3][tid];
  __syncthreads();

  float4 o4 = *(const float4*)&o[(size_t)row * D_ + tid * 4];
  float oa[4] = {o4.x, o4.y, o4.z, o4.w};
  float og4[4];
  float ssq = 0.f;
#pragma unroll
  for (int u = 0; u < 4; ++u) {
    const int d = tid * 4 + u;
    float sg = 0.f;
#pragma unroll
    for (int hh = 0; hh < 16; ++hh) sg += tg[hh] * Wg2[hh * 1024 + d];
    float gate = 1.f / (1.f + expf(-sg));
    og4[u] = oa[u] * gate;
    ssq += og4[u] * og4[u];
  }
#pragma unroll
  for (int off = 32; off > 0; off >>= 1) ssq += __shfl_xor(ssq, off);
  if (lane == 0) rs[wv] = ssq;
  __syncthreads();
  const float tot = rs[0] + rs[1] + rs[2] + rs[3];
  const float rinv = rsqrtf(tot * (1.f / 1024.f) + 1e-6f);
  ushort4 outv;
  outv.x = f2bf(og4[0] * rinv * nw[tid * 4 + 0]);
  outv.y = f2bf(og4[1] * rinv * nw[tid * 4 + 1]);
  outv.z = f2bf(og4[2] * rinv * nw[tid * 4 + 2]);
  outv.w = f2bf(og4[3] * rinv * nw[tid * 4 + 3]);
  *(ushort4*)&og[(size_t)row * D_ + tid * 4] = outv;
}

extern "C" void kernel_launch(void* const* d_in, const int* in_sizes, int n_in,
                              void* d_out, int out_size, void* d_ws, size_t ws_size,
                              hipStream_t stream) {
  const float* x   = (const float*)d_in[0];
  const float* Wq  = (const float*)d_in[1];
  const float* Wk  = (const float*)d_in[2];
  const float* Wv  = (const float*)d_in[3];
  const float* Wo  = (const float*)d_in[4];
  const float* Wg1 = (const float*)d_in[5];
  const float* Wg2 = (const float*)d_in[6];
  const float* nw  = (const float*)d_in[7];
  float* out = (float*)d_out;
  float* ws  = (float*)d_ws;

  // workspace layout (floats); P = B*N*D = 8,388,608 -> 8P floats = 268 MB
  const size_t P = (size_t)B_ * N_ * D_;
  float* k_raw = ws;            // [0,P); later U/S buffer (bf16, 2P elems)
  float* v_buf = ws + P;        // [P,2P)
  float* log_f = ws + 2 * P;    // [2P,3P); after gla_a: og_bf + Wo_p
  float* qg_buf = ws + 3 * P;   // [3P,5P): x_bf early, scan T/P, then qg
  float* k_rot = ws + 5 * P;    // [5P,7P): Wq/Wk/Wv packs early, then k_rot
  float* qs_o  = ws + 7 * P;    // q_silu, overwritten in-place by GLA output o

  unsigned short* U_buf = (unsigned short*)k_raw;
  unsigned short* x_bf  = (unsigned short*)(ws + 3 * P);        // P bf16 = [3P,3.5P)
  float* T_buf = ws + 4 * P;                                    // 4096x32
  float* P_buf = ws + 4 * P + 4096 * 32;
  unsigned short* og_bf = (unsigned short*)(ws + 2 * P);        // [2P,2.5P)
  unsigned short* Wo_p  = (unsigned short*)(ws + 2 * P + P / 2);// [2.5P,2.625P)
  unsigned short* Wq_p  = (unsigned short*)(ws + 5 * P);
  unsigned short* Wk_p  = Wq_p + 1024 * 1024;
  unsigned short* Wv_p  = Wk_p + 1024 * 1024;
  float* glast_g = (float*)d_out;  // dead before final gemm writes d_out

  const int M = B_ * N_;
  const int ggrid = (M / 128) * (D_ / 128);  // 512

  cast_x_bf16<<<(int)(P / 2048), 256, 0, stream>>>(x, x_bf);
  cast_w_pack<<<512, 256, 0, stream>>>(Wq, Wq_p);
  cast_w_pack<<<512, 256, 0, stream>>>(Wk, Wk_p);
  cast_w_pack<<<512, 256, 0, stream>>>(Wv, Wv_p);
  gemm_bf16<<<ggrid, 256, 0, stream>>>(x_bf, Wq_p, qs_o, M, D_, D_, 1);
  gemm_bf16<<<ggrid, 256, 0, stream>>>(x_bf, Wk_p, k_raw, M, D_, D_, 0);
  gemm_bf16<<<ggrid, 256, 0, stream>>>(x_bf, Wv_p, v_buf, M, D_, D_, 0);
  scan_pass_a<<<512, 256, 0, stream>>>(k_raw, T_buf);
  scan_pass_b<<<16, 256, 0, stream>>>(T_buf, P_buf);
  scan_pass_c<<<512, 256, 0, stream>>>(k_raw, P_buf, log_f, k_rot);
  gla_a<<<2048, 256, 0, stream>>>(qs_o, k_rot, log_f, v_buf, qg_buf, U_buf, qs_o, glast_g);
  cast_w_pack<<<512, 256, 0, stream>>>(Wo, Wo_p);  // log_f region now dead
  gla_b<<<512, 256, 0, stream>>>(U_buf, glast_g);
  gla_c<<<2048, 256, 0, stream>>>(qg_buf, U_buf, qs_o);
  gate_norm_kernel<<<M, 256, 0, stream>>>(x, Wg1, Wg2, nw, qs_o, og_bf);
  gemm_bf16<<<ggrid, 256, 0, stream>>>(og_bf, Wo_p, out, M, D_, D_, 0);
}

// Round 5
// 436.015 us; speedup vs baseline: 6.0090x; 1.3209x over previous
//
#include <hip/hip_runtime.h>
#include <hip/hip_bf16.h>
#include <math.h>

#define B_ 4
#define N_ 2048
#define D_ 1024
#define H_ 16
#define HD_ 64

typedef __attribute__((ext_vector_type(8))) short bf16x8;
typedef __attribute__((ext_vector_type(8))) unsigned short u16x8;
typedef __attribute__((ext_vector_type(4))) float f32x4;

#define AS1(p) ((const __attribute__((address_space(1))) void*)(p))
#define AS3(p) ((__attribute__((address_space(3))) void*)(p))

__device__ inline float bf2f(unsigned short u) { return __uint_as_float(((unsigned)u) << 16); }
__device__ inline unsigned short f2bf(float f) {
  unsigned u = __float_as_uint(f);
  return (unsigned short)((u + 0x7fffu + ((u >> 16) & 1u)) >> 16);
}
__device__ inline float lseop(float a, float b) {
  float mx = fmaxf(a, b), mn = fminf(a, b);
  return mx + log1pf(expf(mn - mx));
}

// ---------- cast x (f32) -> bf16 row-major ----------
__global__ __launch_bounds__(256) void cast_x_bf16(const float* __restrict__ x,
                                                   unsigned short* __restrict__ xb) {
  const int t = blockIdx.x * 256 + threadIdx.x;
  float4 a = ((const float4*)x)[(size_t)t * 2];
  float4 b = ((const float4*)x)[(size_t)t * 2 + 1];
  union { unsigned short u[8]; uint4 q; } pk;
  pk.u[0] = f2bf(a.x); pk.u[1] = f2bf(a.y); pk.u[2] = f2bf(a.z); pk.u[3] = f2bf(a.w);
  pk.u[4] = f2bf(b.x); pk.u[5] = f2bf(b.y); pk.u[6] = f2bf(b.z); pk.u[7] = f2bf(b.w);
  ((uint4*)xb)[t] = pk.q;
}

// ---------- cast W (f32 [1024][1024]) -> bf16 k-packed [(K/8)][N][8] ----------
__global__ __launch_bounds__(256) void cast_w_pack(const float* __restrict__ W,
                                                   unsigned short* __restrict__ Wp) {
  const int t = blockIdx.x * 256 + threadIdx.x;
  const int kg = t >> 10, n = t & 1023;
  union { unsigned short u[8]; uint4 q; } pk;
#pragma unroll
  for (int r = 0; r < 8; ++r)
    pk.u[r] = f2bf(W[(size_t)(kg * 8 + r) * 1024 + n]);
  *(uint4*)&Wp[((size_t)kg * 1024 + n) * 8] = pk.q;
}

// ---------- rope table: ropeT[n][j<64]=cos(n*f_j), [j>=64]=sin ----------
__global__ __launch_bounds__(256) void rope_fill(float* __restrict__ ropeT) {
  const int t = blockIdx.x * 256 + threadIdx.x;  // N*64
  const int n = t >> 6, hd = t & 63;
  const float freq = expf((float)hd * -0.28782313662425575f);
  float s, c;
  sincosf((float)n * freq, &s, &c);
  ropeT[(size_t)n * 128 + hd] = c;
  ropeT[(size_t)n * 128 + 64 + hd] = s;
}

// ---------- MFMA bf16 GEMM (m97 structure). mode 0: f32 out; 1: silu->bf16; 2: bf16
__global__ __launch_bounds__(256) void gemm_bf16(
    const unsigned short* __restrict__ A, const unsigned short* __restrict__ Wp,
    float* __restrict__ Cf, unsigned short* __restrict__ Cb,
    int M, int K, int Nn, int mode) {
  __shared__ unsigned short Asm[128 * 32];
  __shared__ unsigned short Bsm[4 * 128 * 8];

  const int tid = threadIdx.x;
  const int lane = tid & 63;
  const int w = tid >> 6;
  const int nb = Nn >> 7;
  const int nwg = gridDim.x;
  const int cpx = nwg >> 3;
  int bid = blockIdx.x;
  bid = (bid & 7) * cpx + (bid >> 3);
  const int by = bid / nb, bx = bid % nb;
  const int m0 = by * 128, n0 = bx * 128;
  const int wr = w >> 1, wc = w & 1;

  f32x4 acc[4][4];
#pragma unroll
  for (int i = 0; i < 4; ++i)
#pragma unroll
    for (int j = 0; j < 4; ++j) acc[i][j] = (f32x4){0.f, 0.f, 0.f, 0.f};

  const int rA0 = w * 16 + (lane >> 2);
  const int rA1 = (w + 4) * 16 + (lane >> 2);
  const int sA0 = (lane & 3) ^ ((rA0 >> 1) & 3);
  const int sA1 = (lane & 3) ^ ((rA1 >> 1) & 3);
  const unsigned short* gA0 = A + (size_t)(m0 + rA0) * K + sA0 * 8;
  const unsigned short* gA1 = A + (size_t)(m0 + rA1) * K + sA1 * 8;
  const unsigned short* gB0 = Wp + (size_t)(w >> 1) * Nn * 8 +
                              (size_t)(n0 + (w & 1) * 64 + lane) * 8;
  const unsigned short* gB1 = Wp + (size_t)((w + 4) >> 1) * Nn * 8 +
                              (size_t)(n0 + ((w + 4) & 1) * 64 + lane) * 8;

  int offA[4], offB[4];
#pragma unroll
  for (int m = 0; m < 4; ++m) {
    const int rowf = wr * 64 + m * 16 + (lane & 15);
    const int sp = (lane >> 4) ^ ((rowf >> 1) & 3);
    offA[m] = rowf * 32 + sp * 8;
  }
#pragma unroll
  for (int n = 0; n < 4; ++n) {
    const int colf = wc * 64 + n * 16 + (lane & 15);
    offB[n] = (lane >> 4) * 1024 + colf * 8;
  }

  for (int kt = 0; kt < K; kt += 32) {
    const size_t kB = (size_t)(kt >> 3) * Nn * 8;
    __builtin_amdgcn_global_load_lds(AS1(gA0 + kt), AS3(&Asm[w * 512]), 16, 0, 0);
    __builtin_amdgcn_global_load_lds(AS1(gA1 + kt), AS3(&Asm[(w + 4) * 512]), 16, 0, 0);
    __builtin_amdgcn_global_load_lds(AS1(gB0 + kB), AS3(&Bsm[w * 512]), 16, 0, 0);
    __builtin_amdgcn_global_load_lds(AS1(gB1 + kB), AS3(&Bsm[(w + 4) * 512]), 16, 0, 0);
    __syncthreads();
    bf16x8 af[4], bfr[4];
#pragma unroll
    for (int m = 0; m < 4; ++m) af[m] = *(const bf16x8*)&Asm[offA[m]];
#pragma unroll
    for (int n = 0; n < 4; ++n) bfr[n] = *(const bf16x8*)&Bsm[offB[n]];
#pragma unroll
    for (int m = 0; m < 4; ++m)
#pragma unroll
      for (int n = 0; n < 4; ++n)
        acc[m][n] = __builtin_amdgcn_mfma_f32_16x16x32_bf16(af[m], bfr[n], acc[m][n], 0, 0, 0);
    __syncthreads();
  }

  const int crow = (lane >> 4) * 4;
  const int ccol = lane & 15;
#pragma unroll
  for (int m = 0; m < 4; ++m)
#pragma unroll
    for (int n = 0; n < 4; ++n) {
#pragma unroll
      for (int r = 0; r < 4; ++r) {
        float vv = acc[m][n][r];
        const size_t idx = (size_t)(m0 + wr * 64 + m * 16 + crow + r) * Nn +
                           n0 + wc * 64 + n * 16 + ccol;
        if (mode == 0) {
          Cf[idx] = vv;
        } else {
          if (mode == 1) vv = vv / (1.f + expf(-vv));
          Cb[idx] = f2bf(vv);
        }
      }
    }
}

// ---------- 3-pass parallel cumlogsumexp scan ----------
__global__ __launch_bounds__(256) void scan_pass_a(const float* __restrict__ k_raw,
                                                   float* __restrict__ T) {
  const int g = blockIdx.x * 256 + threadIdx.x;
  const int hd = g & 63;
  const int c = (g >> 6) & 31;
  const int bh = g >> 11;
  const int b = bh >> 4, h = bh & 15;
  const size_t base = (size_t)b * N_ * D_ + (size_t)(c * 64) * D_ + h * HD_ + hd;
  float nxt = k_raw[base];
  float l = 0.f;
  for (int j = 0; j < 64; ++j) {
    float kr = nxt;
    if (j + 1 < 64) nxt = k_raw[base + (size_t)(j + 1) * D_];
    l = (j == 0) ? kr : lseop(l, kr);
  }
  T[(size_t)(bh * 64 + hd) * 32 + c] = l;
}

__global__ void scan_pass_b(const float* __restrict__ T, float* __restrict__ Pf) {
  const int ch = blockIdx.x * 256 + threadIdx.x;
  const float* t = &T[(size_t)ch * 32];
  float* p = &Pf[(size_t)ch * 32];
  float run = 0.f;
  for (int c = 0; c < 32; ++c) {
    p[c] = run;
    run = lseop(run, t[c]);
  }
}

// Pass C: emit G = P - z (f32), kg = exp(kr-P)*rot (bf16), glast.
__global__ __launch_bounds__(256) void scan_pass_c(const float* __restrict__ k_raw,
    const float* __restrict__ Pf, const float* __restrict__ ropeT,
    float* __restrict__ G_buf, unsigned short* __restrict__ kg_g,
    float* __restrict__ glast_g) {
  const int g = blockIdx.x * 256 + threadIdx.x;
  const int hd = g & 63;
  const int c = (g >> 6) & 31;
  const int bh = g >> 11;
  const int b = bh >> 4, h = bh & 15;
  const size_t base = (size_t)b * N_ * D_ + (size_t)(c * 64) * D_ + h * HD_ + hd;
  const size_t gb = ((size_t)bh * N_ + c * 64) * 64 + hd;
  const size_t kb = ((size_t)bh * N_ + c * 64) * 128 + hd;
  const float P = Pf[(size_t)(bh * 64 + hd) * 32 + c];
  float l = 0.f, G = 0.f;
  float nxt = k_raw[base];
  for (int r = 0; r < 64; ++r) {
    float kr = nxt;
    if (r + 1 < 64) nxt = k_raw[base + (size_t)(r + 1) * D_];
    l = (r == 0) ? kr : lseop(l, kr);
    float z = lseop(P, l);
    G = P - z;
    G_buf[gb + (size_t)r * 64] = G;
    float ke = expf(kr - P);
    float cv = ropeT[(size_t)(c * 64 + r) * 128 + hd];
    float sv = ropeT[(size_t)(c * 64 + r) * 128 + 64 + hd];
    kg_g[kb + (size_t)r * 128] = f2bf(ke * cv);
    kg_g[kb + (size_t)r * 128 + 64] = f2bf(ke * sv);
  }
  glast_g[(size_t)(bh * 32 + c) * 64 + hd] = G;
}

// ---------- GLA pass A (MFMA): A=masked(qg@kg^T), o_intra=A@v, U=(v^T@kg)*e^glast
__global__ __launch_bounds__(256) void gla_a(
    const unsigned short* __restrict__ qs, const unsigned short* __restrict__ kg_g,
    const float* __restrict__ G_buf, const unsigned short* __restrict__ v_bf,
    const float* __restrict__ ropeT, const float* __restrict__ glast_g,
    unsigned short* __restrict__ qg_p, unsigned short* __restrict__ U,
    float* __restrict__ o) {
  __shared__ unsigned short kg_l[64 * 128];   // [s][slot^(s&7)][8]; reused as U_l[d][128]
  __shared__ unsigned short kgT_l[128 * 72];  // [j][s]
  __shared__ unsigned short vT_l[64 * 72];    // [d][s]
  __shared__ unsigned short A_l[64 * 72];     // [c][s] masked

  const int bid = blockIdx.x;
  const int bh = bid >> 5, c = bid & 31;
  const int b = bh >> 4, h = bh & 15;
  const int t0 = c * 64;
  const int tid = threadIdx.x;
  const int lane = tid & 63, w = tid >> 6;
  const int lr = lane & 15, lg = lane >> 4;

  const size_t qv_base = ((size_t)(b * N_ + t0) * H_ + h) * 64;
  const size_t kg_base = ((size_t)bh * N_ + t0) * 128;

  // stage kg_l (swizzled), 16B chunks, coalesced
#pragma unroll
  for (int u = 0; u < 4; ++u) {
    const int flat = u * 256 + tid;
    const int r = flat >> 4, sl = flat & 15;
    u16x8 src = *(const u16x8*)&kg_g[kg_base + (size_t)r * 128 + sl * 8];
    *(u16x8*)&kg_l[r * 128 + ((sl ^ (r & 7)) * 8)] = src;
  }
  // stage vT_l
  {
    const int r = tid >> 2, d0 = (tid & 3) * 16;
    u16x8 a = *(const u16x8*)&v_bf[qv_base + (size_t)r * (H_ * 64) + d0];
    u16x8 b2 = *(const u16x8*)&v_bf[qv_base + (size_t)r * (H_ * 64) + d0 + 8];
#pragma unroll
    for (int e = 0; e < 8; ++e) {
      vT_l[(d0 + e) * 72 + r] = a[e];
      vT_l[(d0 + 8 + e) * 72 + r] = b2[e];
    }
  }
  __syncthreads();
  // build kgT_l from kg_l
  {
    const int j = tid >> 1, sh = (tid & 1) * 32;
#pragma unroll
    for (int u = 0; u < 4; ++u) {
      union { unsigned short us[8]; u16x8 v; } tv;
#pragma unroll
      for (int e = 0; e < 8; ++e) {
        const int s = sh + 8 * u + e;
        tv.us[e] = kg_l[s * 128 + (((j >> 3) ^ (s & 7)) * 8) + (j & 7)];
      }
      *(u16x8*)&kgT_l[j * 72 + sh + 8 * u] = tv.v;
    }
  }
  __syncthreads();

  // ---- qg build (in-fragment) + global qg_p store ----
  bf16x8 af[4];
  {
    const int r = 16 * w + lr;
#pragma unroll
    for (int ks = 0; ks < 4; ++ks) {
      const int jb = 32 * ks + 8 * lg;
      const int jq = jb & 63;
      u16x8 q8 = *(const u16x8*)&qs[qv_base + (size_t)r * (H_ * 64) + jq];
      float4 g0 = *(const float4*)&G_buf[((size_t)bh * N_ + t0 + r) * 64 + jq];
      float4 g1 = *(const float4*)&G_buf[((size_t)bh * N_ + t0 + r) * 64 + jq + 4];
      float4 r0 = *(const float4*)&ropeT[(size_t)(t0 + r) * 128 + jb];
      float4 r1 = *(const float4*)&ropeT[(size_t)(t0 + r) * 128 + jb + 4];
      float gg[8] = {g0.x, g0.y, g0.z, g0.w, g1.x, g1.y, g1.z, g1.w};
      float rr[8] = {r0.x, r0.y, r0.z, r0.w, r1.x, r1.y, r1.z, r1.w};
      union { unsigned short us[8]; bf16x8 v; u16x8 uv; } pk;
#pragma unroll
      for (int e = 0; e < 8; ++e)
        pk.us[e] = f2bf(bf2f(q8[e]) * rr[e] * expf(gg[e]));
      af[ks] = pk.v;
      *(u16x8*)&qg_p[((((size_t)bid * 4 + w) * 4 + ks) * 64 + lane) * 8] = pk.uv;
    }
  }
  // ---- m1: A = qg @ kg^T ----
  f32x4 acc1[4];
#pragma unroll
  for (int n = 0; n < 4; ++n) acc1[n] = (f32x4){0.f, 0.f, 0.f, 0.f};
#pragma unroll
  for (int n = 0; n < 4; ++n) {
    const int s = 16 * n + lr;
#pragma unroll
    for (int ks = 0; ks < 4; ++ks) {
      bf16x8 bk = *(const bf16x8*)&kg_l[s * 128 + (((lg + 4 * ks) ^ (s & 7)) * 8)];
      acc1[n] = __builtin_amdgcn_mfma_f32_16x16x32_bf16(af[ks], bk, acc1[n], 0, 0, 0);
    }
  }
  // masked A -> A_l (bf16)
#pragma unroll
  for (int n = 0; n < 4; ++n) {
    const int s = 16 * n + lr;
#pragma unroll
    for (int reg = 0; reg < 4; ++reg) {
      const int cr = 16 * w + 4 * lg + reg;
      A_l[cr * 72 + s] = (s <= cr) ? f2bf(acc1[n][reg]) : (unsigned short)0;
    }
  }
  // ---- m2: U^T-free: Urows d = v^T @ kg ----
  f32x4 acc2[8];
#pragma unroll
  for (int n = 0; n < 8; ++n) acc2[n] = (f32x4){0.f, 0.f, 0.f, 0.f};
#pragma unroll
  for (int ks = 0; ks < 2; ++ks) {
    const int s0 = 32 * ks + 8 * lg;
    bf16x8 av = *(const bf16x8*)&vT_l[(16 * w + lr) * 72 + s0];
#pragma unroll
    for (int n = 0; n < 8; ++n) {
      bf16x8 bk = *(const bf16x8*)&kgT_l[(16 * n + lr) * 72 + s0];
      acc2[n] = __builtin_amdgcn_mfma_f32_16x16x32_bf16(av, bk, acc2[n], 0, 0, 0);
    }
  }
  __syncthreads();
  // ---- phase D: U_l (=kg_l) writes; m3 = A @ v; o write ----
  float es[4];
#pragma unroll
  for (int n = 0; n < 4; ++n)
    es[n] = expf(glast_g[(size_t)bid * 64 + 16 * n + lr]);
#pragma unroll
  for (int n = 0; n < 8; ++n) {
    const int j = 16 * n + lr;
    const float e = es[n & 3];
#pragma unroll
    for (int reg = 0; reg < 4; ++reg)
      kg_l[(16 * w + 4 * lg + reg) * 128 + j] = f2bf(acc2[n][reg] * e);
  }
  f32x4 acc3[4];
#pragma unroll
  for (int n = 0; n < 4; ++n) acc3[n] = (f32x4){0.f, 0.f, 0.f, 0.f};
#pragma unroll
  for (int ks = 0; ks < 2; ++ks) {
    const int s0 = 32 * ks + 8 * lg;
    bf16x8 aA = *(const bf16x8*)&A_l[(16 * w + lr) * 72 + s0];
#pragma unroll
    for (int n = 0; n < 4; ++n) {
      bf16x8 bV = *(const bf16x8*)&vT_l[(16 * n + lr) * 72 + s0];
      acc3[n] = __builtin_amdgcn_mfma_f32_16x16x32_bf16(aA, bV, acc3[n], 0, 0, 0);
    }
  }
#pragma unroll
  for (int n = 0; n < 4; ++n)
#pragma unroll
    for (int reg = 0; reg < 4; ++reg)
      o[qv_base + (size_t)(16 * w + 4 * lg + reg) * (H_ * 64) + 16 * n + lr] = acc3[n][reg];
  __syncthreads();
  // ---- phase E: U_l -> global (coalesced) ----
#pragma unroll
  for (int u = 0; u < 4; ++u) {
    const int flat = u * 256 + tid;
    const int d = flat >> 4, sl = flat & 15;
    *(u16x8*)&U[((size_t)bid * 64 + d) * 128 + sl * 8] =
        *(const u16x8*)&kg_l[d * 128 + sl * 8];
  }
}

// ---------- GLA pass B: exclusive chunk scan (in place) ----------
__global__ __launch_bounds__(256) void gla_b(unsigned short* __restrict__ U,
                                             const float* __restrict__ glast_g) {
  const int t = blockIdx.x * 256 + threadIdx.x;
  const int j4 = t & 31;
  const int d = (t >> 5) & 63;
  const int bh = t >> 11;
  const int jj0 = (4 * j4) & 63;
  float s0 = 0.f, s1 = 0.f, s2 = 0.f, s3 = 0.f;
  for (int c = 0; c < 32; ++c) {
    const size_t ub = ((size_t)((bh * 32 + c) * 64 + d)) * 128 + 4 * j4;
    ushort4 uv = *(const ushort4*)&U[ub];
    float4 g4 = *(const float4*)&glast_g[(size_t)(bh * 32 + c) * 64 + jj0];
    ushort4 pv;
    pv.x = f2bf(s0); pv.y = f2bf(s1); pv.z = f2bf(s2); pv.w = f2bf(s3);
    *(ushort4*)&U[ub] = pv;
    s0 = s0 * expf(g4.x) + bf2f(uv.x);
    s1 = s1 * expf(g4.y) + bf2f(uv.y);
    s2 = s2 * expf(g4.z) + bf2f(uv.z);
    s3 = s3 * expf(g4.w) + bf2f(uv.w);
  }
}

// ---------- GLA pass C (MFMA): o += qg @ S_{c-1} ----------
__global__ __launch_bounds__(256) void gla_c(
    const unsigned short* __restrict__ qg_p, const unsigned short* __restrict__ S,
    float* __restrict__ o) {
  __shared__ unsigned short S_l[64 * 128];
  const int bid = blockIdx.x;
  const int bh = bid >> 5, c = bid & 31;
  const int b = bh >> 4, h = bh & 15;
  const int t0 = c * 64;
  const int tid = threadIdx.x;
  const int lane = tid & 63, w = tid >> 6;
  const int lr = lane & 15, lg = lane >> 4;
  const size_t s_base = (size_t)bid * 64 * 128;
  const size_t o_base = ((size_t)(b * N_ + t0) * H_ + h) * 64;

#pragma unroll
  for (int u = 0; u < 4; ++u) {
    const int flat = u * 256 + tid;
    const int d = flat >> 4, sl = flat & 15;
    u16x8 src = *(const u16x8*)&S[s_base + (size_t)d * 128 + sl * 8];
    *(u16x8*)&S_l[d * 128 + ((sl ^ (d & 7)) * 8)] = src;
  }
  __syncthreads();
  bf16x8 af[4];
#pragma unroll
  for (int ks = 0; ks < 4; ++ks)
    af[ks] = *(const bf16x8*)&qg_p[((((size_t)bid * 4 + w) * 4 + ks) * 64 + lane) * 8];
  f32x4 acc[4];
#pragma unroll
  for (int n = 0; n < 4; ++n) acc[n] = (f32x4){0.f, 0.f, 0.f, 0.f};
#pragma unroll
  for (int n = 0; n < 4; ++n) {
    const int d = 16 * n + lr;
#pragma unroll
    for (int ks = 0; ks < 4; ++ks) {
      bf16x8 bk = *(const bf16x8*)&S_l[d * 128 + (((lg + 4 * ks) ^ (d & 7)) * 8)];
      acc[n] = __builtin_amdgcn_mfma_f32_16x16x32_bf16(af[ks], bk, acc[n], 0, 0, 0);
    }
  }
#pragma unroll
  for (int n = 0; n < 4; ++n)
#pragma unroll
    for (int reg = 0; reg < 4; ++reg) {
      const size_t idx = o_base + (size_t)(16 * w + 4 * lg + reg) * (H_ * 64) + 16 * n + lr;
      o[idx] += acc[n][reg];
    }
}

// ---------- fused gate * o + RMSNorm; writes bf16 ----------
__global__ __launch_bounds__(256) void gate_norm_kernel(
    const float* __restrict__ x, const float* __restrict__ Wg1,
    const float* __restrict__ Wg2, const float* __restrict__ nw,
    const float* __restrict__ o, unsigned short* __restrict__ og) {
  const int row = blockIdx.x, tid = threadIdx.x;
  const int lane = tid & 63, wv = tid >> 6;
  __shared__ float redp[4][16];
  __shared__ float tg[16];
  __shared__ float rs[4];

  float4 xv = *(const float4*)&x[(size_t)row * D_ + tid * 4];
  float xa[4] = {xv.x, xv.y, xv.z, xv.w};
  float acc[16];
#pragma unroll
  for (int hh = 0; hh < 16; ++hh) acc[hh] = 0.f;
#pragma unroll
  for (int u = 0; u < 4; ++u) {
    const float* wr = &Wg1[(size_t)(tid * 4 + u) * 16];
    float wf[16];
    *(float4*)&wf[0]  = *(const float4*)(wr);
    *(float4*)&wf[4]  = *(const float4*)(wr + 4);
    *(float4*)&wf[8]  = *(const float4*)(wr + 8);
    *(float4*)&wf[12] = *(const float4*)(wr + 12);
#pragma unroll
    for (int hh = 0; hh < 16; ++hh) acc[hh] += xa[u] * wf[hh];
  }
#pragma unroll
  for (int hh = 0; hh < 16; ++hh) {
#pragma unroll
    for (int off = 32; off > 0; off >>= 1) acc[hh] += __shfl_xor(acc[hh], off);
  }
  if (lane == 0) {
#pragma unroll
    for (int hh = 0; hh < 16; ++hh) redp[wv][hh] = acc[hh];
  }
  __syncthreads();
  if (tid < 16) tg[tid] = redp[0][tid] + redp[1][tid] + redp[2][tid] + redp[3][tid];
  __syncthreads();

  float4 o4 = *(const float4*)&o[(size_t)row * D_ + tid * 4];
  float oa[4] = {o4.x, o4.y, o4.z, o4.w};
  float og4[4];
  float ssq = 0.f;
#pragma unroll
  for (int u = 0; u < 4; ++u) {
    const int d = tid * 4 + u;
    float sg = 0.f;
#pragma unroll
    for (int hh = 0; hh < 16; ++hh) sg += tg[hh] * Wg2[hh * 1024 + d];
    float gate = 1.f / (1.f + expf(-sg));
    og4[u] = oa[u] * gate;
    ssq += og4[u] * og4[u];
  }
#pragma unroll
  for (int off = 32; off > 0; off >>= 1) ssq += __shfl_xor(ssq, off);
  if (lane == 0) rs[wv] = ssq;
  __syncthreads();
  const float tot = rs[0] + rs[1] + rs[2] + rs[3];
  const float rinv = rsqrtf(tot * (1.f / 1024.f) + 1e-6f);
  ushort4 outv;
  outv.x = f2bf(og4[0] * rinv * nw[tid * 4 + 0]);
  outv.y = f2bf(og4[1] * rinv * nw[tid * 4 + 1]);
  outv.z = f2bf(og4[2] * rinv * nw[tid * 4 + 2]);
  outv.w = f2bf(og4[3] * rinv * nw[tid * 4 + 3]);
  *(ushort4*)&og[(size_t)row * D_ + tid * 4] = outv;
}

extern "C" void kernel_launch(void* const* d_in, const int* in_sizes, int n_in,
                              void* d_out, int out_size, void* d_ws, size_t ws_size,
                              hipStream_t stream) {
  const float* x   = (const float*)d_in[0];
  const float* Wq  = (const float*)d_in[1];
  const float* Wk  = (const float*)d_in[2];
  const float* Wv  = (const float*)d_in[3];
  const float* Wo  = (const float*)d_in[4];
  const float* Wg1 = (const float*)d_in[5];
  const float* Wg2 = (const float*)d_in[6];
  const float* nw  = (const float*)d_in[7];
  float* out = (float*)d_out;
  float* ws  = (float*)d_ws;

  const size_t P = (size_t)B_ * N_ * D_;  // 8,388,608
  float* k_raw = ws;                        // [0,P); after scan: U_buf (bf16 2P elems)
  float* o_buf = ws + P;                    // [P,2P)
  float* G_buf = ws + 2 * P;                // [2P,3P)
  unsigned short* qg_p = (unsigned short*)(ws + 3 * P);   // 2P elems
  unsigned short* kg_g = (unsigned short*)(ws + 4 * P);   // 2P elems
  unsigned short* v_bf = (unsigned short*)(ws + 5 * P);            // P elems
  unsigned short* q_bf = (unsigned short*)(ws + 5 * P + P / 2);    // P elems
  float* ropeT = ws + 6 * P;                                       // 262144
  float* T_buf = ws + 6 * P + 524288;                              // 131072
  float* P_buf = T_buf + 131072;                                   // 131072
  unsigned short* x_bf = (unsigned short*)(ws + 13 * P / 2);       // P elems
  unsigned short* og_bf = x_bf;  // x_bf dead before gate_norm writes og
  unsigned short* Wq_p = (unsigned short*)(ws + 7 * P);
  unsigned short* Wk_p = Wq_p + 1048576;
  unsigned short* Wv_p = Wk_p + 1048576;
  unsigned short* Wo_p = Wv_p + 1048576;
  float* glast_g = ws + 7 * P + 2097152;                           // 131072
  unsigned short* U_buf = (unsigned short*)k_raw;

  const int M = B_ * N_;
  const int ggrid = (M / 128) * (D_ / 128);  // 512

  cast_x_bf16<<<(int)(P / 2048), 256, 0, stream>>>(x, x_bf);
  rope_fill<<<512, 256, 0, stream>>>(ropeT);
  cast_w_pack<<<512, 256, 0, stream>>>(Wq, Wq_p);
  cast_w_pack<<<512, 256, 0, stream>>>(Wk, Wk_p);
  cast_w_pack<<<512, 256, 0, stream>>>(Wv, Wv_p);
  cast_w_pack<<<512, 256, 0, stream>>>(Wo, Wo_p);
  gemm_bf16<<<ggrid, 256, 0, stream>>>(x_bf, Wq_p, nullptr, q_bf, M, D_, D_, 1);
  gemm_bf16<<<ggrid, 256, 0, stream>>>(x_bf, Wk_p, k_raw, nullptr, M, D_, D_, 0);
  gemm_bf16<<<ggrid, 256, 0, stream>>>(x_bf, Wv_p, nullptr, v_bf, M, D_, D_, 2);
  scan_pass_a<<<512, 256, 0, stream>>>(k_raw, T_buf);
  scan_pass_b<<<16, 256, 0, stream>>>(T_buf, P_buf);
  scan_pass_c<<<512, 256, 0, stream>>>(k_raw, P_buf, ropeT, G_buf, kg_g, glast_g);
  gla_a<<<2048, 256, 0, stream>>>(q_bf, kg_g, G_buf, v_bf, ropeT, glast_g, qg_p, U_buf, o_buf);
  gla_b<<<512, 256, 0, stream>>>(U_buf, glast_g);
  gla_c<<<2048, 256, 0, stream>>>(qg_p, U_buf, o_buf);
  gate_norm_kernel<<<M, 256, 0, stream>>>(x, Wg1, Wg2, nw, o_buf, og_bf);
  gemm_bf16<<<ggrid, 256, 0, stream>>>(og_bf, Wo_p, out, nullptr, M, D_, D_, 0);
}

// Round 6
// 385.493 us; speedup vs baseline: 6.7965x; 1.1311x over previous
//
#include <hip/hip_runtime.h>
#include <hip/hip_bf16.h>
#include <math.h>

#define B_ 4
#define N_ 2048
#define D_ 1024
#define H_ 16
#define HD_ 64

typedef __attribute__((ext_vector_type(8))) short bf16x8;
typedef __attribute__((ext_vector_type(8))) unsigned short u16x8;
typedef __attribute__((ext_vector_type(4))) float f32x4;

#define AS1(p) ((const __attribute__((address_space(1))) void*)(p))
#define AS3(p) ((__attribute__((address_space(3))) void*)(p))

__device__ inline float bf2f(unsigned short u) { return __uint_as_float(((unsigned)u) << 16); }
__device__ inline unsigned short f2bf(float f) {
  unsigned u = __float_as_uint(f);
  return (unsigned short)((u + 0x7fffu + ((u >> 16) & 1u)) >> 16);
}
__device__ inline float lseop(float a, float b) {
  float mx = fmaxf(a, b), mn = fminf(a, b);
  return mx + log1pf(expf(mn - mx));
}

// ---------- cast x (f32) -> bf16 row-major ----------
__global__ __launch_bounds__(256) void cast_x_bf16(const float* __restrict__ x,
                                                   unsigned short* __restrict__ xb) {
  const int t = blockIdx.x * 256 + threadIdx.x;
  float4 a = ((const float4*)x)[(size_t)t * 2];
  float4 b = ((const float4*)x)[(size_t)t * 2 + 1];
  union { unsigned short u[8]; uint4 q; } pk;
  pk.u[0] = f2bf(a.x); pk.u[1] = f2bf(a.y); pk.u[2] = f2bf(a.z); pk.u[3] = f2bf(a.w);
  pk.u[4] = f2bf(b.x); pk.u[5] = f2bf(b.y); pk.u[6] = f2bf(b.z); pk.u[7] = f2bf(b.w);
  ((uint4*)xb)[t] = pk.q;
}

// ---------- cast W (f32 [1024][1024]) -> bf16 k-packed [(K/8)][N][8] ----------
__global__ __launch_bounds__(256) void cast_w_pack(const float* __restrict__ W,
                                                   unsigned short* __restrict__ Wp) {
  const int t = blockIdx.x * 256 + threadIdx.x;
  const int kg = t >> 10, n = t & 1023;
  union { unsigned short u[8]; uint4 q; } pk;
#pragma unroll
  for (int r = 0; r < 8; ++r)
    pk.u[r] = f2bf(W[(size_t)(kg * 8 + r) * 1024 + n]);
  *(uint4*)&Wp[((size_t)kg * 1024 + n) * 8] = pk.q;
}

// ---------- pack Wg1 (f32 [1024][16]) -> bf16 [(K/8)][16][8] ----------
__global__ __launch_bounds__(256) void pack_wg1(const float* __restrict__ Wg1,
                                                unsigned short* __restrict__ Wp) {
  const int t = blockIdx.x * 256 + threadIdx.x;  // 2048 = 128 kg * 16 hh
  const int kg = t >> 4, hh = t & 15;
  union { unsigned short us[8]; u16x8 v; } pk;
#pragma unroll
  for (int r = 0; r < 8; ++r)
    pk.us[r] = f2bf(Wg1[(size_t)(kg * 8 + r) * 16 + hh]);
  *(u16x8*)&Wp[((size_t)kg * 16 + hh) * 8] = pk.v;
}

// ---------- gate logits: tg[M][16] = x_bf @ Wg1_bf (MFMA) ----------
__global__ __launch_bounds__(256) void gate_logits(
    const unsigned short* __restrict__ x_bf, const unsigned short* __restrict__ Wg1p,
    float* __restrict__ tg) {
  __shared__ unsigned short Wl[128 * 16 * 8];  // 32 KB
  const int tid = threadIdx.x;
  const int lane = tid & 63, w = tid >> 6;
  const int lr = lane & 15, lg = lane >> 4;
#pragma unroll
  for (int u = 0; u < 8; ++u) {
    const int flat = u * 256 + tid;
    *(u16x8*)&Wl[flat * 8] = *(const u16x8*)&Wg1p[(size_t)flat * 8];
  }
  __syncthreads();
  const int row = blockIdx.x * 64 + w * 16 + lr;
  f32x4 acc = (f32x4){0.f, 0.f, 0.f, 0.f};
  for (int ks = 0; ks < 32; ++ks) {
    bf16x8 a = *(const bf16x8*)&x_bf[(size_t)row * 1024 + ks * 32 + lg * 8];
    bf16x8 b = *(const bf16x8*)&Wl[((ks * 4 + lg) * 16 + lr) * 8];
    acc = __builtin_amdgcn_mfma_f32_16x16x32_bf16(a, b, acc, 0, 0, 0);
  }
  const int orow = blockIdx.x * 64 + w * 16 + 4 * lg;
#pragma unroll
  for (int reg = 0; reg < 4; ++reg)
    tg[(size_t)(orow + reg) * 16 + lr] = acc[reg];
}

// ---------- rope table: ropeT[n][j<64]=cos(n*f_j), [j>=64]=sin ----------
__global__ __launch_bounds__(256) void rope_fill(float* __restrict__ ropeT) {
  const int t = blockIdx.x * 256 + threadIdx.x;  // N*64
  const int n = t >> 6, hd = t & 63;
  const float freq = expf((float)hd * -0.28782313662425575f);
  float s, c;
  sincosf((float)n * freq, &s, &c);
  ropeT[(size_t)n * 128 + hd] = c;
  ropeT[(size_t)n * 128 + 64 + hd] = s;
}

// ---------- MFMA bf16 GEMM (m97 structure). mode 0: f32 out; 1: silu->bf16; 2: bf16
__global__ __launch_bounds__(256) void gemm_bf16(
    const unsigned short* __restrict__ A, const unsigned short* __restrict__ Wp,
    float* __restrict__ Cf, unsigned short* __restrict__ Cb,
    int M, int K, int Nn, int mode) {
  __shared__ unsigned short Asm[128 * 32];
  __shared__ unsigned short Bsm[4 * 128 * 8];

  const int tid = threadIdx.x;
  const int lane = tid & 63;
  const int w = tid >> 6;
  const int nb = Nn >> 7;
  const int nwg = gridDim.x;
  const int cpx = nwg >> 3;
  int bid = blockIdx.x;
  bid = (bid & 7) * cpx + (bid >> 3);
  const int by = bid / nb, bx = bid % nb;
  const int m0 = by * 128, n0 = bx * 128;
  const int wr = w >> 1, wc = w & 1;

  f32x4 acc[4][4];
#pragma unroll
  for (int i = 0; i < 4; ++i)
#pragma unroll
    for (int j = 0; j < 4; ++j) acc[i][j] = (f32x4){0.f, 0.f, 0.f, 0.f};

  const int rA0 = w * 16 + (lane >> 2);
  const int rA1 = (w + 4) * 16 + (lane >> 2);
  const int sA0 = (lane & 3) ^ ((rA0 >> 1) & 3);
  const int sA1 = (lane & 3) ^ ((rA1 >> 1) & 3);
  const unsigned short* gA0 = A + (size_t)(m0 + rA0) * K + sA0 * 8;
  const unsigned short* gA1 = A + (size_t)(m0 + rA1) * K + sA1 * 8;
  const unsigned short* gB0 = Wp + (size_t)(w >> 1) * Nn * 8 +
                              (size_t)(n0 + (w & 1) * 64 + lane) * 8;
  const unsigned short* gB1 = Wp + (size_t)((w + 4) >> 1) * Nn * 8 +
                              (size_t)(n0 + ((w + 4) & 1) * 64 + lane) * 8;

  int offA[4], offB[4];
#pragma unroll
  for (int m = 0; m < 4; ++m) {
    const int rowf = wr * 64 + m * 16 + (lane & 15);
    const int sp = (lane >> 4) ^ ((rowf >> 1) & 3);
    offA[m] = rowf * 32 + sp * 8;
  }
#pragma unroll
  for (int n = 0; n < 4; ++n) {
    const int colf = wc * 64 + n * 16 + (lane & 15);
    offB[n] = (lane >> 4) * 1024 + colf * 8;
  }

  for (int kt = 0; kt < K; kt += 32) {
    const size_t kB = (size_t)(kt >> 3) * Nn * 8;
    __builtin_amdgcn_global_load_lds(AS1(gA0 + kt), AS3(&Asm[w * 512]), 16, 0, 0);
    __builtin_amdgcn_global_load_lds(AS1(gA1 + kt), AS3(&Asm[(w + 4) * 512]), 16, 0, 0);
    __builtin_amdgcn_global_load_lds(AS1(gB0 + kB), AS3(&Bsm[w * 512]), 16, 0, 0);
    __builtin_amdgcn_global_load_lds(AS1(gB1 + kB), AS3(&Bsm[(w + 4) * 512]), 16, 0, 0);
    __syncthreads();
    bf16x8 af[4], bfr[4];
#pragma unroll
    for (int m = 0; m < 4; ++m) af[m] = *(const bf16x8*)&Asm[offA[m]];
#pragma unroll
    for (int n = 0; n < 4; ++n) bfr[n] = *(const bf16x8*)&Bsm[offB[n]];
#pragma unroll
    for (int m = 0; m < 4; ++m)
#pragma unroll
      for (int n = 0; n < 4; ++n)
        acc[m][n] = __builtin_amdgcn_mfma_f32_16x16x32_bf16(af[m], bfr[n], acc[m][n], 0, 0, 0);
    __syncthreads();
  }

  const int crow = (lane >> 4) * 4;
  const int ccol = lane & 15;
#pragma unroll
  for (int m = 0; m < 4; ++m)
#pragma unroll
    for (int n = 0; n < 4; ++n) {
#pragma unroll
      for (int r = 0; r < 4; ++r) {
        float vv = acc[m][n][r];
        const size_t idx = (size_t)(m0 + wr * 64 + m * 16 + crow + r) * Nn +
                           n0 + wc * 64 + n * 16 + ccol;
        if (mode == 0) {
          Cf[idx] = vv;
        } else {
          if (mode == 1) vv = vv / (1.f + expf(-vv));
          Cb[idx] = f2bf(vv);
        }
      }
    }
}

// ---------- 3-pass parallel cumlogsumexp scan ----------
__global__ __launch_bounds__(256) void scan_pass_a(const float* __restrict__ k_raw,
                                                   float* __restrict__ T) {
  const int g = blockIdx.x * 256 + threadIdx.x;
  const int hd = g & 63;
  const int c = (g >> 6) & 31;
  const int bh = g >> 11;
  const int b = bh >> 4, h = bh & 15;
  const size_t base = (size_t)b * N_ * D_ + (size_t)(c * 64) * D_ + h * HD_ + hd;
  float nxt = k_raw[base];
  float l = 0.f;
  for (int j = 0; j < 64; ++j) {
    float kr = nxt;
    if (j + 1 < 64) nxt = k_raw[base + (size_t)(j + 1) * D_];
    l = (j == 0) ? kr : lseop(l, kr);
  }
  T[(size_t)(bh * 64 + hd) * 32 + c] = l;
}

__global__ void scan_pass_b(const float* __restrict__ T, float* __restrict__ Pf) {
  const int ch = blockIdx.x * 256 + threadIdx.x;
  const float* t = &T[(size_t)ch * 32];
  float* p = &Pf[(size_t)ch * 32];
  float run = 0.f;
  for (int c = 0; c < 32; ++c) {
    p[c] = run;
    run = lseop(run, t[c]);
  }
}

// Pass C: emit G = P - z (f32), kg = exp(kr-P)*rot (bf16), glast.
__global__ __launch_bounds__(256) void scan_pass_c(const float* __restrict__ k_raw,
    const float* __restrict__ Pf, const float* __restrict__ ropeT,
    float* __restrict__ G_buf, unsigned short* __restrict__ kg_g,
    float* __restrict__ glast_g) {
  const int g = blockIdx.x * 256 + threadIdx.x;
  const int hd = g & 63;
  const int c = (g >> 6) & 31;
  const int bh = g >> 11;
  const int b = bh >> 4, h = bh & 15;
  const size_t base = (size_t)b * N_ * D_ + (size_t)(c * 64) * D_ + h * HD_ + hd;
  const size_t gb = ((size_t)bh * N_ + c * 64) * 64 + hd;
  const size_t kb = ((size_t)bh * N_ + c * 64) * 128 + hd;
  const float P = Pf[(size_t)(bh * 64 + hd) * 32 + c];
  float l = 0.f, G = 0.f;
  float nxt = k_raw[base];
  for (int r = 0; r < 64; ++r) {
    float kr = nxt;
    if (r + 1 < 64) nxt = k_raw[base + (size_t)(r + 1) * D_];
    l = (r == 0) ? kr : lseop(l, kr);
    float z = lseop(P, l);
    G = P - z;
    G_buf[gb + (size_t)r * 64] = G;
    float ke = expf(kr - P);
    float cv = ropeT[(size_t)(c * 64 + r) * 128 + hd];
    float sv = ropeT[(size_t)(c * 64 + r) * 128 + 64 + hd];
    kg_g[kb + (size_t)r * 128] = f2bf(ke * cv);
    kg_g[kb + (size_t)r * 128 + 64] = f2bf(ke * sv);
  }
  glast_g[(size_t)(bh * 32 + c) * 64 + hd] = G;
}

// ---------- GLA pass A (MFMA): A=masked(qg@kg^T), o_intra=A@v, U=(v^T@kg)*e^glast
__global__ __launch_bounds__(256) void gla_a(
    const unsigned short* __restrict__ qs, const unsigned short* __restrict__ kg_g,
    const float* __restrict__ G_buf, const unsigned short* __restrict__ v_bf,
    const float* __restrict__ ropeT, const float* __restrict__ glast_g,
    unsigned short* __restrict__ qg_p, unsigned short* __restrict__ U,
    float* __restrict__ o) {
  __shared__ unsigned short kg_l[64 * 128];   // [s][slot^(s&7)][8]; reused as U_l[d][128]
  __shared__ unsigned short kgT_l[128 * 72];  // [j][s]
  __shared__ unsigned short vT_l[64 * 72];    // [d][s]
  __shared__ unsigned short A_l[64 * 72];     // [c][s] masked

  const int bid = blockIdx.x;
  const int bh = bid >> 5, c = bid & 31;
  const int b = bh >> 4, h = bh & 15;
  const int t0 = c * 64;
  const int tid = threadIdx.x;
  const int lane = tid & 63, w = tid >> 6;
  const int lr = lane & 15, lg = lane >> 4;

  const size_t qv_base = ((size_t)(b * N_ + t0) * H_ + h) * 64;
  const size_t kg_base = ((size_t)bh * N_ + t0) * 128;

  // stage kg_l (swizzled), 16B chunks, coalesced
#pragma unroll
  for (int u = 0; u < 4; ++u) {
    const int flat = u * 256 + tid;
    const int r = flat >> 4, sl = flat & 15;
    u16x8 src = *(const u16x8*)&kg_g[kg_base + (size_t)r * 128 + sl * 8];
    *(u16x8*)&kg_l[r * 128 + ((sl ^ (r & 7)) * 8)] = src;
  }
  // stage vT_l
  {
    const int r = tid >> 2, d0 = (tid & 3) * 16;
    u16x8 a = *(const u16x8*)&v_bf[qv_base + (size_t)r * (H_ * 64) + d0];
    u16x8 b2 = *(const u16x8*)&v_bf[qv_base + (size_t)r * (H_ * 64) + d0 + 8];
#pragma unroll
    for (int e = 0; e < 8; ++e) {
      vT_l[(d0 + e) * 72 + r] = a[e];
      vT_l[(d0 + 8 + e) * 72 + r] = b2[e];
    }
  }
  __syncthreads();
  // build kgT_l from kg_l
  {
    const int j = tid >> 1, sh = (tid & 1) * 32;
#pragma unroll
    for (int u = 0; u < 4; ++u) {
      union { unsigned short us[8]; u16x8 v; } tv;
#pragma unroll
      for (int e = 0; e < 8; ++e) {
        const int s = sh + 8 * u + e;
        tv.us[e] = kg_l[s * 128 + (((j >> 3) ^ (s & 7)) * 8) + (j & 7)];
      }
      *(u16x8*)&kgT_l[j * 72 + sh + 8 * u] = tv.v;
    }
  }
  __syncthreads();

  // ---- qg build (in-fragment) + global qg_p store ----
  bf16x8 af[4];
  {
    const int r = 16 * w + lr;
#pragma unroll
    for (int ks = 0; ks < 4; ++ks) {
      const int jb = 32 * ks + 8 * lg;
      const int jq = jb & 63;
      u16x8 q8 = *(const u16x8*)&qs[qv_base + (size_t)r * (H_ * 64) + jq];
      float4 g0 = *(const float4*)&G_buf[((size_t)bh * N_ + t0 + r) * 64 + jq];
      float4 g1 = *(const float4*)&G_buf[((size_t)bh * N_ + t0 + r) * 64 + jq + 4];
      float4 r0 = *(const float4*)&ropeT[(size_t)(t0 + r) * 128 + jb];
      float4 r1 = *(const float4*)&ropeT[(size_t)(t0 + r) * 128 + jb + 4];
      float gg[8] = {g0.x, g0.y, g0.z, g0.w, g1.x, g1.y, g1.z, g1.w};
      float rr[8] = {r0.x, r0.y, r0.z, r0.w, r1.x, r1.y, r1.z, r1.w};
      union { unsigned short us[8]; bf16x8 v; u16x8 uv; } pk;
#pragma unroll
      for (int e = 0; e < 8; ++e)
        pk.us[e] = f2bf(bf2f(q8[e]) * rr[e] * expf(gg[e]));
      af[ks] = pk.v;
      *(u16x8*)&qg_p[((((size_t)bid * 4 + w) * 4 + ks) * 64 + lane) * 8] = pk.uv;
    }
  }
  // ---- m1: A = qg @ kg^T ----
  f32x4 acc1[4];
#pragma unroll
  for (int n = 0; n < 4; ++n) acc1[n] = (f32x4){0.f, 0.f, 0.f, 0.f};
#pragma unroll
  for (int n = 0; n < 4; ++n) {
    const int s = 16 * n + lr;
#pragma unroll
    for (int ks = 0; ks < 4; ++ks) {
      bf16x8 bk = *(const bf16x8*)&kg_l[s * 128 + (((lg + 4 * ks) ^ (s & 7)) * 8)];
      acc1[n] = __builtin_amdgcn_mfma_f32_16x16x32_bf16(af[ks], bk, acc1[n], 0, 0, 0);
    }
  }
  // masked A -> A_l (bf16)
#pragma unroll
  for (int n = 0; n < 4; ++n) {
    const int s = 16 * n + lr;
#pragma unroll
    for (int reg = 0; reg < 4; ++reg) {
      const int cr = 16 * w + 4 * lg + reg;
      A_l[cr * 72 + s] = (s <= cr) ? f2bf(acc1[n][reg]) : (unsigned short)0;
    }
  }
  // ---- m2: U^T-free: Urows d = v^T @ kg ----
  f32x4 acc2[8];
#pragma unroll
  for (int n = 0; n < 8; ++n) acc2[n] = (f32x4){0.f, 0.f, 0.f, 0.f};
#pragma unroll
  for (int ks = 0; ks < 2; ++ks) {
    const int s0 = 32 * ks + 8 * lg;
    bf16x8 av = *(const bf16x8*)&vT_l[(16 * w + lr) * 72 + s0];
#pragma unroll
    for (int n = 0; n < 8; ++n) {
      bf16x8 bk = *(const bf16x8*)&kgT_l[(16 * n + lr) * 72 + s0];
      acc2[n] = __builtin_amdgcn_mfma_f32_16x16x32_bf16(av, bk, acc2[n], 0, 0, 0);
    }
  }
  __syncthreads();
  // ---- phase D: U_l (=kg_l) writes; m3 = A @ v; o write ----
  float es[4];
#pragma unroll
  for (int n = 0; n < 4; ++n)
    es[n] = expf(glast_g[(size_t)bid * 64 + 16 * n + lr]);
#pragma unroll
  for (int n = 0; n < 8; ++n) {
    const int j = 16 * n + lr;
    const float e = es[n & 3];
#pragma unroll
    for (int reg = 0; reg < 4; ++reg)
      kg_l[(16 * w + 4 * lg + reg) * 128 + j] = f2bf(acc2[n][reg] * e);
  }
  f32x4 acc3[4];
#pragma unroll
  for (int n = 0; n < 4; ++n) acc3[n] = (f32x4){0.f, 0.f, 0.f, 0.f};
#pragma unroll
  for (int ks = 0; ks < 2; ++ks) {
    const int s0 = 32 * ks + 8 * lg;
    bf16x8 aA = *(const bf16x8*)&A_l[(16 * w + lr) * 72 + s0];
#pragma unroll
    for (int n = 0; n < 4; ++n) {
      bf16x8 bV = *(const bf16x8*)&vT_l[(16 * n + lr) * 72 + s0];
      acc3[n] = __builtin_amdgcn_mfma_f32_16x16x32_bf16(aA, bV, acc3[n], 0, 0, 0);
    }
  }
#pragma unroll
  for (int n = 0; n < 4; ++n)
#pragma unroll
    for (int reg = 0; reg < 4; ++reg)
      o[qv_base + (size_t)(16 * w + 4 * lg + reg) * (H_ * 64) + 16 * n + lr] = acc3[n][reg];
  __syncthreads();
  // ---- phase E: U_l -> global (coalesced) ----
#pragma unroll
  for (int u = 0; u < 4; ++u) {
    const int flat = u * 256 + tid;
    const int d = flat >> 4, sl = flat & 15;
    *(u16x8*)&U[((size_t)bid * 64 + d) * 128 + sl * 8] =
        *(const u16x8*)&kg_l[d * 128 + sl * 8];
  }
}

// ---------- GLA pass B: exclusive chunk scan (in place) ----------
__global__ __launch_bounds__(256) void gla_b(unsigned short* __restrict__ U,
                                             const float* __restrict__ glast_g) {
  const int t = blockIdx.x * 256 + threadIdx.x;
  const int j4 = t & 31;
  const int d = (t >> 5) & 63;
  const int bh = t >> 11;
  const int jj0 = (4 * j4) & 63;
  float s0 = 0.f, s1 = 0.f, s2 = 0.f, s3 = 0.f;
  for (int c = 0; c < 32; ++c) {
    const size_t ub = ((size_t)((bh * 32 + c) * 64 + d)) * 128 + 4 * j4;
    ushort4 uv = *(const ushort4*)&U[ub];
    float4 g4 = *(const float4*)&glast_g[(size_t)(bh * 32 + c) * 64 + jj0];
    ushort4 pv;
    pv.x = f2bf(s0); pv.y = f2bf(s1); pv.z = f2bf(s2); pv.w = f2bf(s3);
    *(ushort4*)&U[ub] = pv;
    s0 = s0 * expf(g4.x) + bf2f(uv.x);
    s1 = s1 * expf(g4.y) + bf2f(uv.y);
    s2 = s2 * expf(g4.z) + bf2f(uv.z);
    s3 = s3 * expf(g4.w) + bf2f(uv.w);
  }
}

// ---------- GLA pass C (MFMA): o += qg @ S_{c-1} ----------
__global__ __launch_bounds__(256) void gla_c(
    const unsigned short* __restrict__ qg_p, const unsigned short* __restrict__ S,
    float* __restrict__ o) {
  __shared__ unsigned short S_l[64 * 128];
  const int bid = blockIdx.x;
  const int bh = bid >> 5, c = bid & 31;
  const int b = bh >> 4, h = bh & 15;
  const int t0 = c * 64;
  const int tid = threadIdx.x;
  const int lane = tid & 63, w = tid >> 6;
  const int lr = lane & 15, lg = lane >> 4;
  const size_t s_base = (size_t)bid * 64 * 128;
  const size_t o_base = ((size_t)(b * N_ + t0) * H_ + h) * 64;

#pragma unroll
  for (int u = 0; u < 4; ++u) {
    const int flat = u * 256 + tid;
    const int d = flat >> 4, sl = flat & 15;
    u16x8 src = *(const u16x8*)&S[s_base + (size_t)d * 128 + sl * 8];
    *(u16x8*)&S_l[d * 128 + ((sl ^ (d & 7)) * 8)] = src;
  }
  __syncthreads();
  bf16x8 af[4];
#pragma unroll
  for (int ks = 0; ks < 4; ++ks)
    af[ks] = *(const bf16x8*)&qg_p[((((size_t)bid * 4 + w) * 4 + ks) * 64 + lane) * 8];
  f32x4 acc[4];
#pragma unroll
  for (int n = 0; n < 4; ++n) acc[n] = (f32x4){0.f, 0.f, 0.f, 0.f};
#pragma unroll
  for (int n = 0; n < 4; ++n) {
    const int d = 16 * n + lr;
#pragma unroll
    for (int ks = 0; ks < 4; ++ks) {
      bf16x8 bk = *(const bf16x8*)&S_l[d * 128 + (((lg + 4 * ks) ^ (d & 7)) * 8)];
      acc[n] = __builtin_amdgcn_mfma_f32_16x16x32_bf16(af[ks], bk, acc[n], 0, 0, 0);
    }
  }
#pragma unroll
  for (int n = 0; n < 4; ++n)
#pragma unroll
    for (int reg = 0; reg < 4; ++reg) {
      const size_t idx = o_base + (size_t)(16 * w + 4 * lg + reg) * (H_ * 64) + 16 * n + lr;
      o[idx] += acc[n][reg];
    }
}

// ---------- gate+norm v2: one wave per row, reduction-free gate ----------
__global__ __launch_bounds__(256) void gate_norm2(
    const float* __restrict__ tg, const float* __restrict__ Wg2,
    const float* __restrict__ nw, const float* __restrict__ o,
    unsigned short* __restrict__ og) {
  const int w = threadIdx.x >> 6, lane = threadIdx.x & 63;
  const int row = blockIdx.x * 4 + w;
  float tgv[16];
  const float* tp = &tg[(size_t)row * 16];
#pragma unroll
  for (int hh = 0; hh < 16; ++hh) tgv[hh] = tp[hh];
  float ogr[4][4];
  float ssq = 0.f;
#pragma unroll
  for (int u = 0; u < 4; ++u) {
    const int d0 = u * 256 + lane * 4;
    float4 o4 = *(const float4*)&o[(size_t)row * 1024 + d0];
    float sgx = 0.f, sgy = 0.f, sgz = 0.f, sgw = 0.f;
#pragma unroll
    for (int hh = 0; hh < 16; ++hh) {
      float4 w4 = *(const float4*)&Wg2[hh * 1024 + d0];
      sgx += tgv[hh] * w4.x; sgy += tgv[hh] * w4.y;
      sgz += tgv[hh] * w4.z; sgw += tgv[hh] * w4.w;
    }
    ogr[u][0] = o4.x / (1.f + expf(-sgx));
    ogr[u][1] = o4.y / (1.f + expf(-sgy));
    ogr[u][2] = o4.z / (1.f + expf(-sgz));
    ogr[u][3] = o4.w / (1.f + expf(-sgw));
    ssq += ogr[u][0] * ogr[u][0] + ogr[u][1] * ogr[u][1] +
           ogr[u][2] * ogr[u][2] + ogr[u][3] * ogr[u][3];
  }
#pragma unroll
  for (int off = 32; off > 0; off >>= 1) ssq += __shfl_xor(ssq, off);
  const float rinv = rsqrtf(ssq * (1.f / 1024.f) + 1e-6f);
#pragma unroll
  for (int u = 0; u < 4; ++u) {
    const int d0 = u * 256 + lane * 4;
    float4 nw4 = *(const float4*)&nw[d0];
    ushort4 st;
    st.x = f2bf(ogr[u][0] * rinv * nw4.x);
    st.y = f2bf(ogr[u][1] * rinv * nw4.y);
    st.z = f2bf(ogr[u][2] * rinv * nw4.z);
    st.w = f2bf(ogr[u][3] * rinv * nw4.w);
    *(ushort4*)&og[(size_t)row * 1024 + d0] = st;
  }
}

extern "C" void kernel_launch(void* const* d_in, const int* in_sizes, int n_in,
                              void* d_out, int out_size, void* d_ws, size_t ws_size,
                              hipStream_t stream) {
  const float* x   = (const float*)d_in[0];
  const float* Wq  = (const float*)d_in[1];
  const float* Wk  = (const float*)d_in[2];
  const float* Wv  = (const float*)d_in[3];
  const float* Wo  = (const float*)d_in[4];
  const float* Wg1 = (const float*)d_in[5];
  const float* Wg2 = (const float*)d_in[6];
  const float* nw  = (const float*)d_in[7];
  float* out = (float*)d_out;
  float* ws  = (float*)d_ws;

  const size_t P = (size_t)B_ * N_ * D_;  // 8,388,608
  float* k_raw = ws;                        // [0,P); after scan: U_buf (bf16 2P elems)
  float* o_buf = ws + P;                    // [P,2P)
  float* G_buf = ws + 2 * P;                // [2P,3P)
  unsigned short* qg_p = (unsigned short*)(ws + 3 * P);   // 2P elems
  unsigned short* kg_g = (unsigned short*)(ws + 4 * P);   // 2P elems
  unsigned short* v_bf = (unsigned short*)(ws + 5 * P);            // P elems
  unsigned short* q_bf = (unsigned short*)(ws + 5 * P + P / 2);    // P elems
  float* ropeT = ws + 6 * P;                                       // 262144
  float* T_buf = ws + 6 * P + 524288;                              // 131072
  float* P_buf = T_buf + 131072;                                   // 131072
  unsigned short* Wg1p = (unsigned short*)(ws + 6 * P + 786432);   // 16384 u16
  float* tg_buf = ws + 6 * P + 794624;                             // 131072
  unsigned short* x_bf = (unsigned short*)(ws + 13 * P / 2);       // P elems
  unsigned short* og_bf = x_bf;  // x_bf dead before gate_norm2 writes og
  unsigned short* Wq_p = (unsigned short*)(ws + 7 * P);
  unsigned short* Wk_p = Wq_p + 1048576;
  unsigned short* Wv_p = Wk_p + 1048576;
  unsigned short* Wo_p = Wv_p + 1048576;
  float* glast_g = ws + 7 * P + 2097152;                           // 131072
  unsigned short* U_buf = (unsigned short*)k_raw;

  const int M = B_ * N_;
  const int ggrid = (M / 128) * (D_ / 128);  // 512

  cast_x_bf16<<<(int)(P / 2048), 256, 0, stream>>>(x, x_bf);
  rope_fill<<<512, 256, 0, stream>>>(ropeT);
  cast_w_pack<<<512, 256, 0, stream>>>(Wq, Wq_p);
  cast_w_pack<<<512, 256, 0, stream>>>(Wk, Wk_p);
  cast_w_pack<<<512, 256, 0, stream>>>(Wv, Wv_p);
  cast_w_pack<<<512, 256, 0, stream>>>(Wo, Wo_p);
  pack_wg1<<<8, 256, 0, stream>>>(Wg1, Wg1p);
  gate_logits<<<M / 64, 256, 0, stream>>>(x_bf, Wg1p, tg_buf);
  gemm_bf16<<<ggrid, 256, 0, stream>>>(x_bf, Wq_p, nullptr, q_bf, M, D_, D_, 1);
  gemm_bf16<<<ggrid, 256, 0, stream>>>(x_bf, Wk_p, k_raw, nullptr, M, D_, D_, 0);
  gemm_bf16<<<ggrid, 256, 0, stream>>>(x_bf, Wv_p, nullptr, v_bf, M, D_, D_, 2);
  scan_pass_a<<<512, 256, 0, stream>>>(k_raw, T_buf);
  scan_pass_b<<<16, 256, 0, stream>>>(T_buf, P_buf);
  scan_pass_c<<<512, 256, 0, stream>>>(k_raw, P_buf, ropeT, G_buf, kg_g, glast_g);
  gla_a<<<2048, 256, 0, stream>>>(q_bf, kg_g, G_buf, v_bf, ropeT, glast_g, qg_p, U_buf, o_buf);
  gla_b<<<512, 256, 0, stream>>>(U_buf, glast_g);
  gla_c<<<2048, 256, 0, stream>>>(qg_p, U_buf, o_buf);
  gate_norm2<<<M / 4, 256, 0, stream>>>(tg_buf, Wg2, nw, o_buf, og_bf);
  gemm_bf16<<<ggrid, 256, 0, stream>>>(og_bf, Wo_p, out, nullptr, M, D_, D_, 0);
}

// Round 7
// 301.180 us; speedup vs baseline: 8.6992x; 1.2799x over previous
//
#include <hip/hip_runtime.h>
#include <hip/hip_bf16.h>
#include <math.h>

#define B_ 4
#define N_ 2048
#define D_ 1024
#define H_ 16
#define HD_ 64

typedef __attribute__((ext_vector_type(8))) short bf16x8;
typedef __attribute__((ext_vector_type(8))) unsigned short u16x8;
typedef __attribute__((ext_vector_type(4))) float f32x4;

#define AS1(p) ((const __attribute__((address_space(1))) void*)(p))
#define AS3(p) ((__attribute__((address_space(3))) void*)(p))

__device__ inline float bf2f(unsigned short u) { return __uint_as_float(((unsigned)u) << 16); }
__device__ inline unsigned short f2bf(float f) {
  unsigned u = __float_as_uint(f);
  return (unsigned short)((u + 0x7fffu + ((u >> 16) & 1u)) >> 16);
}
__device__ inline float lseop_fast(float a, float b) {
  float mx = fmaxf(a, b), mn = fminf(a, b);
  return mx + __logf(1.f + __expf(mn - mx));
}

// ---------- cast x (f32) -> bf16 row-major ----------
__global__ __launch_bounds__(256) void cast_x_bf16(const float* __restrict__ x,
                                                   unsigned short* __restrict__ xb) {
  const int t = blockIdx.x * 256 + threadIdx.x;
  float4 a = ((const float4*)x)[(size_t)t * 2];
  float4 b = ((const float4*)x)[(size_t)t * 2 + 1];
  union { unsigned short u[8]; uint4 q; } pk;
  pk.u[0] = f2bf(a.x); pk.u[1] = f2bf(a.y); pk.u[2] = f2bf(a.z); pk.u[3] = f2bf(a.w);
  pk.u[4] = f2bf(b.x); pk.u[5] = f2bf(b.y); pk.u[6] = f2bf(b.z); pk.u[7] = f2bf(b.w);
  ((uint4*)xb)[t] = pk.q;
}

// ---------- cast W (f32 [1024][1024]) -> bf16 k-packed [(K/8)][N][8] ----------
__global__ __launch_bounds__(256) void cast_w_pack(const float* __restrict__ W,
                                                   unsigned short* __restrict__ Wp) {
  const int t = blockIdx.x * 256 + threadIdx.x;
  const int kg = t >> 10, n = t & 1023;
  union { unsigned short u[8]; uint4 q; } pk;
#pragma unroll
  for (int r = 0; r < 8; ++r)
    pk.u[r] = f2bf(W[(size_t)(kg * 8 + r) * 1024 + n]);
  *(uint4*)&Wp[((size_t)kg * 1024 + n) * 8] = pk.q;
}

// ---------- pack Wg1 (f32 [1024][16]) -> bf16 [(K/8)][16][8] ----------
__global__ __launch_bounds__(256) void pack_wg1(const float* __restrict__ Wg1,
                                                unsigned short* __restrict__ Wp) {
  const int t = blockIdx.x * 256 + threadIdx.x;  // 2048 = 128 kg * 16 hh
  const int kg = t >> 4, hh = t & 15;
  union { unsigned short us[8]; u16x8 v; } pk;
#pragma unroll
  for (int r = 0; r < 8; ++r)
    pk.us[r] = f2bf(Wg1[(size_t)(kg * 8 + r) * 16 + hh]);
  *(u16x8*)&Wp[((size_t)kg * 16 + hh) * 8] = pk.v;
}

// ---------- gate logits: tg[M][16] = x_bf @ Wg1_bf (MFMA) ----------
__global__ __launch_bounds__(256) void gate_logits(
    const unsigned short* __restrict__ x_bf, const unsigned short* __restrict__ Wg1p,
    float* __restrict__ tg) {
  __shared__ unsigned short Wl[128 * 16 * 8];  // 32 KB
  const int tid = threadIdx.x;
  const int lane = tid & 63, w = tid >> 6;
  const int lr = lane & 15, lg = lane >> 4;
#pragma unroll
  for (int u = 0; u < 8; ++u) {
    const int flat = u * 256 + tid;
    *(u16x8*)&Wl[flat * 8] = *(const u16x8*)&Wg1p[(size_t)flat * 8];
  }
  __syncthreads();
  const int row = blockIdx.x * 64 + w * 16 + lr;
  f32x4 acc = (f32x4){0.f, 0.f, 0.f, 0.f};
  for (int ks = 0; ks < 32; ++ks) {
    bf16x8 a = *(const bf16x8*)&x_bf[(size_t)row * 1024 + ks * 32 + lg * 8];
    bf16x8 b = *(const bf16x8*)&Wl[((ks * 4 + lg) * 16 + lr) * 8];
    acc = __builtin_amdgcn_mfma_f32_16x16x32_bf16(a, b, acc, 0, 0, 0);
  }
  const int orow = blockIdx.x * 64 + w * 16 + 4 * lg;
#pragma unroll
  for (int reg = 0; reg < 4; ++reg)
    tg[(size_t)(orow + reg) * 16 + lr] = acc[reg];
}

// ---------- rope table: ropeT[n][j<64]=cos(n*f_j), [j>=64]=sin ----------
__global__ __launch_bounds__(256) void rope_fill(float* __restrict__ ropeT) {
  const int t = blockIdx.x * 256 + threadIdx.x;  // N*64
  const int n = t >> 6, hd = t & 63;
  const float freq = expf((float)hd * -0.28782313662425575f);
  float s, c;
  sincosf((float)n * freq, &s, &c);
  ropeT[(size_t)n * 128 + hd] = c;
  ropeT[(size_t)n * 128 + 64 + hd] = s;
}

// ---------- MFMA bf16 GEMM (m97 structure). mode 0: f32 out; 1: silu->bf16; 2: bf16
__global__ __launch_bounds__(256) void gemm_bf16(
    const unsigned short* __restrict__ A, const unsigned short* __restrict__ Wp,
    float* __restrict__ Cf, unsigned short* __restrict__ Cb,
    int M, int K, int Nn, int mode) {
  __shared__ unsigned short Asm[128 * 32];
  __shared__ unsigned short Bsm[4 * 128 * 8];

  const int tid = threadIdx.x;
  const int lane = tid & 63;
  const int w = tid >> 6;
  const int nb = Nn >> 7;
  const int nwg = gridDim.x;
  const int cpx = nwg >> 3;
  int bid = blockIdx.x;
  bid = (bid & 7) * cpx + (bid >> 3);
  const int by = bid / nb, bx = bid % nb;
  const int m0 = by * 128, n0 = bx * 128;
  const int wr = w >> 1, wc = w & 1;

  f32x4 acc[4][4];
#pragma unroll
  for (int i = 0; i < 4; ++i)
#pragma unroll
    for (int j = 0; j < 4; ++j) acc[i][j] = (f32x4){0.f, 0.f, 0.f, 0.f};

  const int rA0 = w * 16 + (lane >> 2);
  const int rA1 = (w + 4) * 16 + (lane >> 2);
  const int sA0 = (lane & 3) ^ ((rA0 >> 1) & 3);
  const int sA1 = (lane & 3) ^ ((rA1 >> 1) & 3);
  const unsigned short* gA0 = A + (size_t)(m0 + rA0) * K + sA0 * 8;
  const unsigned short* gA1 = A + (size_t)(m0 + rA1) * K + sA1 * 8;
  const unsigned short* gB0 = Wp + (size_t)(w >> 1) * Nn * 8 +
                              (size_t)(n0 + (w & 1) * 64 + lane) * 8;
  const unsigned short* gB1 = Wp + (size_t)((w + 4) >> 1) * Nn * 8 +
                              (size_t)(n0 + ((w + 4) & 1) * 64 + lane) * 8;

  int offA[4], offB[4];
#pragma unroll
  for (int m = 0; m < 4; ++m) {
    const int rowf = wr * 64 + m * 16 + (lane & 15);
    const int sp = (lane >> 4) ^ ((rowf >> 1) & 3);
    offA[m] = rowf * 32 + sp * 8;
  }
#pragma unroll
  for (int n = 0; n < 4; ++n) {
    const int colf = wc * 64 + n * 16 + (lane & 15);
    offB[n] = (lane >> 4) * 1024 + colf * 8;
  }

  for (int kt = 0; kt < K; kt += 32) {
    const size_t kB = (size_t)(kt >> 3) * Nn * 8;
    __builtin_amdgcn_global_load_lds(AS1(gA0 + kt), AS3(&Asm[w * 512]), 16, 0, 0);
    __builtin_amdgcn_global_load_lds(AS1(gA1 + kt), AS3(&Asm[(w + 4) * 512]), 16, 0, 0);
    __builtin_amdgcn_global_load_lds(AS1(gB0 + kB), AS3(&Bsm[w * 512]), 16, 0, 0);
    __builtin_amdgcn_global_load_lds(AS1(gB1 + kB), AS3(&Bsm[(w + 4) * 512]), 16, 0, 0);
    __syncthreads();
    bf16x8 af[4], bfr[4];
#pragma unroll
    for (int m = 0; m < 4; ++m) af[m] = *(const bf16x8*)&Asm[offA[m]];
#pragma unroll
    for (int n = 0; n < 4; ++n) bfr[n] = *(const bf16x8*)&Bsm[offB[n]];
#pragma unroll
    for (int m = 0; m < 4; ++m)
#pragma unroll
      for (int n = 0; n < 4; ++n)
        acc[m][n] = __builtin_amdgcn_mfma_f32_16x16x32_bf16(af[m], bfr[n], acc[m][n], 0, 0, 0);
    __syncthreads();
  }

  const int crow = (lane >> 4) * 4;
  const int ccol = lane & 15;
#pragma unroll
  for (int m = 0; m < 4; ++m)
#pragma unroll
    for (int n = 0; n < 4; ++n) {
#pragma unroll
      for (int r = 0; r < 4; ++r) {
        float vv = acc[m][n][r];
        const size_t idx = (size_t)(m0 + wr * 64 + m * 16 + crow + r) * Nn +
                           n0 + wc * 64 + n * 16 + ccol;
        if (mode == 0) {
          Cf[idx] = vv;
        } else {
          if (mode == 1) vv = vv / (1.f + __expf(-vv));
          Cb[idx] = f2bf(vv);
        }
      }
    }
}

// ---------- 3-pass parallel cumlogsumexp scan (sum-of-exp form) ----------
// Pass A: T_c = ln(sum_i exp(k_i)) per (channel, chunk). No serial transcendental chain.
__global__ __launch_bounds__(256) void scan_pass_a(const float* __restrict__ k_raw,
                                                   float* __restrict__ T) {
  const int g = blockIdx.x * 256 + threadIdx.x;
  const int hd = g & 63;
  const int c = (g >> 6) & 31;
  const int bh = g >> 11;
  const int b = bh >> 4, h = bh & 15;
  const size_t base = (size_t)b * N_ * D_ + (size_t)(c * 64) * D_ + h * HD_ + hd;
  float sum = 0.f;
  for (int j0 = 0; j0 < 64; j0 += 8) {
    float kr[8];
#pragma unroll
    for (int e = 0; e < 8; ++e) kr[e] = k_raw[base + (size_t)(j0 + e) * D_];
#pragma unroll
    for (int e = 0; e < 8; ++e) sum += __expf(kr[e]);
  }
  T[(size_t)(bh * 64 + hd) * 32 + c] = __logf(sum);
}

__global__ void scan_pass_b(const float* __restrict__ T, float* __restrict__ Pf) {
  const int ch = blockIdx.x * 256 + threadIdx.x;
  const float* t = &T[(size_t)ch * 32];
  float* p = &Pf[(size_t)ch * 32];
  float run = 0.f;
  for (int c = 0; c < 32; ++c) {
    p[c] = run;
    run = lseop_fast(run, t[c]);
  }
}

// Pass C: e_i = exp(k_i - P); S = cumsum(e); G = -ln(1+S); kg = e_i * rope.
__global__ __launch_bounds__(256) void scan_pass_c(const float* __restrict__ k_raw,
    const float* __restrict__ Pf, const float* __restrict__ ropeT,
    float* __restrict__ G_buf, unsigned short* __restrict__ kg_g,
    float* __restrict__ glast_g) {
  const int g = blockIdx.x * 256 + threadIdx.x;
  const int hd = g & 63;
  const int c = (g >> 6) & 31;
  const int bh = g >> 11;
  const int b = bh >> 4, h = bh & 15;
  const size_t base = (size_t)b * N_ * D_ + (size_t)(c * 64) * D_ + h * HD_ + hd;
  const size_t gb = ((size_t)bh * N_ + c * 64) * 64 + hd;
  const size_t kb = ((size_t)bh * N_ + c * 64) * 128 + hd;
  const size_t rb = (size_t)(c * 64) * 128 + hd;
  const float P = Pf[(size_t)(bh * 64 + hd) * 32 + c];
  float S = 0.f, G = 0.f;
  for (int j0 = 0; j0 < 64; j0 += 8) {
    float kr[8], cv[8], sv[8];
#pragma unroll
    for (int e = 0; e < 8; ++e) kr[e] = k_raw[base + (size_t)(j0 + e) * D_];
#pragma unroll
    for (int e = 0; e < 8; ++e) {
      cv[e] = ropeT[rb + (size_t)(j0 + e) * 128];
      sv[e] = ropeT[rb + (size_t)(j0 + e) * 128 + 64];
    }
#pragma unroll
    for (int e = 0; e < 8; ++e) {
      float ei = __expf(kr[e] - P);
      S += ei;
      G = -__logf(1.f + S);
      G_buf[gb + (size_t)(j0 + e) * 64] = G;
      kg_g[kb + (size_t)(j0 + e) * 128] = f2bf(ei * cv[e]);
      kg_g[kb + (size_t)(j0 + e) * 128 + 64] = f2bf(ei * sv[e]);
    }
  }
  glast_g[(size_t)(bh * 32 + c) * 64 + hd] = G;
}

// ---------- GLA pass A (MFMA): A=masked(qg@kg^T), o_intra=A@v, U=(v^T@kg)*e^glast
__global__ __launch_bounds__(256) void gla_a(
    const unsigned short* __restrict__ qs, const unsigned short* __restrict__ kg_g,
    const float* __restrict__ G_buf, const unsigned short* __restrict__ v_bf,
    const float* __restrict__ ropeT, const float* __restrict__ glast_g,
    unsigned short* __restrict__ qg_p, unsigned short* __restrict__ U,
    float* __restrict__ o) {
  __shared__ unsigned short kg_l[64 * 128];   // [s][slot^(s&7)][8]; reused as U_l[d][128]
  __shared__ unsigned short kgT_l[128 * 72];  // [j][s]
  __shared__ unsigned short vT_l[64 * 72];    // [d][s]
  __shared__ unsigned short A_l[64 * 72];     // [c][s] masked

  const int bid = blockIdx.x;
  const int bh = bid >> 5, c = bid & 31;
  const int b = bh >> 4, h = bh & 15;
  const int t0 = c * 64;
  const int tid = threadIdx.x;
  const int lane = tid & 63, w = tid >> 6;
  const int lr = lane & 15, lg = lane >> 4;

  const size_t qv_base = ((size_t)(b * N_ + t0) * H_ + h) * 64;
  const size_t kg_base = ((size_t)bh * N_ + t0) * 128;

  // stage kg_l (swizzled), 16B chunks, coalesced
#pragma unroll
  for (int u = 0; u < 4; ++u) {
    const int flat = u * 256 + tid;
    const int r = flat >> 4, sl = flat & 15;
    u16x8 src = *(const u16x8*)&kg_g[kg_base + (size_t)r * 128 + sl * 8];
    *(u16x8*)&kg_l[r * 128 + ((sl ^ (r & 7)) * 8)] = src;
  }
  // stage vT_l
  {
    const int r = tid >> 2, d0 = (tid & 3) * 16;
    u16x8 a = *(const u16x8*)&v_bf[qv_base + (size_t)r * (H_ * 64) + d0];
    u16x8 b2 = *(const u16x8*)&v_bf[qv_base + (size_t)r * (H_ * 64) + d0 + 8];
#pragma unroll
    for (int e = 0; e < 8; ++e) {
      vT_l[(d0 + e) * 72 + r] = a[e];
      vT_l[(d0 + 8 + e) * 72 + r] = b2[e];
    }
  }
  __syncthreads();
  // build kgT_l from kg_l
  {
    const int j = tid >> 1, sh = (tid & 1) * 32;
#pragma unroll
    for (int u = 0; u < 4; ++u) {
      union { unsigned short us[8]; u16x8 v; } tv;
#pragma unroll
      for (int e = 0; e < 8; ++e) {
        const int s = sh + 8 * u + e;
        tv.us[e] = kg_l[s * 128 + (((j >> 3) ^ (s & 7)) * 8) + (j & 7)];
      }
      *(u16x8*)&kgT_l[j * 72 + sh + 8 * u] = tv.v;
    }
  }
  __syncthreads();

  // ---- qg build (in-fragment) + global qg_p store ----
  bf16x8 af[4];
  {
    const int r = 16 * w + lr;
#pragma unroll
    for (int ks = 0; ks < 4; ++ks) {
      const int jb = 32 * ks + 8 * lg;
      const int jq = jb & 63;
      u16x8 q8 = *(const u16x8*)&qs[qv_base + (size_t)r * (H_ * 64) + jq];
      float4 g0 = *(const float4*)&G_buf[((size_t)bh * N_ + t0 + r) * 64 + jq];
      float4 g1 = *(const float4*)&G_buf[((size_t)bh * N_ + t0 + r) * 64 + jq + 4];
      float4 r0 = *(const float4*)&ropeT[(size_t)(t0 + r) * 128 + jb];
      float4 r1 = *(const float4*)&ropeT[(size_t)(t0 + r) * 128 + jb + 4];
      float gg[8] = {g0.x, g0.y, g0.z, g0.w, g1.x, g1.y, g1.z, g1.w};
      float rr[8] = {r0.x, r0.y, r0.z, r0.w, r1.x, r1.y, r1.z, r1.w};
      union { unsigned short us[8]; bf16x8 v; u16x8 uv; } pk;
#pragma unroll
      for (int e = 0; e < 8; ++e)
        pk.us[e] = f2bf(bf2f(q8[e]) * rr[e] * __expf(gg[e]));
      af[ks] = pk.v;
      *(u16x8*)&qg_p[((((size_t)bid * 4 + w) * 4 + ks) * 64 + lane) * 8] = pk.uv;
    }
  }
  // ---- m1: A = qg @ kg^T ----
  f32x4 acc1[4];
#pragma unroll
  for (int n = 0; n < 4; ++n) acc1[n] = (f32x4){0.f, 0.f, 0.f, 0.f};
#pragma unroll
  for (int n = 0; n < 4; ++n) {
    const int s = 16 * n + lr;
#pragma unroll
    for (int ks = 0; ks < 4; ++ks) {
      bf16x8 bk = *(const bf16x8*)&kg_l[s * 128 + (((lg + 4 * ks) ^ (s & 7)) * 8)];
      acc1[n] = __builtin_amdgcn_mfma_f32_16x16x32_bf16(af[ks], bk, acc1[n], 0, 0, 0);
    }
  }
  // masked A -> A_l (bf16)
#pragma unroll
  for (int n = 0; n < 4; ++n) {
    const int s = 16 * n + lr;
#pragma unroll
    for (int reg = 0; reg < 4; ++reg) {
      const int cr = 16 * w + 4 * lg + reg;
      A_l[cr * 72 + s] = (s <= cr) ? f2bf(acc1[n][reg]) : (unsigned short)0;
    }
  }
  // ---- m2: Urows d = v^T @ kg ----
  f32x4 acc2[8];
#pragma unroll
  for (int n = 0; n < 8; ++n) acc2[n] = (f32x4){0.f, 0.f, 0.f, 0.f};
#pragma unroll
  for (int ks = 0; ks < 2; ++ks) {
    const int s0 = 32 * ks + 8 * lg;
    bf16x8 av = *(const bf16x8*)&vT_l[(16 * w + lr) * 72 + s0];
#pragma unroll
    for (int n = 0; n < 8; ++n) {
      bf16x8 bk = *(const bf16x8*)&kgT_l[(16 * n + lr) * 72 + s0];
      acc2[n] = __builtin_amdgcn_mfma_f32_16x16x32_bf16(av, bk, acc2[n], 0, 0, 0);
    }
  }
  __syncthreads();
  // ---- phase D: U_l (=kg_l) writes; m3 = A @ v; o write ----
  float es[4];
#pragma unroll
  for (int n = 0; n < 4; ++n)
    es[n] = __expf(glast_g[(size_t)bid * 64 + 16 * n + lr]);
#pragma unroll
  for (int n = 0; n < 8; ++n) {
    const int j = 16 * n + lr;
    const float e = es[n & 3];
#pragma unroll
    for (int reg = 0; reg < 4; ++reg)
      kg_l[(16 * w + 4 * lg + reg) * 128 + j] = f2bf(acc2[n][reg] * e);
  }
  f32x4 acc3[4];
#pragma unroll
  for (int n = 0; n < 4; ++n) acc3[n] = (f32x4){0.f, 0.f, 0.f, 0.f};
#pragma unroll
  for (int ks = 0; ks < 2; ++ks) {
    const int s0 = 32 * ks + 8 * lg;
    bf16x8 aA = *(const bf16x8*)&A_l[(16 * w + lr) * 72 + s0];
#pragma unroll
    for (int n = 0; n < 4; ++n) {
      bf16x8 bV = *(const bf16x8*)&vT_l[(16 * n + lr) * 72 + s0];
      acc3[n] = __builtin_amdgcn_mfma_f32_16x16x32_bf16(aA, bV, acc3[n], 0, 0, 0);
    }
  }
#pragma unroll
  for (int n = 0; n < 4; ++n)
#pragma unroll
    for (int reg = 0; reg < 4; ++reg)
      o[qv_base + (size_t)(16 * w + 4 * lg + reg) * (H_ * 64) + 16 * n + lr] = acc3[n][reg];
  __syncthreads();
  // ---- phase E: U_l -> global (coalesced) ----
#pragma unroll
  for (int u = 0; u < 4; ++u) {
    const int flat = u * 256 + tid;
    const int d = flat >> 4, sl = flat & 15;
    *(u16x8*)&U[((size_t)bid * 64 + d) * 128 + sl * 8] =
        *(const u16x8*)&kg_l[d * 128 + sl * 8];
  }
}

// ---------- GLA pass B: exclusive chunk scan (in place) ----------
__global__ __launch_bounds__(256) void gla_b(unsigned short* __restrict__ U,
                                             const float* __restrict__ glast_g) {
  const int t = blockIdx.x * 256 + threadIdx.x;
  const int j4 = t & 31;
  const int d = (t >> 5) & 63;
  const int bh = t >> 11;
  const int jj0 = (4 * j4) & 63;
  float s0 = 0.f, s1 = 0.f, s2 = 0.f, s3 = 0.f;
  for (int c = 0; c < 32; ++c) {
    const size_t ub = ((size_t)((bh * 32 + c) * 64 + d)) * 128 + 4 * j4;
    ushort4 uv = *(const ushort4*)&U[ub];
    float4 g4 = *(const float4*)&glast_g[(size_t)(bh * 32 + c) * 64 + jj0];
    ushort4 pv;
    pv.x = f2bf(s0); pv.y = f2bf(s1); pv.z = f2bf(s2); pv.w = f2bf(s3);
    *(ushort4*)&U[ub] = pv;
    s0 = s0 * __expf(g4.x) + bf2f(uv.x);
    s1 = s1 * __expf(g4.y) + bf2f(uv.y);
    s2 = s2 * __expf(g4.z) + bf2f(uv.z);
    s3 = s3 * __expf(g4.w) + bf2f(uv.w);
  }
}

// ---------- GLA pass C (MFMA): o += qg @ S_{c-1} ----------
__global__ __launch_bounds__(256) void gla_c(
    const unsigned short* __restrict__ qg_p, const unsigned short* __restrict__ S,
    float* __restrict__ o) {
  __shared__ unsigned short S_l[64 * 128];
  const int bid = blockIdx.x;
  const int bh = bid >> 5, c = bid & 31;
  const int b = bh >> 4, h = bh & 15;
  const int t0 = c * 64;
  const int tid = threadIdx.x;
  const int lane = tid & 63, w = tid >> 6;
  const int lr = lane & 15, lg = lane >> 4;
  const size_t s_base = (size_t)bid * 64 * 128;
  const size_t o_base = ((size_t)(b * N_ + t0) * H_ + h) * 64;

#pragma unroll
  for (int u = 0; u < 4; ++u) {
    const int flat = u * 256 + tid;
    const int d = flat >> 4, sl = flat & 15;
    u16x8 src = *(const u16x8*)&S[s_base + (size_t)d * 128 + sl * 8];
    *(u16x8*)&S_l[d * 128 + ((sl ^ (d & 7)) * 8)] = src;
  }
  __syncthreads();
  bf16x8 af[4];
#pragma unroll
  for (int ks = 0; ks < 4; ++ks)
    af[ks] = *(const bf16x8*)&qg_p[((((size_t)bid * 4 + w) * 4 + ks) * 64 + lane) * 8];
  f32x4 acc[4];
#pragma unroll
  for (int n = 0; n < 4; ++n) acc[n] = (f32x4){0.f, 0.f, 0.f, 0.f};
#pragma unroll
  for (int n = 0; n < 4; ++n) {
    const int d = 16 * n + lr;
#pragma unroll
    for (int ks = 0; ks < 4; ++ks) {
      bf16x8 bk = *(const bf16x8*)&S_l[d * 128 + (((lg + 4 * ks) ^ (d & 7)) * 8)];
      acc[n] = __builtin_amdgcn_mfma_f32_16x16x32_bf16(af[ks], bk, acc[n], 0, 0, 0);
    }
  }
#pragma unroll
  for (int n = 0; n < 4; ++n)
#pragma unroll
    for (int reg = 0; reg < 4; ++reg) {
      const size_t idx = o_base + (size_t)(16 * w + 4 * lg + reg) * (H_ * 64) + 16 * n + lr;
      o[idx] += acc[n][reg];
    }
}

// ---------- gate+norm v2: one wave per row, reduction-free gate ----------
__global__ __launch_bounds__(256) void gate_norm2(
    const float* __restrict__ tg, const float* __restrict__ Wg2,
    const float* __restrict__ nw, const float* __restrict__ o,
    unsigned short* __restrict__ og) {
  const int w = threadIdx.x >> 6, lane = threadIdx.x & 63;
  const int row = blockIdx.x * 4 + w;
  float tgv[16];
  const float* tp = &tg[(size_t)row * 16];
#pragma unroll
  for (int hh = 0; hh < 16; ++hh) tgv[hh] = tp[hh];
  float ogr[4][4];
  float ssq = 0.f;
#pragma unroll
  for (int u = 0; u < 4; ++u) {
    const int d0 = u * 256 + lane * 4;
    float4 o4 = *(const float4*)&o[(size_t)row * 1024 + d0];
    float sgx = 0.f, sgy = 0.f, sgz = 0.f, sgw = 0.f;
#pragma unroll
    for (int hh = 0; hh < 16; ++hh) {
      float4 w4 = *(const float4*)&Wg2[hh * 1024 + d0];
      sgx += tgv[hh] * w4.x; sgy += tgv[hh] * w4.y;
      sgz += tgv[hh] * w4.z; sgw += tgv[hh] * w4.w;
    }
    ogr[u][0] = o4.x / (1.f + __expf(-sgx));
    ogr[u][1] = o4.y / (1.f + __expf(-sgy));
    ogr[u][2] = o4.z / (1.f + __expf(-sgz));
    ogr[u][3] = o4.w / (1.f + __expf(-sgw));
    ssq += ogr[u][0] * ogr[u][0] + ogr[u][1] * ogr[u][1] +
           ogr[u][2] * ogr[u][2] + ogr[u][3] * ogr[u][3];
  }
#pragma unroll
  for (int off = 32; off > 0; off >>= 1) ssq += __shfl_xor(ssq, off);
  const float rinv = rsqrtf(ssq * (1.f / 1024.f) + 1e-6f);
#pragma unroll
  for (int u = 0; u < 4; ++u) {
    const int d0 = u * 256 + lane * 4;
    float4 nw4 = *(const float4*)&nw[d0];
    ushort4 st;
    st.x = f2bf(ogr[u][0] * rinv * nw4.x);
    st.y = f2bf(ogr[u][1] * rinv * nw4.y);
    st.z = f2bf(ogr[u][2] * rinv * nw4.z);
    st.w = f2bf(ogr[u][3] * rinv * nw4.w);
    *(ushort4*)&og[(size_t)row * 1024 + d0] = st;
  }
}

extern "C" void kernel_launch(void* const* d_in, const int* in_sizes, int n_in,
                              void* d_out, int out_size, void* d_ws, size_t ws_size,
                              hipStream_t stream) {
  const float* x   = (const float*)d_in[0];
  const float* Wq  = (const float*)d_in[1];
  const float* Wk  = (const float*)d_in[2];
  const float* Wv  = (const float*)d_in[3];
  const float* Wo  = (const float*)d_in[4];
  const float* Wg1 = (const float*)d_in[5];
  const float* Wg2 = (const float*)d_in[6];
  const float* nw  = (const float*)d_in[7];
  float* out = (float*)d_out;
  float* ws  = (float*)d_ws;

  const size_t P = (size_t)B_ * N_ * D_;  // 8,388,608
  float* k_raw = ws;                        // [0,P); after scan: U_buf (bf16 2P elems)
  float* o_buf = ws + P;                    // [P,2P)
  float* G_buf = ws + 2 * P;                // [2P,3P)
  unsigned short* qg_p = (unsigned short*)(ws + 3 * P);   // 2P elems
  unsigned short* kg_g = (unsigned short*)(ws + 4 * P);   // 2P elems
  unsigned short* v_bf = (unsigned short*)(ws + 5 * P);            // P elems
  unsigned short* q_bf = (unsigned short*)(ws + 5 * P + P / 2);    // P elems
  float* ropeT = ws + 6 * P;                                       // 262144
  float* T_buf = ws + 6 * P + 524288;                              // 131072
  float* P_buf = T_buf + 131072;                                   // 131072
  unsigned short* Wg1p = (unsigned short*)(ws + 6 * P + 786432);   // 16384 u16
  float* tg_buf = ws + 6 * P + 794624;                             // 131072
  unsigned short* x_bf = (unsigned short*)(ws + 13 * P / 2);       // P elems
  unsigned short* og_bf = x_bf;  // x_bf dead before gate_norm2 writes og
  unsigned short* Wq_p = (unsigned short*)(ws + 7 * P);
  unsigned short* Wk_p = Wq_p + 1048576;
  unsigned short* Wv_p = Wk_p + 1048576;
  unsigned short* Wo_p = Wv_p + 1048576;
  float* glast_g = ws + 7 * P + 2097152;                           // 131072
  unsigned short* U_buf = (unsigned short*)k_raw;

  const int M = B_ * N_;
  const int ggrid = (M / 128) * (D_ / 128);  // 512

  cast_x_bf16<<<(int)(P / 2048), 256, 0, stream>>>(x, x_bf);
  rope_fill<<<512, 256, 0, stream>>>(ropeT);
  cast_w_pack<<<512, 256, 0, stream>>>(Wq, Wq_p);
  cast_w_pack<<<512, 256, 0, stream>>>(Wk, Wk_p);
  cast_w_pack<<<512, 256, 0, stream>>>(Wv, Wv_p);
  cast_w_pack<<<512, 256, 0, stream>>>(Wo, Wo_p);
  pack_wg1<<<8, 256, 0, stream>>>(Wg1, Wg1p);
  gate_logits<<<M / 64, 256, 0, stream>>>(x_bf, Wg1p, tg_buf);
  gemm_bf16<<<ggrid, 256, 0, stream>>>(x_bf, Wq_p, nullptr, q_bf, M, D_, D_, 1);
  gemm_bf16<<<ggrid, 256, 0, stream>>>(x_bf, Wk_p, k_raw, nullptr, M, D_, D_, 0);
  gemm_bf16<<<ggrid, 256, 0, stream>>>(x_bf, Wv_p, nullptr, v_bf, M, D_, D_, 2);
  scan_pass_a<<<512, 256, 0, stream>>>(k_raw, T_buf);
  scan_pass_b<<<16, 256, 0, stream>>>(T_buf, P_buf);
  scan_pass_c<<<512, 256, 0, stream>>>(k_raw, P_buf, ropeT, G_buf, kg_g, glast_g);
  gla_a<<<2048, 256, 0, stream>>>(q_bf, kg_g, G_buf, v_bf, ropeT, glast_g, qg_p, U_buf, o_buf);
  gla_b<<<512, 256, 0, stream>>>(U_buf, glast_g);
  gla_c<<<2048, 256, 0, stream>>>(qg_p, U_buf, o_buf);
  gate_norm2<<<M / 4, 256, 0, stream>>>(tg_buf, Wg2, nw, o_buf, og_bf);
  gemm_bf16<<<ggrid, 256, 0, stream>>>(og_bf, Wo_p, out, nullptr, M, D_, D_, 0);
}

// Round 8
// 261.801 us; speedup vs baseline: 10.0077x; 1.1504x over previous
//
#include <hip/hip_runtime.h>
#include <hip/hip_bf16.h>
#include <math.h>

#define B_ 4
#define N_ 2048
#define D_ 1024
#define H_ 16
#define HD_ 64

typedef __attribute__((ext_vector_type(8))) short bf16x8;
typedef __attribute__((ext_vector_type(8))) unsigned short u16x8;
typedef __attribute__((ext_vector_type(4))) float f32x4;

#define AS1(p) ((const __attribute__((address_space(1))) void*)(p))
#define AS3(p) ((__attribute__((address_space(3))) void*)(p))

__device__ inline float bf2f(unsigned short u) { return __uint_as_float(((unsigned)u) << 16); }
__device__ inline unsigned short f2bf(float f) {
  unsigned u = __float_as_uint(f);
  return (unsigned short)((u + 0x7fffu + ((u >> 16) & 1u)) >> 16);
}
__device__ inline unsigned short f2h(float f) {
  _Float16 h = (_Float16)f; unsigned short u; __builtin_memcpy(&u, &h, 2); return u;
}
__device__ inline float h2f(unsigned short u) {
  _Float16 h; __builtin_memcpy(&h, &u, 2); return (float)h;
}
__device__ inline float lseop_fast(float a, float b) {
  float mx = fmaxf(a, b), mn = fminf(a, b);
  return mx + __logf(1.f + __expf(mn - mx));
}

// ---------- cast x (f32) -> bf16 row-major ----------
__global__ __launch_bounds__(256) void cast_x_bf16(const float* __restrict__ x,
                                                   unsigned short* __restrict__ xb) {
  const int t = blockIdx.x * 256 + threadIdx.x;
  float4 a = ((const float4*)x)[(size_t)t * 2];
  float4 b = ((const float4*)x)[(size_t)t * 2 + 1];
  union { unsigned short u[8]; uint4 q; } pk;
  pk.u[0] = f2bf(a.x); pk.u[1] = f2bf(a.y); pk.u[2] = f2bf(a.z); pk.u[3] = f2bf(a.w);
  pk.u[4] = f2bf(b.x); pk.u[5] = f2bf(b.y); pk.u[6] = f2bf(b.z); pk.u[7] = f2bf(b.w);
  ((uint4*)xb)[t] = pk.q;
}

// ---------- cast W (f32 [1024][1024]) -> bf16 k-packed [(K/8)][Ntot][8] at col0 ----------
__global__ __launch_bounds__(256) void cast_w_pack(const float* __restrict__ W,
                                                   unsigned short* __restrict__ Wp,
                                                   int col0, int Ntot) {
  const int t = blockIdx.x * 256 + threadIdx.x;
  const int kg = t >> 10, n = t & 1023;
  union { unsigned short u[8]; uint4 q; } pk;
#pragma unroll
  for (int r = 0; r < 8; ++r)
    pk.u[r] = f2bf(W[(size_t)(kg * 8 + r) * 1024 + n]);
  *(uint4*)&Wp[((size_t)kg * Ntot + col0 + n) * 8] = pk.q;
}

// ---------- pack Wg1 (f32 [1024][16]) -> bf16 [(K/8)][16][8] ----------
__global__ __launch_bounds__(256) void pack_wg1(const float* __restrict__ Wg1,
                                                unsigned short* __restrict__ Wp) {
  const int t = blockIdx.x * 256 + threadIdx.x;  // 2048 = 128 kg * 16 hh
  const int kg = t >> 4, hh = t & 15;
  union { unsigned short us[8]; u16x8 v; } pk;
#pragma unroll
  for (int r = 0; r < 8; ++r)
    pk.us[r] = f2bf(Wg1[(size_t)(kg * 8 + r) * 16 + hh]);
  *(u16x8*)&Wp[((size_t)kg * 16 + hh) * 8] = pk.v;
}

// ---------- gate logits: tg[M][16] = x_bf @ Wg1_bf (MFMA) ----------
__global__ __launch_bounds__(256) void gate_logits(
    const unsigned short* __restrict__ x_bf, const unsigned short* __restrict__ Wg1p,
    float* __restrict__ tg) {
  __shared__ unsigned short Wl[128 * 16 * 8];  // 32 KB
  const int tid = threadIdx.x;
  const int lane = tid & 63, w = tid >> 6;
  const int lr = lane & 15, lg = lane >> 4;
#pragma unroll
  for (int u = 0; u < 8; ++u) {
    const int flat = u * 256 + tid;
    *(u16x8*)&Wl[flat * 8] = *(const u16x8*)&Wg1p[(size_t)flat * 8];
  }
  __syncthreads();
  const int row = blockIdx.x * 64 + w * 16 + lr;
  f32x4 acc = (f32x4){0.f, 0.f, 0.f, 0.f};
  for (int ks = 0; ks < 32; ++ks) {
    bf16x8 a = *(const bf16x8*)&x_bf[(size_t)row * 1024 + ks * 32 + lg * 8];
    bf16x8 b = *(const bf16x8*)&Wl[((ks * 4 + lg) * 16 + lr) * 8];
    acc = __builtin_amdgcn_mfma_f32_16x16x32_bf16(a, b, acc, 0, 0, 0);
  }
  const int orow = blockIdx.x * 64 + w * 16 + 4 * lg;
#pragma unroll
  for (int reg = 0; reg < 4; ++reg)
    tg[(size_t)(orow + reg) * 16 + lr] = acc[reg];
}

// ---------- rope table ----------
__global__ __launch_bounds__(256) void rope_fill(float* __restrict__ ropeT) {
  const int t = blockIdx.x * 256 + threadIdx.x;  // N*64
  const int n = t >> 6, hd = t & 63;
  const float freq = expf((float)hd * -0.28782313662425575f);
  float s, c;
  sincosf((float)n * freq, &s, &c);
  ropeT[(size_t)n * 128 + hd] = c;
  ropeT[(size_t)n * 128 + 64 + hd] = s;
}

// ---------- fused QKV GEMM: [M,3072] = x_bf @ Wqkv; routes slices ----------
__global__ __launch_bounds__(256) void gemm_qkv(
    const unsigned short* __restrict__ A, const unsigned short* __restrict__ Wp,
    unsigned short* __restrict__ qb, float* __restrict__ kf,
    unsigned short* __restrict__ vb, int M, int K) {
  const int Nn = 3072;
  __shared__ unsigned short Asm[128 * 32];
  __shared__ unsigned short Bsm[4 * 128 * 8];

  const int tid = threadIdx.x;
  const int lane = tid & 63;
  const int w = tid >> 6;
  const int nb = Nn >> 7;  // 24
  const int nwg = gridDim.x;
  const int cpx = nwg >> 3;
  int bid = blockIdx.x;
  bid = (bid & 7) * cpx + (bid >> 3);
  const int by = bid / nb, bx = bid % nb;
  const int m0 = by * 128, n0 = bx * 128;
  const int wr = w >> 1, wc = w & 1;

  f32x4 acc[4][4];
#pragma unroll
  for (int i = 0; i < 4; ++i)
#pragma unroll
    for (int j = 0; j < 4; ++j) acc[i][j] = (f32x4){0.f, 0.f, 0.f, 0.f};

  const int rA0 = w * 16 + (lane >> 2);
  const int rA1 = (w + 4) * 16 + (lane >> 2);
  const int sA0 = (lane & 3) ^ ((rA0 >> 1) & 3);
  const int sA1 = (lane & 3) ^ ((rA1 >> 1) & 3);
  const unsigned short* gA0 = A + (size_t)(m0 + rA0) * K + sA0 * 8;
  const unsigned short* gA1 = A + (size_t)(m0 + rA1) * K + sA1 * 8;
  const unsigned short* gB0 = Wp + (size_t)(w >> 1) * Nn * 8 +
                              (size_t)(n0 + (w & 1) * 64 + lane) * 8;
  const unsigned short* gB1 = Wp + (size_t)((w + 4) >> 1) * Nn * 8 +
                              (size_t)(n0 + ((w + 4) & 1) * 64 + lane) * 8;

  int offA[4], offB[4];
#pragma unroll
  for (int m = 0; m < 4; ++m) {
    const int rowf = wr * 64 + m * 16 + (lane & 15);
    const int sp = (lane >> 4) ^ ((rowf >> 1) & 3);
    offA[m] = rowf * 32 + sp * 8;
  }
#pragma unroll
  for (int n = 0; n < 4; ++n) {
    const int colf = wc * 64 + n * 16 + (lane & 15);
    offB[n] = (lane >> 4) * 1024 + colf * 8;
  }

  for (int kt = 0; kt < K; kt += 32) {
    const size_t kB = (size_t)(kt >> 3) * Nn * 8;
    __builtin_amdgcn_global_load_lds(AS1(gA0 + kt), AS3(&Asm[w * 512]), 16, 0, 0);
    __builtin_amdgcn_global_load_lds(AS1(gA1 + kt), AS3(&Asm[(w + 4) * 512]), 16, 0, 0);
    __builtin_amdgcn_global_load_lds(AS1(gB0 + kB), AS3(&Bsm[w * 512]), 16, 0, 0);
    __builtin_amdgcn_global_load_lds(AS1(gB1 + kB), AS3(&Bsm[(w + 4) * 512]), 16, 0, 0);
    __syncthreads();
    bf16x8 af[4], bfr[4];
#pragma unroll
    for (int m = 0; m < 4; ++m) af[m] = *(const bf16x8*)&Asm[offA[m]];
#pragma unroll
    for (int n = 0; n < 4; ++n) bfr[n] = *(const bf16x8*)&Bsm[offB[n]];
#pragma unroll
    for (int m = 0; m < 4; ++m)
#pragma unroll
      for (int n = 0; n < 4; ++n)
        acc[m][n] = __builtin_amdgcn_mfma_f32_16x16x32_bf16(af[m], bfr[n], acc[m][n], 0, 0, 0);
    __syncthreads();
  }

  const int crow = (lane >> 4) * 4;
  const int ccol = lane & 15;
  const int slice = bx >> 3;  // block-uniform: 0=q,1=k,2=v
#pragma unroll
  for (int m = 0; m < 4; ++m)
#pragma unroll
    for (int n = 0; n < 4; ++n) {
#pragma unroll
      for (int r = 0; r < 4; ++r) {
        float vv = acc[m][n][r];
        const int row = m0 + wr * 64 + m * 16 + crow + r;
        const int lcol = (n0 & 1023) + wc * 64 + n * 16 + ccol;
        const size_t idx = (size_t)row * 1024 + lcol;
        if (slice == 0) {
          vv = vv / (1.f + __expf(-vv));
          qb[idx] = f2bf(vv);
        } else if (slice == 1) {
          kf[idx] = vv;
        } else {
          vb[idx] = f2bf(vv);
        }
      }
    }
}

// ---------- MFMA bf16 GEMM (Wo): f32 out ----------
__global__ __launch_bounds__(256) void gemm_bf16(
    const unsigned short* __restrict__ A, const unsigned short* __restrict__ Wp,
    float* __restrict__ Cf, int M, int K, int Nn) {
  __shared__ unsigned short Asm[128 * 32];
  __shared__ unsigned short Bsm[4 * 128 * 8];

  const int tid = threadIdx.x;
  const int lane = tid & 63;
  const int w = tid >> 6;
  const int nb = Nn >> 7;
  const int nwg = gridDim.x;
  const int cpx = nwg >> 3;
  int bid = blockIdx.x;
  bid = (bid & 7) * cpx + (bid >> 3);
  const int by = bid / nb, bx = bid % nb;
  const int m0 = by * 128, n0 = bx * 128;
  const int wr = w >> 1, wc = w & 1;

  f32x4 acc[4][4];
#pragma unroll
  for (int i = 0; i < 4; ++i)
#pragma unroll
    for (int j = 0; j < 4; ++j) acc[i][j] = (f32x4){0.f, 0.f, 0.f, 0.f};

  const int rA0 = w * 16 + (lane >> 2);
  const int rA1 = (w + 4) * 16 + (lane >> 2);
  const int sA0 = (lane & 3) ^ ((rA0 >> 1) & 3);
  const int sA1 = (lane & 3) ^ ((rA1 >> 1) & 3);
  const unsigned short* gA0 = A + (size_t)(m0 + rA0) * K + sA0 * 8;
  const unsigned short* gA1 = A + (size_t)(m0 + rA1) * K + sA1 * 8;
  const unsigned short* gB0 = Wp + (size_t)(w >> 1) * Nn * 8 +
                              (size_t)(n0 + (w & 1) * 64 + lane) * 8;
  const unsigned short* gB1 = Wp + (size_t)((w + 4) >> 1) * Nn * 8 +
                              (size_t)(n0 + ((w + 4) & 1) * 64 + lane) * 8;

  int offA[4], offB[4];
#pragma unroll
  for (int m = 0; m < 4; ++m) {
    const int rowf = wr * 64 + m * 16 + (lane & 15);
    const int sp = (lane >> 4) ^ ((rowf >> 1) & 3);
    offA[m] = rowf * 32 + sp * 8;
  }
#pragma unroll
  for (int n = 0; n < 4; ++n) {
    const int colf = wc * 64 + n * 16 + (lane & 15);
    offB[n] = (lane >> 4) * 1024 + colf * 8;
  }

  for (int kt = 0; kt < K; kt += 32) {
    const size_t kB = (size_t)(kt >> 3) * Nn * 8;
    __builtin_amdgcn_global_load_lds(AS1(gA0 + kt), AS3(&Asm[w * 512]), 16, 0, 0);
    __builtin_amdgcn_global_load_lds(AS1(gA1 + kt), AS3(&Asm[(w + 4) * 512]), 16, 0, 0);
    __builtin_amdgcn_global_load_lds(AS1(gB0 + kB), AS3(&Bsm[w * 512]), 16, 0, 0);
    __builtin_amdgcn_global_load_lds(AS1(gB1 + kB), AS3(&Bsm[(w + 4) * 512]), 16, 0, 0);
    __syncthreads();
    bf16x8 af[4], bfr[4];
#pragma unroll
    for (int m = 0; m < 4; ++m) af[m] = *(const bf16x8*)&Asm[offA[m]];
#pragma unroll
    for (int n = 0; n < 4; ++n) bfr[n] = *(const bf16x8*)&Bsm[offB[n]];
#pragma unroll
    for (int m = 0; m < 4; ++m)
#pragma unroll
      for (int n = 0; n < 4; ++n)
        acc[m][n] = __builtin_amdgcn_mfma_f32_16x16x32_bf16(af[m], bfr[n], acc[m][n], 0, 0, 0);
    __syncthreads();
  }

  const int crow = (lane >> 4) * 4;
  const int ccol = lane & 15;
#pragma unroll
  for (int m = 0; m < 4; ++m)
#pragma unroll
    for (int n = 0; n < 4; ++n) {
#pragma unroll
      for (int r = 0; r < 4; ++r) {
        Cf[(size_t)(m0 + wr * 64 + m * 16 + crow + r) * Nn +
           n0 + wc * 64 + n * 16 + ccol] = acc[m][n][r];
      }
    }
}

// ---------- 3-pass parallel cumlogsumexp scan (sum-of-exp form) ----------
__global__ __launch_bounds__(256) void scan_pass_a(const float* __restrict__ k_raw,
                                                   float* __restrict__ T) {
  const int g = blockIdx.x * 256 + threadIdx.x;
  const int hd = g & 63;
  const int c = (g >> 6) & 31;
  const int bh = g >> 11;
  const int b = bh >> 4, h = bh & 15;
  const size_t base = (size_t)b * N_ * D_ + (size_t)(c * 64) * D_ + h * HD_ + hd;
  float sum = 0.f;
  for (int j0 = 0; j0 < 64; j0 += 8) {
    float kr[8];
#pragma unroll
    for (int e = 0; e < 8; ++e) kr[e] = k_raw[base + (size_t)(j0 + e) * D_];
#pragma unroll
    for (int e = 0; e < 8; ++e) sum += __expf(kr[e]);
  }
  T[(size_t)(bh * 64 + hd) * 32 + c] = __logf(sum);
}

__global__ void scan_pass_b(const float* __restrict__ T, float* __restrict__ Pf) {
  const int ch = blockIdx.x * 256 + threadIdx.x;
  const float* t = &T[(size_t)ch * 32];
  float* p = &Pf[(size_t)ch * 32];
  float run = 0.f;
  for (int c = 0; c < 32; ++c) {
    p[c] = run;
    run = lseop_fast(run, t[c]);
  }
}

// Pass C: e_i = exp(k_i - P); S = cumsum(e); G = -ln(1+S) (f16); kg = e_i * rope.
__global__ __launch_bounds__(256) void scan_pass_c(const float* __restrict__ k_raw,
    const float* __restrict__ Pf, const float* __restrict__ ropeT,
    unsigned short* __restrict__ G_h, unsigned short* __restrict__ kg_g,
    float* __restrict__ glast_g) {
  const int g = blockIdx.x * 256 + threadIdx.x;
  const int hd = g & 63;
  const int c = (g >> 6) & 31;
  const int bh = g >> 11;
  const int b = bh >> 4, h = bh & 15;
  const size_t base = (size_t)b * N_ * D_ + (size_t)(c * 64) * D_ + h * HD_ + hd;
  const size_t gb = ((size_t)bh * N_ + c * 64) * 64 + hd;
  const size_t kb = ((size_t)bh * N_ + c * 64) * 128 + hd;
  const size_t rb = (size_t)(c * 64) * 128 + hd;
  const float P = Pf[(size_t)(bh * 64 + hd) * 32 + c];
  float S = 0.f, G = 0.f;
  for (int j0 = 0; j0 < 64; j0 += 8) {
    float kr[8], cv[8], sv[8];
#pragma unroll
    for (int e = 0; e < 8; ++e) kr[e] = k_raw[base + (size_t)(j0 + e) * D_];
#pragma unroll
    for (int e = 0; e < 8; ++e) {
      cv[e] = ropeT[rb + (size_t)(j0 + e) * 128];
      sv[e] = ropeT[rb + (size_t)(j0 + e) * 128 + 64];
    }
#pragma unroll
    for (int e = 0; e < 8; ++e) {
      float ei = __expf(kr[e] - P);
      S += ei;
      G = -__logf(1.f + S);
      G_h[gb + (size_t)(j0 + e) * 64] = f2h(G);
      kg_g[kb + (size_t)(j0 + e) * 128] = f2bf(ei * cv[e]);
      kg_g[kb + (size_t)(j0 + e) * 128 + 64] = f2bf(ei * sv[e]);
    }
  }
  glast_g[(size_t)(bh * 32 + c) * 64 + hd] = G;
}

// ---------- GLA pass A (MFMA) ----------
__global__ __launch_bounds__(256) void gla_a(
    const unsigned short* __restrict__ qs, const unsigned short* __restrict__ kg_g,
    const unsigned short* __restrict__ G_h, const unsigned short* __restrict__ v_bf,
    const float* __restrict__ ropeT, const float* __restrict__ glast_g,
    unsigned short* __restrict__ qg_p, unsigned short* __restrict__ U,
    unsigned short* __restrict__ o_bf) {
  __shared__ unsigned short kg_l[64 * 128];   // swizzled; reused as U_l
  __shared__ unsigned short kgT_l[128 * 72];  // [j][s]
  __shared__ unsigned short vT_l[64 * 72];    // [d][s]
  __shared__ unsigned short A_l[64 * 72];     // [c][s] masked

  const int bid = blockIdx.x;
  const int bh = bid >> 5, c = bid & 31;
  const int b = bh >> 4, h = bh & 15;
  const int t0 = c * 64;
  const int tid = threadIdx.x;
  const int lane = tid & 63, w = tid >> 6;
  const int lr = lane & 15, lg = lane >> 4;

  const size_t qv_base = ((size_t)(b * N_ + t0) * H_ + h) * 64;
  const size_t kg_base = ((size_t)bh * N_ + t0) * 128;

#pragma unroll
  for (int u = 0; u < 4; ++u) {
    const int flat = u * 256 + tid;
    const int r = flat >> 4, sl = flat & 15;
    u16x8 src = *(const u16x8*)&kg_g[kg_base + (size_t)r * 128 + sl * 8];
    *(u16x8*)&kg_l[r * 128 + ((sl ^ (r & 7)) * 8)] = src;
  }
  {
    const int r = tid >> 2, d0 = (tid & 3) * 16;
    u16x8 a = *(const u16x8*)&v_bf[qv_base + (size_t)r * (H_ * 64) + d0];
    u16x8 b2 = *(const u16x8*)&v_bf[qv_base + (size_t)r * (H_ * 64) + d0 + 8];
#pragma unroll
    for (int e = 0; e < 8; ++e) {
      vT_l[(d0 + e) * 72 + r] = a[e];
      vT_l[(d0 + 8 + e) * 72 + r] = b2[e];
    }
  }
  __syncthreads();
  {
    const int j = tid >> 1, sh = (tid & 1) * 32;
#pragma unroll
    for (int u = 0; u < 4; ++u) {
      union { unsigned short us[8]; u16x8 v; } tv;
#pragma unroll
      for (int e = 0; e < 8; ++e) {
        const int s = sh + 8 * u + e;
        tv.us[e] = kg_l[s * 128 + (((j >> 3) ^ (s & 7)) * 8) + (j & 7)];
      }
      *(u16x8*)&kgT_l[j * 72 + sh + 8 * u] = tv.v;
    }
  }
  __syncthreads();

  // ---- qg build (in-fragment) + global qg_p store ----
  bf16x8 af[4];
  {
    const int r = 16 * w + lr;
#pragma unroll
    for (int ks = 0; ks < 4; ++ks) {
      const int jb = 32 * ks + 8 * lg;
      const int jq = jb & 63;
      u16x8 q8 = *(const u16x8*)&qs[qv_base + (size_t)r * (H_ * 64) + jq];
      u16x8 gh8 = *(const u16x8*)&G_h[((size_t)bh * N_ + t0 + r) * 64 + jq];
      float4 r0 = *(const float4*)&ropeT[(size_t)(t0 + r) * 128 + jb];
      float4 r1 = *(const float4*)&ropeT[(size_t)(t0 + r) * 128 + jb + 4];
      float rr[8] = {r0.x, r0.y, r0.z, r0.w, r1.x, r1.y, r1.z, r1.w};
      union { unsigned short us[8]; bf16x8 v; u16x8 uv; } pk;
#pragma unroll
      for (int e = 0; e < 8; ++e)
        pk.us[e] = f2bf(bf2f(q8[e]) * rr[e] * __expf(h2f(gh8[e])));
      af[ks] = pk.v;
      *(u16x8*)&qg_p[((((size_t)bid * 4 + w) * 4 + ks) * 64 + lane) * 8] = pk.uv;
    }
  }
  // ---- m1: A = qg @ kg^T ----
  f32x4 acc1[4];
#pragma unroll
  for (int n = 0; n < 4; ++n) acc1[n] = (f32x4){0.f, 0.f, 0.f, 0.f};
#pragma unroll
  for (int n = 0; n < 4; ++n) {
    const int s = 16 * n + lr;
#pragma unroll
    for (int ks = 0; ks < 4; ++ks) {
      bf16x8 bk = *(const bf16x8*)&kg_l[s * 128 + (((lg + 4 * ks) ^ (s & 7)) * 8)];
      acc1[n] = __builtin_amdgcn_mfma_f32_16x16x32_bf16(af[ks], bk, acc1[n], 0, 0, 0);
    }
  }
#pragma unroll
  for (int n = 0; n < 4; ++n) {
    const int s = 16 * n + lr;
#pragma unroll
    for (int reg = 0; reg < 4; ++reg) {
      const int cr = 16 * w + 4 * lg + reg;
      A_l[cr * 72 + s] = (s <= cr) ? f2bf(acc1[n][reg]) : (unsigned short)0;
    }
  }
  // ---- m2: Urows d = v^T @ kg ----
  f32x4 acc2[8];
#pragma unroll
  for (int n = 0; n < 8; ++n) acc2[n] = (f32x4){0.f, 0.f, 0.f, 0.f};
#pragma unroll
  for (int ks = 0; ks < 2; ++ks) {
    const int s0 = 32 * ks + 8 * lg;
    bf16x8 av = *(const bf16x8*)&vT_l[(16 * w + lr) * 72 + s0];
#pragma unroll
    for (int n = 0; n < 8; ++n) {
      bf16x8 bk = *(const bf16x8*)&kgT_l[(16 * n + lr) * 72 + s0];
      acc2[n] = __builtin_amdgcn_mfma_f32_16x16x32_bf16(av, bk, acc2[n], 0, 0, 0);
    }
  }
  __syncthreads();
  // ---- phase D: U_l writes; m3 = A @ v; o write (bf16) ----
  float es[4];
#pragma unroll
  for (int n = 0; n < 4; ++n)
    es[n] = __expf(glast_g[(size_t)bid * 64 + 16 * n + lr]);
#pragma unroll
  for (int n = 0; n < 8; ++n) {
    const int j = 16 * n + lr;
    const float e = es[n & 3];
#pragma unroll
    for (int reg = 0; reg < 4; ++reg)
      kg_l[(16 * w + 4 * lg + reg) * 128 + j] = f2bf(acc2[n][reg] * e);
  }
  f32x4 acc3[4];
#pragma unroll
  for (int n = 0; n < 4; ++n) acc3[n] = (f32x4){0.f, 0.f, 0.f, 0.f};
#pragma unroll
  for (int ks = 0; ks < 2; ++ks) {
    const int s0 = 32 * ks + 8 * lg;
    bf16x8 aA = *(const bf16x8*)&A_l[(16 * w + lr) * 72 + s0];
#pragma unroll
    for (int n = 0; n < 4; ++n) {
      bf16x8 bV = *(const bf16x8*)&vT_l[(16 * n + lr) * 72 + s0];
      acc3[n] = __builtin_amdgcn_mfma_f32_16x16x32_bf16(aA, bV, acc3[n], 0, 0, 0);
    }
  }
#pragma unroll
  for (int n = 0; n < 4; ++n)
#pragma unroll
    for (int reg = 0; reg < 4; ++reg)
      o_bf[qv_base + (size_t)(16 * w + 4 * lg + reg) * (H_ * 64) + 16 * n + lr] =
          f2bf(acc3[n][reg]);
  __syncthreads();
#pragma unroll
  for (int u = 0; u < 4; ++u) {
    const int flat = u * 256 + tid;
    const int d = flat >> 4, sl = flat & 15;
    *(u16x8*)&U[((size_t)bid * 64 + d) * 128 + sl * 8] =
        *(const u16x8*)&kg_l[d * 128 + sl * 8];
  }
}

// ---------- GLA pass B: exclusive chunk scan (in place) ----------
__global__ __launch_bounds__(256) void gla_b(unsigned short* __restrict__ U,
                                             const float* __restrict__ glast_g) {
  const int t = blockIdx.x * 256 + threadIdx.x;
  const int j4 = t & 31;
  const int d = (t >> 5) & 63;
  const int bh = t >> 11;
  const int jj0 = (4 * j4) & 63;
  float s0 = 0.f, s1 = 0.f, s2 = 0.f, s3 = 0.f;
  for (int c = 0; c < 32; ++c) {
    const size_t ub = ((size_t)((bh * 32 + c) * 64 + d)) * 128 + 4 * j4;
    ushort4 uv = *(const ushort4*)&U[ub];
    float4 g4 = *(const float4*)&glast_g[(size_t)(bh * 32 + c) * 64 + jj0];
    ushort4 pv;
    pv.x = f2bf(s0); pv.y = f2bf(s1); pv.z = f2bf(s2); pv.w = f2bf(s3);
    *(ushort4*)&U[ub] = pv;
    s0 = s0 * __expf(g4.x) + bf2f(uv.x);
    s1 = s1 * __expf(g4.y) + bf2f(uv.y);
    s2 = s2 * __expf(g4.z) + bf2f(uv.z);
    s3 = s3 * __expf(g4.w) + bf2f(uv.w);
  }
}

// ---------- GLA pass C (MFMA): o += qg @ S_{c-1} (bf16 RMW) ----------
__global__ __launch_bounds__(256) void gla_c(
    const unsigned short* __restrict__ qg_p, const unsigned short* __restrict__ S,
    unsigned short* __restrict__ o_bf) {
  __shared__ unsigned short S_l[64 * 128];
  const int bid = blockIdx.x;
  const int bh = bid >> 5, c = bid & 31;
  const int b = bh >> 4, h = bh & 15;
  const int t0 = c * 64;
  const int tid = threadIdx.x;
  const int lane = tid & 63, w = tid >> 6;
  const int lr = lane & 15, lg = lane >> 4;
  const size_t s_base = (size_t)bid * 64 * 128;
  const size_t o_base = ((size_t)(b * N_ + t0) * H_ + h) * 64;

#pragma unroll
  for (int u = 0; u < 4; ++u) {
    const int flat = u * 256 + tid;
    const int d = flat >> 4, sl = flat & 15;
    u16x8 src = *(const u16x8*)&S[s_base + (size_t)d * 128 + sl * 8];
    *(u16x8*)&S_l[d * 128 + ((sl ^ (d & 7)) * 8)] = src;
  }
  __syncthreads();
  bf16x8 af[4];
#pragma unroll
  for (int ks = 0; ks < 4; ++ks)
    af[ks] = *(const bf16x8*)&qg_p[((((size_t)bid * 4 + w) * 4 + ks) * 64 + lane) * 8];
  f32x4 acc[4];
#pragma unroll
  for (int n = 0; n < 4; ++n) acc[n] = (f32x4){0.f, 0.f, 0.f, 0.f};
#pragma unroll
  for (int n = 0; n < 4; ++n) {
    const int d = 16 * n + lr;
#pragma unroll
    for (int ks = 0; ks < 4; ++ks) {
      bf16x8 bk = *(const bf16x8*)&S_l[d * 128 + (((lg + 4 * ks) ^ (d & 7)) * 8)];
      acc[n] = __builtin_amdgcn_mfma_f32_16x16x32_bf16(af[ks], bk, acc[n], 0, 0, 0);
    }
  }
#pragma unroll
  for (int n = 0; n < 4; ++n)
#pragma unroll
    for (int reg = 0; reg < 4; ++reg) {
      const size_t idx = o_base + (size_t)(16 * w + 4 * lg + reg) * (H_ * 64) + 16 * n + lr;
      o_bf[idx] = f2bf(bf2f(o_bf[idx]) + acc[n][reg]);
    }
}

// ---------- gate+norm: one wave per row, reduction-free gate; o in bf16 ----------
__global__ __launch_bounds__(256) void gate_norm2(
    const float* __restrict__ tg, const float* __restrict__ Wg2,
    const float* __restrict__ nw, const unsigned short* __restrict__ o_bf,
    unsigned short* __restrict__ og) {
  const int w = threadIdx.x >> 6, lane = threadIdx.x & 63;
  const int row = blockIdx.x * 4 + w;
  float tgv[16];
  const float* tp = &tg[(size_t)row * 16];
#pragma unroll
  for (int hh = 0; hh < 16; ++hh) tgv[hh] = tp[hh];
  float ogr[4][4];
  float ssq = 0.f;
#pragma unroll
  for (int u = 0; u < 4; ++u) {
    const int d0 = u * 256 + lane * 4;
    ushort4 o4 = *(const ushort4*)&o_bf[(size_t)row * 1024 + d0];
    float oa[4] = {bf2f(o4.x), bf2f(o4.y), bf2f(o4.z), bf2f(o4.w)};
    float sgx = 0.f, sgy = 0.f, sgz = 0.f, sgw = 0.f;
#pragma unroll
    for (int hh = 0; hh < 16; ++hh) {
      float4 w4 = *(const float4*)&Wg2[hh * 1024 + d0];
      sgx += tgv[hh] * w4.x; sgy += tgv[hh] * w4.y;
      sgz += tgv[hh] * w4.z; sgw += tgv[hh] * w4.w;
    }
    ogr[u][0] = oa[0] / (1.f + __expf(-sgx));
    ogr[u][1] = oa[1] / (1.f + __expf(-sgy));
    ogr[u][2] = oa[2] / (1.f + __expf(-sgz));
    ogr[u][3] = oa[3] / (1.f + __expf(-sgw));
    ssq += ogr[u][0] * ogr[u][0] + ogr[u][1] * ogr[u][1] +
           ogr[u][2] * ogr[u][2] + ogr[u][3] * ogr[u][3];
  }
#pragma unroll
  for (int off = 32; off > 0; off >>= 1) ssq += __shfl_xor(ssq, off);
  const float rinv = rsqrtf(ssq * (1.f / 1024.f) + 1e-6f);
#pragma unroll
  for (int u = 0; u < 4; ++u) {
    const int d0 = u * 256 + lane * 4;
    float4 nw4 = *(const float4*)&nw[d0];
    ushort4 st;
    st.x = f2bf(ogr[u][0] * rinv * nw4.x);
    st.y = f2bf(ogr[u][1] * rinv * nw4.y);
    st.z = f2bf(ogr[u][2] * rinv * nw4.z);
    st.w = f2bf(ogr[u][3] * rinv * nw4.w);
    *(ushort4*)&og[(size_t)row * 1024 + d0] = st;
  }
}

extern "C" void kernel_launch(void* const* d_in, const int* in_sizes, int n_in,
                              void* d_out, int out_size, void* d_ws, size_t ws_size,
                              hipStream_t stream) {
  const float* x   = (const float*)d_in[0];
  const float* Wq  = (const float*)d_in[1];
  const float* Wk  = (const float*)d_in[2];
  const float* Wv  = (const float*)d_in[3];
  const float* Wo  = (const float*)d_in[4];
  const float* Wg1 = (const float*)d_in[5];
  const float* Wg2 = (const float*)d_in[6];
  const float* nw  = (const float*)d_in[7];
  float* out = (float*)d_out;
  float* ws  = (float*)d_ws;

  const size_t P = (size_t)B_ * N_ * D_;  // 8,388,608
  float* k_raw = ws;                                      // [0,P); later U_buf
  unsigned short* o_bf = (unsigned short*)(ws + P);       // P u16
  unsigned short* G_h  = (unsigned short*)(ws + 2 * P);   // P u16 (f16)
  unsigned short* qg_p = (unsigned short*)(ws + 3 * P);   // 2P u16
  unsigned short* kg_g = (unsigned short*)(ws + 4 * P);   // 2P u16
  unsigned short* v_bf = (unsigned short*)(ws + 5 * P);            // P u16
  unsigned short* q_bf = (unsigned short*)(ws + 5 * P + P / 2);    // P u16
  float* ropeT = ws + 6 * P;                                       // 262144
  float* T_buf = ws + 6 * P + 524288;                              // 131072
  float* P_buf = T_buf + 131072;                                   // 131072
  unsigned short* Wg1p = (unsigned short*)(ws + 6 * P + 786432);   // 16384 u16
  float* tg_buf = ws + 6 * P + 794624;                             // 131072
  unsigned short* x_bf = (unsigned short*)(ws + 13 * P / 2);       // P u16
  unsigned short* og_bf = x_bf;  // x_bf dead before gate_norm2 writes og
  unsigned short* Wqkv_p = (unsigned short*)(ws + 7 * P);          // 3145728 u16
  unsigned short* Wo_p = (unsigned short*)(ws + 7 * P + 1572864);  // 1048576 u16
  float* glast_g = ws + 7 * P + 2097152;                           // 131072
  unsigned short* U_buf = (unsigned short*)k_raw;

  const int M = B_ * N_;
  const int ggrid = (M / 128) * (D_ / 128);       // 512 (Wo)
  const int qkvgrid = (M / 128) * (3 * D_ / 128); // 1536

  cast_x_bf16<<<(int)(P / 2048), 256, 0, stream>>>(x, x_bf);
  rope_fill<<<512, 256, 0, stream>>>(ropeT);
  cast_w_pack<<<512, 256, 0, stream>>>(Wq, Wqkv_p, 0, 3072);
  cast_w_pack<<<512, 256, 0, stream>>>(Wk, Wqkv_p, 1024, 3072);
  cast_w_pack<<<512, 256, 0, stream>>>(Wv, Wqkv_p, 2048, 3072);
  cast_w_pack<<<512, 256, 0, stream>>>(Wo, Wo_p, 0, 1024);
  pack_wg1<<<8, 256, 0, stream>>>(Wg1, Wg1p);
  gate_logits<<<M / 64, 256, 0, stream>>>(x_bf, Wg1p, tg_buf);
  gemm_qkv<<<qkvgrid, 256, 0, stream>>>(x_bf, Wqkv_p, q_bf, k_raw, v_bf, M, D_);
  scan_pass_a<<<512, 256, 0, stream>>>(k_raw, T_buf);
  scan_pass_b<<<16, 256, 0, stream>>>(T_buf, P_buf);
  scan_pass_c<<<512, 256, 0, stream>>>(k_raw, P_buf, ropeT, G_h, kg_g, glast_g);
  gla_a<<<2048, 256, 0, stream>>>(q_bf, kg_g, G_h, v_bf, ropeT, glast_g, qg_p, U_buf, o_bf);
  gla_b<<<512, 256, 0, stream>>>(U_buf, glast_g);
  gla_c<<<2048, 256, 0, stream>>>(qg_p, U_buf, o_bf);
  gate_norm2<<<M / 4, 256, 0, stream>>>(tg_buf, Wg2, nw, o_bf, og_bf);
  gemm_bf16<<<ggrid, 256, 0, stream>>>(og_bf, Wo_p, out, M, D_, D_);
}

// Round 9
// 229.879 us; speedup vs baseline: 11.3974x; 1.1389x over previous
//
#include <hip/hip_runtime.h>
#include <hip/hip_bf16.h>
#include <math.h>

#define B_ 4
#define N_ 2048
#define D_ 1024
#define H_ 16
#define HD_ 64

typedef __attribute__((ext_vector_type(8))) short bf16x8;
typedef __attribute__((ext_vector_type(8))) unsigned short u16x8;
typedef __attribute__((ext_vector_type(4))) float f32x4;

#define AS1(p) ((const __attribute__((address_space(1))) void*)(p))
#define AS3(p) ((__attribute__((address_space(3))) void*)(p))

__device__ inline float bf2f(unsigned short u) { return __uint_as_float(((unsigned)u) << 16); }
__device__ inline unsigned short f2bf(float f) {
  unsigned u = __float_as_uint(f);
  return (unsigned short)((u + 0x7fffu + ((u >> 16) & 1u)) >> 16);
}
__device__ inline unsigned short f2h(float f) {
  _Float16 h = (_Float16)f; unsigned short u; __builtin_memcpy(&u, &h, 2); return u;
}
__device__ inline float h2f(unsigned short u) {
  _Float16 h; __builtin_memcpy(&h, &u, 2); return (float)h;
}
__device__ inline float lseop_fast(float a, float b) {
  float mx = fmaxf(a, b), mn = fminf(a, b);
  return mx + __logf(1.f + __expf(mn - mx));
}

// ---------- cast x (f32) -> bf16 row-major ----------
__global__ __launch_bounds__(256) void cast_x_bf16(const float* __restrict__ x,
                                                   unsigned short* __restrict__ xb) {
  const int t = blockIdx.x * 256 + threadIdx.x;
  float4 a = ((const float4*)x)[(size_t)t * 2];
  float4 b = ((const float4*)x)[(size_t)t * 2 + 1];
  union { unsigned short u[8]; uint4 q; } pk;
  pk.u[0] = f2bf(a.x); pk.u[1] = f2bf(a.y); pk.u[2] = f2bf(a.z); pk.u[3] = f2bf(a.w);
  pk.u[4] = f2bf(b.x); pk.u[5] = f2bf(b.y); pk.u[6] = f2bf(b.z); pk.u[7] = f2bf(b.w);
  ((uint4*)xb)[t] = pk.q;
}

// ---------- all 4 weight casts in one launch: 2048 blocks, 512 per weight ----------
__global__ __launch_bounds__(256) void cast_w_all(
    const float* __restrict__ Wq, const float* __restrict__ Wk,
    const float* __restrict__ Wv, const float* __restrict__ Wo,
    unsigned short* __restrict__ Wqkv_p, unsigned short* __restrict__ Wo_p) {
  const int bid = blockIdx.x;
  const int which = bid >> 9;
  const float* W = (which == 0) ? Wq : (which == 1) ? Wk : (which == 2) ? Wv : Wo;
  const int col0 = (which == 1) ? 1024 : (which == 2) ? 2048 : 0;
  const int Ntot = (which == 3) ? 1024 : 3072;
  unsigned short* dst = (which == 3) ? Wo_p : Wqkv_p;
  const int t = (bid & 511) * 256 + threadIdx.x;
  const int kg = t >> 10, n = t & 1023;
  union { unsigned short u[8]; uint4 q; } pk;
#pragma unroll
  for (int r = 0; r < 8; ++r)
    pk.u[r] = f2bf(W[(size_t)(kg * 8 + r) * 1024 + n]);
  *(uint4*)&dst[((size_t)kg * Ntot + col0 + n) * 8] = pk.q;
}

// ---------- pack Wg1 (f32 [1024][16]) -> bf16 [(K/8)][16][8] ----------
__global__ __launch_bounds__(256) void pack_wg1(const float* __restrict__ Wg1,
                                                unsigned short* __restrict__ Wp) {
  const int t = blockIdx.x * 256 + threadIdx.x;  // 2048 = 128 kg * 16 hh
  const int kg = t >> 4, hh = t & 15;
  union { unsigned short us[8]; u16x8 v; } pk;
#pragma unroll
  for (int r = 0; r < 8; ++r)
    pk.us[r] = f2bf(Wg1[(size_t)(kg * 8 + r) * 16 + hh]);
  *(u16x8*)&Wp[((size_t)kg * 16 + hh) * 8] = pk.v;
}

// ---------- gate logits: tg[M][16] = x_bf @ Wg1_bf (MFMA) ----------
__global__ __launch_bounds__(256) void gate_logits(
    const unsigned short* __restrict__ x_bf, const unsigned short* __restrict__ Wg1p,
    float* __restrict__ tg) {
  __shared__ unsigned short Wl[128 * 16 * 8];  // 32 KB
  const int tid = threadIdx.x;
  const int lane = tid & 63, w = tid >> 6;
  const int lr = lane & 15, lg = lane >> 4;
#pragma unroll
  for (int u = 0; u < 8; ++u) {
    const int flat = u * 256 + tid;
    *(u16x8*)&Wl[flat * 8] = *(const u16x8*)&Wg1p[(size_t)flat * 8];
  }
  __syncthreads();
  const int row = blockIdx.x * 64 + w * 16 + lr;
  f32x4 acc = (f32x4){0.f, 0.f, 0.f, 0.f};
  for (int ks = 0; ks < 32; ++ks) {
    bf16x8 a = *(const bf16x8*)&x_bf[(size_t)row * 1024 + ks * 32 + lg * 8];
    bf16x8 b = *(const bf16x8*)&Wl[((ks * 4 + lg) * 16 + lr) * 8];
    acc = __builtin_amdgcn_mfma_f32_16x16x32_bf16(a, b, acc, 0, 0, 0);
  }
  const int orow = blockIdx.x * 64 + w * 16 + 4 * lg;
#pragma unroll
  for (int reg = 0; reg < 4; ++reg)
    tg[(size_t)(orow + reg) * 16 + lr] = acc[reg];
}

// ---------- rope table ----------
__global__ __launch_bounds__(256) void rope_fill(float* __restrict__ ropeT) {
  const int t = blockIdx.x * 256 + threadIdx.x;  // N*64
  const int n = t >> 6, hd = t & 63;
  const float freq = expf((float)hd * -0.28782313662425575f);
  float s, c;
  sincosf((float)n * freq, &s, &c);
  ropeT[(size_t)n * 128 + hd] = c;
  ropeT[(size_t)n * 128 + 64 + hd] = s;
}

// ---------- fused QKV GEMM (double-buffered): routes q(silu,bf16)/k(f16 + chunk-sum T)/v(bf16)
__global__ __launch_bounds__(256) void gemm_qkv(
    const unsigned short* __restrict__ A, const unsigned short* __restrict__ Wp,
    unsigned short* __restrict__ qb, unsigned short* __restrict__ kh,
    unsigned short* __restrict__ vb, float* __restrict__ T, int M, int K) {
  const int Nn = 3072;
  __shared__ unsigned short Asm[2][128 * 32];
  __shared__ unsigned short Bsm[2][4 * 128 * 8];

  const int tid = threadIdx.x;
  const int lane = tid & 63;
  const int w = tid >> 6;
  const int nb = Nn >> 7;  // 24
  const int nwg = gridDim.x;
  const int cpx = nwg >> 3;
  int bid = blockIdx.x;
  bid = (bid & 7) * cpx + (bid >> 3);
  const int by = bid / nb, bx = bid % nb;
  const int m0 = by * 128, n0 = bx * 128;
  const int wr = w >> 1, wc = w & 1;

  f32x4 acc[4][4];
#pragma unroll
  for (int i = 0; i < 4; ++i)
#pragma unroll
    for (int j = 0; j < 4; ++j) acc[i][j] = (f32x4){0.f, 0.f, 0.f, 0.f};

  const int rA0 = w * 16 + (lane >> 2);
  const int rA1 = (w + 4) * 16 + (lane >> 2);
  const int sA0 = (lane & 3) ^ ((rA0 >> 1) & 3);
  const int sA1 = (lane & 3) ^ ((rA1 >> 1) & 3);
  const unsigned short* gA0 = A + (size_t)(m0 + rA0) * K + sA0 * 8;
  const unsigned short* gA1 = A + (size_t)(m0 + rA1) * K + sA1 * 8;
  const unsigned short* gB0 = Wp + (size_t)(w >> 1) * Nn * 8 +
                              (size_t)(n0 + (w & 1) * 64 + lane) * 8;
  const unsigned short* gB1 = Wp + (size_t)((w + 4) >> 1) * Nn * 8 +
                              (size_t)(n0 + ((w + 4) & 1) * 64 + lane) * 8;

  int offA[4], offB[4];
#pragma unroll
  for (int m = 0; m < 4; ++m) {
    const int rowf = wr * 64 + m * 16 + (lane & 15);
    const int sp = (lane >> 4) ^ ((rowf >> 1) & 3);
    offA[m] = rowf * 32 + sp * 8;
  }
#pragma unroll
  for (int n = 0; n < 4; ++n) {
    const int colf = wc * 64 + n * 16 + (lane & 15);
    offB[n] = (lane >> 4) * 1024 + colf * 8;
  }

  auto STAGE = [&](int buf, int t) {
    const int kt = t * 32;
    const size_t kB = (size_t)(kt >> 3) * Nn * 8;
    __builtin_amdgcn_global_load_lds(AS1(gA0 + kt), AS3(&Asm[buf][w * 512]), 16, 0, 0);
    __builtin_amdgcn_global_load_lds(AS1(gA1 + kt), AS3(&Asm[buf][(w + 4) * 512]), 16, 0, 0);
    __builtin_amdgcn_global_load_lds(AS1(gB0 + kB), AS3(&Bsm[buf][w * 512]), 16, 0, 0);
    __builtin_amdgcn_global_load_lds(AS1(gB1 + kB), AS3(&Bsm[buf][(w + 4) * 512]), 16, 0, 0);
  };

  const int NT = K >> 5;  // 32
  STAGE(0, 0);
  __syncthreads();
  int cur = 0;
  for (int t = 0; t < NT; ++t) {
    if (t + 1 < NT) STAGE(cur ^ 1, t + 1);
    bf16x8 af[4], bfr[4];
#pragma unroll
    for (int m = 0; m < 4; ++m) af[m] = *(const bf16x8*)&Asm[cur][offA[m]];
#pragma unroll
    for (int n = 0; n < 4; ++n) bfr[n] = *(const bf16x8*)&Bsm[cur][offB[n]];
#pragma unroll
    for (int m = 0; m < 4; ++m)
#pragma unroll
      for (int n = 0; n < 4; ++n)
        acc[m][n] = __builtin_amdgcn_mfma_f32_16x16x32_bf16(af[m], bfr[n], acc[m][n], 0, 0, 0);
    __syncthreads();
    cur ^= 1;
  }

  const int crow = (lane >> 4) * 4;
  const int ccol = lane & 15;
  const int slice = bx >> 3;  // block-uniform: 0=q,1=k,2=v
  if (slice == 1) {
    // k slice: f16 store + fused per-chunk exp-sum (replaces scan_pass_a)
#pragma unroll
    for (int n = 0; n < 4; ++n) {
      float se = 0.f;
#pragma unroll
      for (int m = 0; m < 4; ++m)
#pragma unroll
        for (int r = 0; r < 4; ++r) {
          float vv = acc[m][n][r];
          se += __expf(vv);
          kh[(size_t)(m0 + wr * 64 + m * 16 + crow + r) * 1024 +
             (n0 & 1023) + wc * 64 + n * 16 + ccol] = f2h(vv);
        }
      se += __shfl_xor(se, 16);
      se += __shfl_xor(se, 32);
      if ((lane >> 4) == 0) {
        const int bb = m0 >> 11;
        const int h = ((n0 & 1023) + wc * 64) >> 6;
        const int hd = n * 16 + ccol;
        const int c = ((m0 & 2047) >> 6) + wr;
        T[(size_t)((bb * 16 + h) * 64 + hd) * 32 + c] = __logf(se);
      }
    }
  } else {
#pragma unroll
    for (int m = 0; m < 4; ++m)
#pragma unroll
      for (int n = 0; n < 4; ++n)
#pragma unroll
        for (int r = 0; r < 4; ++r) {
          float vv = acc[m][n][r];
          const size_t idx = (size_t)(m0 + wr * 64 + m * 16 + crow + r) * 1024 +
                             (n0 & 1023) + wc * 64 + n * 16 + ccol;
          if (slice == 0) {
            vv = vv / (1.f + __expf(-vv));
            qb[idx] = f2bf(vv);
          } else {
            vb[idx] = f2bf(vv);
          }
        }
  }
}

// ---------- MFMA bf16 GEMM (Wo, double-buffered): f32 out ----------
__global__ __launch_bounds__(256) void gemm_bf16(
    const unsigned short* __restrict__ A, const unsigned short* __restrict__ Wp,
    float* __restrict__ Cf, int M, int K, int Nn) {
  __shared__ unsigned short Asm[2][128 * 32];
  __shared__ unsigned short Bsm[2][4 * 128 * 8];

  const int tid = threadIdx.x;
  const int lane = tid & 63;
  const int w = tid >> 6;
  const int nb = Nn >> 7;
  const int nwg = gridDim.x;
  const int cpx = nwg >> 3;
  int bid = blockIdx.x;
  bid = (bid & 7) * cpx + (bid >> 3);
  const int by = bid / nb, bx = bid % nb;
  const int m0 = by * 128, n0 = bx * 128;
  const int wr = w >> 1, wc = w & 1;

  f32x4 acc[4][4];
#pragma unroll
  for (int i = 0; i < 4; ++i)
#pragma unroll
    for (int j = 0; j < 4; ++j) acc[i][j] = (f32x4){0.f, 0.f, 0.f, 0.f};

  const int rA0 = w * 16 + (lane >> 2);
  const int rA1 = (w + 4) * 16 + (lane >> 2);
  const int sA0 = (lane & 3) ^ ((rA0 >> 1) & 3);
  const int sA1 = (lane & 3) ^ ((rA1 >> 1) & 3);
  const unsigned short* gA0 = A + (size_t)(m0 + rA0) * K + sA0 * 8;
  const unsigned short* gA1 = A + (size_t)(m0 + rA1) * K + sA1 * 8;
  const unsigned short* gB0 = Wp + (size_t)(w >> 1) * Nn * 8 +
                              (size_t)(n0 + (w & 1) * 64 + lane) * 8;
  const unsigned short* gB1 = Wp + (size_t)((w + 4) >> 1) * Nn * 8 +
                              (size_t)(n0 + ((w + 4) & 1) * 64 + lane) * 8;

  int offA[4], offB[4];
#pragma unroll
  for (int m = 0; m < 4; ++m) {
    const int rowf = wr * 64 + m * 16 + (lane & 15);
    const int sp = (lane >> 4) ^ ((rowf >> 1) & 3);
    offA[m] = rowf * 32 + sp * 8;
  }
#pragma unroll
  for (int n = 0; n < 4; ++n) {
    const int colf = wc * 64 + n * 16 + (lane & 15);
    offB[n] = (lane >> 4) * 1024 + colf * 8;
  }

  auto STAGE = [&](int buf, int t) {
    const int kt = t * 32;
    const size_t kB = (size_t)(kt >> 3) * Nn * 8;
    __builtin_amdgcn_global_load_lds(AS1(gA0 + kt), AS3(&Asm[buf][w * 512]), 16, 0, 0);
    __builtin_amdgcn_global_load_lds(AS1(gA1 + kt), AS3(&Asm[buf][(w + 4) * 512]), 16, 0, 0);
    __builtin_amdgcn_global_load_lds(AS1(gB0 + kB), AS3(&Bsm[buf][w * 512]), 16, 0, 0);
    __builtin_amdgcn_global_load_lds(AS1(gB1 + kB), AS3(&Bsm[buf][(w + 4) * 512]), 16, 0, 0);
  };

  const int NT = K >> 5;
  STAGE(0, 0);
  __syncthreads();
  int cur = 0;
  for (int t = 0; t < NT; ++t) {
    if (t + 1 < NT) STAGE(cur ^ 1, t + 1);
    bf16x8 af[4], bfr[4];
#pragma unroll
    for (int m = 0; m < 4; ++m) af[m] = *(const bf16x8*)&Asm[cur][offA[m]];
#pragma unroll
    for (int n = 0; n < 4; ++n) bfr[n] = *(const bf16x8*)&Bsm[cur][offB[n]];
#pragma unroll
    for (int m = 0; m < 4; ++m)
#pragma unroll
      for (int n = 0; n < 4; ++n)
        acc[m][n] = __builtin_amdgcn_mfma_f32_16x16x32_bf16(af[m], bfr[n], acc[m][n], 0, 0, 0);
    __syncthreads();
    cur ^= 1;
  }

  const int crow = (lane >> 4) * 4;
  const int ccol = lane & 15;
#pragma unroll
  for (int m = 0; m < 4; ++m)
#pragma unroll
    for (int n = 0; n < 4; ++n) {
#pragma unroll
      for (int r = 0; r < 4; ++r) {
        Cf[(size_t)(m0 + wr * 64 + m * 16 + crow + r) * Nn +
           n0 + wc * 64 + n * 16 + ccol] = acc[m][n][r];
      }
    }
}

// ---------- scan pass B: per-channel chunk-prefix LSE ----------
__global__ void scan_pass_b(const float* __restrict__ T, float* __restrict__ Pf) {
  const int ch = blockIdx.x * 256 + threadIdx.x;
  const float* t = &T[(size_t)ch * 32];
  float* p = &Pf[(size_t)ch * 32];
  float run = 0.f;
  for (int c = 0; c < 32; ++c) {
    p[c] = run;
    run = lseop_fast(run, t[c]);
  }
}

// Pass C: e_i = exp(k_i - P); S = cumsum(e); G = -ln(1+S) (f16); kg = e_i * rope.
__global__ __launch_bounds__(256) void scan_pass_c(const unsigned short* __restrict__ k_h,
    const float* __restrict__ Pf, const float* __restrict__ ropeT,
    unsigned short* __restrict__ G_h, unsigned short* __restrict__ kg_g,
    float* __restrict__ glast_g) {
  const int g = blockIdx.x * 256 + threadIdx.x;
  const int hd = g & 63;
  const int c = (g >> 6) & 31;
  const int bh = g >> 11;
  const int b = bh >> 4, h = bh & 15;
  const size_t base = (size_t)b * N_ * D_ + (size_t)(c * 64) * D_ + h * HD_ + hd;
  const size_t gb = ((size_t)bh * N_ + c * 64) * 64 + hd;
  const size_t kb = ((size_t)bh * N_ + c * 64) * 128 + hd;
  const size_t rb = (size_t)(c * 64) * 128 + hd;
  const float P = Pf[(size_t)(bh * 64 + hd) * 32 + c];
  float S = 0.f, G = 0.f;
  for (int j0 = 0; j0 < 64; j0 += 8) {
    float kr[8], cv[8], sv[8];
#pragma unroll
    for (int e = 0; e < 8; ++e) kr[e] = h2f(k_h[base + (size_t)(j0 + e) * D_]);
#pragma unroll
    for (int e = 0; e < 8; ++e) {
      cv[e] = ropeT[rb + (size_t)(j0 + e) * 128];
      sv[e] = ropeT[rb + (size_t)(j0 + e) * 128 + 64];
    }
#pragma unroll
    for (int e = 0; e < 8; ++e) {
      float ei = __expf(kr[e] - P);
      S += ei;
      G = -__logf(1.f + S);
      G_h[gb + (size_t)(j0 + e) * 64] = f2h(G);
      kg_g[kb + (size_t)(j0 + e) * 128] = f2bf(ei * cv[e]);
      kg_g[kb + (size_t)(j0 + e) * 128 + 64] = f2bf(ei * sv[e]);
    }
  }
  glast_g[(size_t)(bh * 32 + c) * 64 + hd] = G;
}

// ---------- GLA pass A (MFMA) ----------
__global__ __launch_bounds__(256) void gla_a(
    const unsigned short* __restrict__ qs, const unsigned short* __restrict__ kg_g,
    const unsigned short* __restrict__ G_h, const unsigned short* __restrict__ v_bf,
    const float* __restrict__ ropeT, const float* __restrict__ glast_g,
    unsigned short* __restrict__ qg_p, unsigned short* __restrict__ U,
    unsigned short* __restrict__ o_bf) {
  __shared__ unsigned short kg_l[64 * 128];   // swizzled; reused as U_l
  __shared__ unsigned short kgT_l[128 * 72];  // [j][s]
  __shared__ unsigned short vT_l[64 * 72];    // [d][s]
  __shared__ unsigned short A_l[64 * 72];     // [c][s] masked

  const int bid = blockIdx.x;
  const int bh = bid >> 5, c = bid & 31;
  const int b = bh >> 4, h = bh & 15;
  const int t0 = c * 64;
  const int tid = threadIdx.x;
  const int lane = tid & 63, w = tid >> 6;
  const int lr = lane & 15, lg = lane >> 4;

  const size_t qv_base = ((size_t)(b * N_ + t0) * H_ + h) * 64;
  const size_t kg_base = ((size_t)bh * N_ + t0) * 128;

#pragma unroll
  for (int u = 0; u < 4; ++u) {
    const int flat = u * 256 + tid;
    const int r = flat >> 4, sl = flat & 15;
    u16x8 src = *(const u16x8*)&kg_g[kg_base + (size_t)r * 128 + sl * 8];
    *(u16x8*)&kg_l[r * 128 + ((sl ^ (r & 7)) * 8)] = src;
  }
  {
    const int r = tid >> 2, d0 = (tid & 3) * 16;
    u16x8 a = *(const u16x8*)&v_bf[qv_base + (size_t)r * (H_ * 64) + d0];
    u16x8 b2 = *(const u16x8*)&v_bf[qv_base + (size_t)r * (H_ * 64) + d0 + 8];
#pragma unroll
    for (int e = 0; e < 8; ++e) {
      vT_l[(d0 + e) * 72 + r] = a[e];
      vT_l[(d0 + 8 + e) * 72 + r] = b2[e];
    }
  }
  __syncthreads();
  {
    const int j = tid >> 1, sh = (tid & 1) * 32;
#pragma unroll
    for (int u = 0; u < 4; ++u) {
      union { unsigned short us[8]; u16x8 v; } tv;
#pragma unroll
      for (int e = 0; e < 8; ++e) {
        const int s = sh + 8 * u + e;
        tv.us[e] = kg_l[s * 128 + (((j >> 3) ^ (s & 7)) * 8) + (j & 7)];
      }
      *(u16x8*)&kgT_l[j * 72 + sh + 8 * u] = tv.v;
    }
  }
  __syncthreads();

  // ---- qg build (in-fragment) + global qg_p store ----
  bf16x8 af[4];
  {
    const int r = 16 * w + lr;
#pragma unroll
    for (int ks = 0; ks < 4; ++ks) {
      const int jb = 32 * ks + 8 * lg;
      const int jq = jb & 63;
      u16x8 q8 = *(const u16x8*)&qs[qv_base + (size_t)r * (H_ * 64) + jq];
      u16x8 gh8 = *(const u16x8*)&G_h[((size_t)bh * N_ + t0 + r) * 64 + jq];
      float4 r0 = *(const float4*)&ropeT[(size_t)(t0 + r) * 128 + jb];
      float4 r1 = *(const float4*)&ropeT[(size_t)(t0 + r) * 128 + jb + 4];
      float rr[8] = {r0.x, r0.y, r0.z, r0.w, r1.x, r1.y, r1.z, r1.w};
      union { unsigned short us[8]; bf16x8 v; u16x8 uv; } pk;
#pragma unroll
      for (int e = 0; e < 8; ++e)
        pk.us[e] = f2bf(bf2f(q8[e]) * rr[e] * __expf(h2f(gh8[e])));
      af[ks] = pk.v;
      *(u16x8*)&qg_p[((((size_t)bid * 4 + w) * 4 + ks) * 64 + lane) * 8] = pk.uv;
    }
  }
  // ---- m1: A = qg @ kg^T ----
  f32x4 acc1[4];
#pragma unroll
  for (int n = 0; n < 4; ++n) acc1[n] = (f32x4){0.f, 0.f, 0.f, 0.f};
#pragma unroll
  for (int n = 0; n < 4; ++n) {
    const int s = 16 * n + lr;
#pragma unroll
    for (int ks = 0; ks < 4; ++ks) {
      bf16x8 bk = *(const bf16x8*)&kg_l[s * 128 + (((lg + 4 * ks) ^ (s & 7)) * 8)];
      acc1[n] = __builtin_amdgcn_mfma_f32_16x16x32_bf16(af[ks], bk, acc1[n], 0, 0, 0);
    }
  }
#pragma unroll
  for (int n = 0; n < 4; ++n) {
    const int s = 16 * n + lr;
#pragma unroll
    for (int reg = 0; reg < 4; ++reg) {
      const int cr = 16 * w + 4 * lg + reg;
      A_l[cr * 72 + s] = (s <= cr) ? f2bf(acc1[n][reg]) : (unsigned short)0;
    }
  }
  // ---- m2: Urows d = v^T @ kg ----
  f32x4 acc2[8];
#pragma unroll
  for (int n = 0; n < 8; ++n) acc2[n] = (f32x4){0.f, 0.f, 0.f, 0.f};
#pragma unroll
  for (int ks = 0; ks < 2; ++ks) {
    const int s0 = 32 * ks + 8 * lg;
    bf16x8 av = *(const bf16x8*)&vT_l[(16 * w + lr) * 72 + s0];
#pragma unroll
    for (int n = 0; n < 8; ++n) {
      bf16x8 bk = *(const bf16x8*)&kgT_l[(16 * n + lr) * 72 + s0];
      acc2[n] = __builtin_amdgcn_mfma_f32_16x16x32_bf16(av, bk, acc2[n], 0, 0, 0);
    }
  }
  __syncthreads();
  // ---- phase D: U_l writes; m3 = A @ v; o write (bf16) ----
  float es[4];
#pragma unroll
  for (int n = 0; n < 4; ++n)
    es[n] = __expf(glast_g[(size_t)bid * 64 + 16 * n + lr]);
#pragma unroll
  for (int n = 0; n < 8; ++n) {
    const int j = 16 * n + lr;
    const float e = es[n & 3];
#pragma unroll
    for (int reg = 0; reg < 4; ++reg)
      kg_l[(16 * w + 4 * lg + reg) * 128 + j] = f2bf(acc2[n][reg] * e);
  }
  f32x4 acc3[4];
#pragma unroll
  for (int n = 0; n < 4; ++n) acc3[n] = (f32x4){0.f, 0.f, 0.f, 0.f};
#pragma unroll
  for (int ks = 0; ks < 2; ++ks) {
    const int s0 = 32 * ks + 8 * lg;
    bf16x8 aA = *(const bf16x8*)&A_l[(16 * w + lr) * 72 + s0];
#pragma unroll
    for (int n = 0; n < 4; ++n) {
      bf16x8 bV = *(const bf16x8*)&vT_l[(16 * n + lr) * 72 + s0];
      acc3[n] = __builtin_amdgcn_mfma_f32_16x16x32_bf16(aA, bV, acc3[n], 0, 0, 0);
    }
  }
#pragma unroll
  for (int n = 0; n < 4; ++n)
#pragma unroll
    for (int reg = 0; reg < 4; ++reg)
      o_bf[qv_base + (size_t)(16 * w + 4 * lg + reg) * (H_ * 64) + 16 * n + lr] =
          f2bf(acc3[n][reg]);
  __syncthreads();
#pragma unroll
  for (int u = 0; u < 4; ++u) {
    const int flat = u * 256 + tid;
    const int d = flat >> 4, sl = flat & 15;
    *(u16x8*)&U[((size_t)bid * 64 + d) * 128 + sl * 8] =
        *(const u16x8*)&kg_l[d * 128 + sl * 8];
  }
}

// ---------- GLA pass B: exclusive chunk scan (in place) ----------
__global__ __launch_bounds__(256) void gla_b(unsigned short* __restrict__ U,
                                             const float* __restrict__ glast_g) {
  const int t = blockIdx.x * 256 + threadIdx.x;
  const int j4 = t & 31;
  const int d = (t >> 5) & 63;
  const int bh = t >> 11;
  const int jj0 = (4 * j4) & 63;
  float s0 = 0.f, s1 = 0.f, s2 = 0.f, s3 = 0.f;
  for (int c = 0; c < 32; ++c) {
    const size_t ub = ((size_t)((bh * 32 + c) * 64 + d)) * 128 + 4 * j4;
    ushort4 uv = *(const ushort4*)&U[ub];
    float4 g4 = *(const float4*)&glast_g[(size_t)(bh * 32 + c) * 64 + jj0];
    ushort4 pv;
    pv.x = f2bf(s0); pv.y = f2bf(s1); pv.z = f2bf(s2); pv.w = f2bf(s3);
    *(ushort4*)&U[ub] = pv;
    s0 = s0 * __expf(g4.x) + bf2f(uv.x);
    s1 = s1 * __expf(g4.y) + bf2f(uv.y);
    s2 = s2 * __expf(g4.z) + bf2f(uv.z);
    s3 = s3 * __expf(g4.w) + bf2f(uv.w);
  }
}

// ---------- GLA pass C (MFMA): o += qg @ S_{c-1} (bf16 RMW) ----------
__global__ __launch_bounds__(256) void gla_c(
    const unsigned short* __restrict__ qg_p, const unsigned short* __restrict__ S,
    unsigned short* __restrict__ o_bf) {
  __shared__ unsigned short S_l[64 * 128];
  const int bid = blockIdx.x;
  const int bh = bid >> 5, c = bid & 31;
  const int b = bh >> 4, h = bh & 15;
  const int t0 = c * 64;
  const int tid = threadIdx.x;
  const int lane = tid & 63, w = tid >> 6;
  const int lr = lane & 15, lg = lane >> 4;
  const size_t s_base = (size_t)bid * 64 * 128;
  const size_t o_base = ((size_t)(b * N_ + t0) * H_ + h) * 64;

#pragma unroll
  for (int u = 0; u < 4; ++u) {
    const int flat = u * 256 + tid;
    const int d = flat >> 4, sl = flat & 15;
    u16x8 src = *(const u16x8*)&S[s_base + (size_t)d * 128 + sl * 8];
    *(u16x8*)&S_l[d * 128 + ((sl ^ (d & 7)) * 8)] = src;
  }
  __syncthreads();
  bf16x8 af[4];
#pragma unroll
  for (int ks = 0; ks < 4; ++ks)
    af[ks] = *(const bf16x8*)&qg_p[((((size_t)bid * 4 + w) * 4 + ks) * 64 + lane) * 8];
  f32x4 acc[4];
#pragma unroll
  for (int n = 0; n < 4; ++n) acc[n] = (f32x4){0.f, 0.f, 0.f, 0.f};
#pragma unroll
  for (int n = 0; n < 4; ++n) {
    const int d = 16 * n + lr;
#pragma unroll
    for (int ks = 0; ks < 4; ++ks) {
      bf16x8 bk = *(const bf16x8*)&S_l[d * 128 + (((lg + 4 * ks) ^ (d & 7)) * 8)];
      acc[n] = __builtin_amdgcn_mfma_f32_16x16x32_bf16(af[ks], bk, acc[n], 0, 0, 0);
    }
  }
#pragma unroll
  for (int n = 0; n < 4; ++n)
#pragma unroll
    for (int reg = 0; reg < 4; ++reg) {
      const size_t idx = o_base + (size_t)(16 * w + 4 * lg + reg) * (H_ * 64) + 16 * n + lr;
      o_bf[idx] = f2bf(bf2f(o_bf[idx]) + acc[n][reg]);
    }
}

// ---------- gate+norm: one wave per row, reduction-free gate; o in bf16 ----------
__global__ __launch_bounds__(256) void gate_norm2(
    const float* __restrict__ tg, const float* __restrict__ Wg2,
    const float* __restrict__ nw, const unsigned short* __restrict__ o_bf,
    unsigned short* __restrict__ og) {
  const int w = threadIdx.x >> 6, lane = threadIdx.x & 63;
  const int row = blockIdx.x * 4 + w;
  float tgv[16];
  const float* tp = &tg[(size_t)row * 16];
#pragma unroll
  for (int hh = 0; hh < 16; ++hh) tgv[hh] = tp[hh];
  float ogr[4][4];
  float ssq = 0.f;
#pragma unroll
  for (int u = 0; u < 4; ++u) {
    const int d0 = u * 256 + lane * 4;
    ushort4 o4 = *(const ushort4*)&o_bf[(size_t)row * 1024 + d0];
    float oa[4] = {bf2f(o4.x), bf2f(o4.y), bf2f(o4.z), bf2f(o4.w)};
    float sgx = 0.f, sgy = 0.f, sgz = 0.f, sgw = 0.f;
#pragma unroll
    for (int hh = 0; hh < 16; ++hh) {
      float4 w4 = *(const float4*)&Wg2[hh * 1024 + d0];
      sgx += tgv[hh] * w4.x; sgy += tgv[hh] * w4.y;
      sgz += tgv[hh] * w4.z; sgw += tgv[hh] * w4.w;
    }
    ogr[u][0] = oa[0] / (1.f + __expf(-sgx));
    ogr[u][1] = oa[1] / (1.f + __expf(-sgy));
    ogr[u][2] = oa[2] / (1.f + __expf(-sgz));
    ogr[u][3] = oa[3] / (1.f + __expf(-sgw));
    ssq += ogr[u][0] * ogr[u][0] + ogr[u][1] * ogr[u][1] +
           ogr[u][2] * ogr[u][2] + ogr[u][3] * ogr[u][3];
  }
#pragma unroll
  for (int off = 32; off > 0; off >>= 1) ssq += __shfl_xor(ssq, off);
  const float rinv = rsqrtf(ssq * (1.f / 1024.f) + 1e-6f);
#pragma unroll
  for (int u = 0; u < 4; ++u) {
    const int d0 = u * 256 + lane * 4;
    float4 nw4 = *(const float4*)&nw[d0];
    ushort4 st;
    st.x = f2bf(ogr[u][0] * rinv * nw4.x);
    st.y = f2bf(ogr[u][1] * rinv * nw4.y);
    st.z = f2bf(ogr[u][2] * rinv * nw4.z);
    st.w = f2bf(ogr[u][3] * rinv * nw4.w);
    *(ushort4*)&og[(size_t)row * 1024 + d0] = st;
  }
}

extern "C" void kernel_launch(void* const* d_in, const int* in_sizes, int n_in,
                              void* d_out, int out_size, void* d_ws, size_t ws_size,
                              hipStream_t stream) {
  const float* x   = (const float*)d_in[0];
  const float* Wq  = (const float*)d_in[1];
  const float* Wk  = (const float*)d_in[2];
  const float* Wv  = (const float*)d_in[3];
  const float* Wo  = (const float*)d_in[4];
  const float* Wg1 = (const float*)d_in[5];
  const float* Wg2 = (const float*)d_in[6];
  const float* nw  = (const float*)d_in[7];
  float* out = (float*)d_out;
  float* ws  = (float*)d_ws;

  const size_t P = (size_t)B_ * N_ * D_;  // 8,388,608
  unsigned short* k_h = (unsigned short*)ws;              // P u16 in [0, P/2) floats
  unsigned short* U_buf = (unsigned short*)ws;            // 2P u16 = [0,P) floats (after scans)
  unsigned short* o_bf = (unsigned short*)(ws + P);       // P u16
  unsigned short* G_h  = (unsigned short*)(ws + 2 * P);   // P u16 (f16)
  unsigned short* qg_p = (unsigned short*)(ws + 3 * P);   // 2P u16
  unsigned short* kg_g = (unsigned short*)(ws + 4 * P);   // 2P u16
  unsigned short* v_bf = (unsigned short*)(ws + 5 * P);            // P u16
  unsigned short* q_bf = (unsigned short*)(ws + 5 * P + P / 2);    // P u16
  float* ropeT = ws + 6 * P;                                       // 262144
  float* T_buf = ws + 6 * P + 524288;                              // 131072
  float* P_buf = T_buf + 131072;                                   // 131072
  unsigned short* Wg1p = (unsigned short*)(ws + 6 * P + 786432);   // 16384 u16
  float* tg_buf = ws + 6 * P + 794624;                             // 131072
  unsigned short* x_bf = (unsigned short*)(ws + 13 * P / 2);       // P u16
  unsigned short* og_bf = x_bf;  // x_bf dead before gate_norm2 writes og
  unsigned short* Wqkv_p = (unsigned short*)(ws + 7 * P);          // 3145728 u16
  unsigned short* Wo_p = (unsigned short*)(ws + 7 * P + 1572864);  // 1048576 u16
  float* glast_g = ws + 7 * P + 2097152;                           // 131072

  const int M = B_ * N_;
  const int ggrid = (M / 128) * (D_ / 128);       // 512 (Wo)
  const int qkvgrid = (M / 128) * (3 * D_ / 128); // 1536

  cast_x_bf16<<<(int)(P / 2048), 256, 0, stream>>>(x, x_bf);
  rope_fill<<<512, 256, 0, stream>>>(ropeT);
  cast_w_all<<<2048, 256, 0, stream>>>(Wq, Wk, Wv, Wo, Wqkv_p, Wo_p);
  pack_wg1<<<8, 256, 0, stream>>>(Wg1, Wg1p);
  gate_logits<<<M / 64, 256, 0, stream>>>(x_bf, Wg1p, tg_buf);
  gemm_qkv<<<qkvgrid, 256, 0, stream>>>(x_bf, Wqkv_p, q_bf, k_h, v_bf, T_buf, M, D_);
  scan_pass_b<<<16, 256, 0, stream>>>(T_buf, P_buf);
  scan_pass_c<<<512, 256, 0, stream>>>(k_h, P_buf, ropeT, G_h, kg_g, glast_g);
  gla_a<<<2048, 256, 0, stream>>>(q_bf, kg_g, G_h, v_bf, ropeT, glast_g, qg_p, U_buf, o_bf);
  gla_b<<<512, 256, 0, stream>>>(U_buf, glast_g);
  gla_c<<<2048, 256, 0, stream>>>(qg_p, U_buf, o_bf);
  gate_norm2<<<M / 4, 256, 0, stream>>>(tg_buf, Wg2, nw, o_bf, og_bf);
  gemm_bf16<<<ggrid, 256, 0, stream>>>(og_bf, Wo_p, out, M, D_, D_);
}

// Round 10
// 214.938 us; speedup vs baseline: 12.1896x; 1.0695x over previous
//
#include <hip/hip_runtime.h>
#include <hip/hip_bf16.h>
#include <math.h>

#define B_ 4
#define N_ 2048
#define D_ 1024
#define H_ 16
#define HD_ 64

typedef __attribute__((ext_vector_type(8))) short bf16x8;
typedef __attribute__((ext_vector_type(8))) unsigned short u16x8;
typedef __attribute__((ext_vector_type(4))) float f32x4;

#define AS1(p) ((const __attribute__((address_space(1))) void*)(p))
#define AS3(p) ((__attribute__((address_space(3))) void*)(p))

__device__ inline float bf2f(unsigned short u) { return __uint_as_float(((unsigned)u) << 16); }
__device__ inline unsigned short f2bf(float f) {
  unsigned u = __float_as_uint(f);
  return (unsigned short)((u + 0x7fffu + ((u >> 16) & 1u)) >> 16);
}
__device__ inline unsigned short f2h(float f) {
  _Float16 h = (_Float16)f; unsigned short u; __builtin_memcpy(&u, &h, 2); return u;
}
__device__ inline float h2f(unsigned short u) {
  _Float16 h; __builtin_memcpy(&h, &u, 2); return (float)h;
}
__device__ inline float lseop_fast(float a, float b) {
  float mx = fmaxf(a, b), mn = fminf(a, b);
  return mx + __logf(1.f + __expf(mn - mx));
}

// ---------- cast x (f32) -> bf16 row-major ----------
__global__ __launch_bounds__(256) void cast_x_bf16(const float* __restrict__ x,
                                                   unsigned short* __restrict__ xb) {
  const int t = blockIdx.x * 256 + threadIdx.x;
  float4 a = ((const float4*)x)[(size_t)t * 2];
  float4 b = ((const float4*)x)[(size_t)t * 2 + 1];
  union { unsigned short u[8]; uint4 q; } pk;
  pk.u[0] = f2bf(a.x); pk.u[1] = f2bf(a.y); pk.u[2] = f2bf(a.z); pk.u[3] = f2bf(a.w);
  pk.u[4] = f2bf(b.x); pk.u[5] = f2bf(b.y); pk.u[6] = f2bf(b.z); pk.u[7] = f2bf(b.w);
  ((uint4*)xb)[t] = pk.q;
}

// ---------- all 4 weight casts in one launch: 2048 blocks, 512 per weight ----------
__global__ __launch_bounds__(256) void cast_w_all(
    const float* __restrict__ Wq, const float* __restrict__ Wk,
    const float* __restrict__ Wv, const float* __restrict__ Wo,
    unsigned short* __restrict__ Wqkv_p, unsigned short* __restrict__ Wo_p) {
  const int bid = blockIdx.x;
  const int which = bid >> 9;
  const float* W = (which == 0) ? Wq : (which == 1) ? Wk : (which == 2) ? Wv : Wo;
  const int col0 = (which == 1) ? 1024 : (which == 2) ? 2048 : 0;
  const int Ntot = (which == 3) ? 1024 : 3072;
  unsigned short* dst = (which == 3) ? Wo_p : Wqkv_p;
  const int t = (bid & 511) * 256 + threadIdx.x;
  const int kg = t >> 10, n = t & 1023;
  union { unsigned short u[8]; uint4 q; } pk;
#pragma unroll
  for (int r = 0; r < 8; ++r)
    pk.u[r] = f2bf(W[(size_t)(kg * 8 + r) * 1024 + n]);
  *(uint4*)&dst[((size_t)kg * Ntot + col0 + n) * 8] = pk.q;
}

// ---------- pack Wg1 (f32 [1024][16]) -> bf16 [(K/8)][16][8] ----------
__global__ __launch_bounds__(256) void pack_wg1(const float* __restrict__ Wg1,
                                                unsigned short* __restrict__ Wp) {
  const int t = blockIdx.x * 256 + threadIdx.x;  // 2048 = 128 kg * 16 hh
  const int kg = t >> 4, hh = t & 15;
  union { unsigned short us[8]; u16x8 v; } pk;
#pragma unroll
  for (int r = 0; r < 8; ++r)
    pk.us[r] = f2bf(Wg1[(size_t)(kg * 8 + r) * 16 + hh]);
  *(u16x8*)&Wp[((size_t)kg * 16 + hh) * 8] = pk.v;
}

// ---------- gate logits: tg[M][16] = x_bf @ Wg1_bf (MFMA) ----------
__global__ __launch_bounds__(256) void gate_logits(
    const unsigned short* __restrict__ x_bf, const unsigned short* __restrict__ Wg1p,
    float* __restrict__ tg) {
  __shared__ unsigned short Wl[128 * 16 * 8];  // 32 KB
  const int tid = threadIdx.x;
  const int lane = tid & 63, w = tid >> 6;
  const int lr = lane & 15, lg = lane >> 4;
#pragma unroll
  for (int u = 0; u < 8; ++u) {
    const int flat = u * 256 + tid;
    *(u16x8*)&Wl[flat * 8] = *(const u16x8*)&Wg1p[(size_t)flat * 8];
  }
  __syncthreads();
  const int row = blockIdx.x * 64 + w * 16 + lr;
  f32x4 acc = (f32x4){0.f, 0.f, 0.f, 0.f};
  for (int ks = 0; ks < 32; ++ks) {
    bf16x8 a = *(const bf16x8*)&x_bf[(size_t)row * 1024 + ks * 32 + lg * 8];
    bf16x8 b = *(const bf16x8*)&Wl[((ks * 4 + lg) * 16 + lr) * 8];
    acc = __builtin_amdgcn_mfma_f32_16x16x32_bf16(a, b, acc, 0, 0, 0);
  }
  const int orow = blockIdx.x * 64 + w * 16 + 4 * lg;
#pragma unroll
  for (int reg = 0; reg < 4; ++reg)
    tg[(size_t)(orow + reg) * 16 + lr] = acc[reg];
}

// ---------- rope table ----------
__global__ __launch_bounds__(256) void rope_fill(float* __restrict__ ropeT) {
  const int t = blockIdx.x * 256 + threadIdx.x;  // N*64
  const int n = t >> 6, hd = t & 63;
  const float freq = expf((float)hd * -0.28782313662425575f);
  float s, c;
  sincosf((float)n * freq, &s, &c);
  ropeT[(size_t)n * 128 + hd] = c;
  ropeT[(size_t)n * 128 + 64 + hd] = s;
}

// ---------- fused QKV GEMM (double-buffered): routes q(silu,bf16)/k(f16 + chunk-sum T)/v(bf16)
__global__ __launch_bounds__(256) void gemm_qkv(
    const unsigned short* __restrict__ A, const unsigned short* __restrict__ Wp,
    unsigned short* __restrict__ qb, unsigned short* __restrict__ kh,
    unsigned short* __restrict__ vb, float* __restrict__ T, int M, int K) {
  const int Nn = 3072;
  __shared__ unsigned short Asm[2][128 * 32];
  __shared__ unsigned short Bsm[2][4 * 128 * 8];

  const int tid = threadIdx.x;
  const int lane = tid & 63;
  const int w = tid >> 6;
  const int nb = Nn >> 7;  // 24
  const int nwg = gridDim.x;
  const int cpx = nwg >> 3;
  int bid = blockIdx.x;
  bid = (bid & 7) * cpx + (bid >> 3);
  const int by = bid / nb, bx = bid % nb;
  const int m0 = by * 128, n0 = bx * 128;
  const int wr = w >> 1, wc = w & 1;

  f32x4 acc[4][4];
#pragma unroll
  for (int i = 0; i < 4; ++i)
#pragma unroll
    for (int j = 0; j < 4; ++j) acc[i][j] = (f32x4){0.f, 0.f, 0.f, 0.f};

  const int rA0 = w * 16 + (lane >> 2);
  const int rA1 = (w + 4) * 16 + (lane >> 2);
  const int sA0 = (lane & 3) ^ ((rA0 >> 1) & 3);
  const int sA1 = (lane & 3) ^ ((rA1 >> 1) & 3);
  const unsigned short* gA0 = A + (size_t)(m0 + rA0) * K + sA0 * 8;
  const unsigned short* gA1 = A + (size_t)(m0 + rA1) * K + sA1 * 8;
  const unsigned short* gB0 = Wp + (size_t)(w >> 1) * Nn * 8 +
                              (size_t)(n0 + (w & 1) * 64 + lane) * 8;
  const unsigned short* gB1 = Wp + (size_t)((w + 4) >> 1) * Nn * 8 +
                              (size_t)(n0 + ((w + 4) & 1) * 64 + lane) * 8;

  int offA[4], offB[4];
#pragma unroll
  for (int m = 0; m < 4; ++m) {
    const int rowf = wr * 64 + m * 16 + (lane & 15);
    const int sp = (lane >> 4) ^ ((rowf >> 1) & 3);
    offA[m] = rowf * 32 + sp * 8;
  }
#pragma unroll
  for (int n = 0; n < 4; ++n) {
    const int colf = wc * 64 + n * 16 + (lane & 15);
    offB[n] = (lane >> 4) * 1024 + colf * 8;
  }

  auto STAGE = [&](int buf, int t) {
    const int kt = t * 32;
    const size_t kB = (size_t)(kt >> 3) * Nn * 8;
    __builtin_amdgcn_global_load_lds(AS1(gA0 + kt), AS3(&Asm[buf][w * 512]), 16, 0, 0);
    __builtin_amdgcn_global_load_lds(AS1(gA1 + kt), AS3(&Asm[buf][(w + 4) * 512]), 16, 0, 0);
    __builtin_amdgcn_global_load_lds(AS1(gB0 + kB), AS3(&Bsm[buf][w * 512]), 16, 0, 0);
    __builtin_amdgcn_global_load_lds(AS1(gB1 + kB), AS3(&Bsm[buf][(w + 4) * 512]), 16, 0, 0);
  };

  const int NT = K >> 5;  // 32
  STAGE(0, 0);
  __syncthreads();
  int cur = 0;
  for (int t = 0; t < NT; ++t) {
    if (t + 1 < NT) STAGE(cur ^ 1, t + 1);
    bf16x8 af[4], bfr[4];
#pragma unroll
    for (int m = 0; m < 4; ++m) af[m] = *(const bf16x8*)&Asm[cur][offA[m]];
#pragma unroll
    for (int n = 0; n < 4; ++n) bfr[n] = *(const bf16x8*)&Bsm[cur][offB[n]];
#pragma unroll
    for (int m = 0; m < 4; ++m)
#pragma unroll
      for (int n = 0; n < 4; ++n)
        acc[m][n] = __builtin_amdgcn_mfma_f32_16x16x32_bf16(af[m], bfr[n], acc[m][n], 0, 0, 0);
    __syncthreads();
    cur ^= 1;
  }

  const int crow = (lane >> 4) * 4;
  const int ccol = lane & 15;
  const int slice = bx >> 3;  // block-uniform: 0=q,1=k,2=v
  if (slice == 1) {
    // k slice: f16 store + fused per-chunk exp-sum (replaces scan_pass_a)
#pragma unroll
    for (int n = 0; n < 4; ++n) {
      float se = 0.f;
#pragma unroll
      for (int m = 0; m < 4; ++m)
#pragma unroll
        for (int r = 0; r < 4; ++r) {
          float vv = acc[m][n][r];
          se += __expf(vv);
          kh[(size_t)(m0 + wr * 64 + m * 16 + crow + r) * 1024 +
             (n0 & 1023) + wc * 64 + n * 16 + ccol] = f2h(vv);
        }
      se += __shfl_xor(se, 16);
      se += __shfl_xor(se, 32);
      if ((lane >> 4) == 0) {
        const int bb = m0 >> 11;
        const int h = ((n0 & 1023) + wc * 64) >> 6;
        const int hd = n * 16 + ccol;
        const int c = ((m0 & 2047) >> 6) + wr;
        T[(size_t)((bb * 16 + h) * 64 + hd) * 32 + c] = __logf(se);
      }
    }
  } else {
#pragma unroll
    for (int m = 0; m < 4; ++m)
#pragma unroll
      for (int n = 0; n < 4; ++n)
#pragma unroll
        for (int r = 0; r < 4; ++r) {
          float vv = acc[m][n][r];
          const size_t idx = (size_t)(m0 + wr * 64 + m * 16 + crow + r) * 1024 +
                             (n0 & 1023) + wc * 64 + n * 16 + ccol;
          if (slice == 0) {
            vv = vv / (1.f + __expf(-vv));
            qb[idx] = f2bf(vv);
          } else {
            vb[idx] = f2bf(vv);
          }
        }
  }
}

// ---------- MFMA bf16 GEMM (Wo, double-buffered): f32 out ----------
__global__ __launch_bounds__(256) void gemm_bf16(
    const unsigned short* __restrict__ A, const unsigned short* __restrict__ Wp,
    float* __restrict__ Cf, int M, int K, int Nn) {
  __shared__ unsigned short Asm[2][128 * 32];
  __shared__ unsigned short Bsm[2][4 * 128 * 8];

  const int tid = threadIdx.x;
  const int lane = tid & 63;
  const int w = tid >> 6;
  const int nb = Nn >> 7;
  const int nwg = gridDim.x;
  const int cpx = nwg >> 3;
  int bid = blockIdx.x;
  bid = (bid & 7) * cpx + (bid >> 3);
  const int by = bid / nb, bx = bid % nb;
  const int m0 = by * 128, n0 = bx * 128;
  const int wr = w >> 1, wc = w & 1;

  f32x4 acc[4][4];
#pragma unroll
  for (int i = 0; i < 4; ++i)
#pragma unroll
    for (int j = 0; j < 4; ++j) acc[i][j] = (f32x4){0.f, 0.f, 0.f, 0.f};

  const int rA0 = w * 16 + (lane >> 2);
  const int rA1 = (w + 4) * 16 + (lane >> 2);
  const int sA0 = (lane & 3) ^ ((rA0 >> 1) & 3);
  const int sA1 = (lane & 3) ^ ((rA1 >> 1) & 3);
  const unsigned short* gA0 = A + (size_t)(m0 + rA0) * K + sA0 * 8;
  const unsigned short* gA1 = A + (size_t)(m0 + rA1) * K + sA1 * 8;
  const unsigned short* gB0 = Wp + (size_t)(w >> 1) * Nn * 8 +
                              (size_t)(n0 + (w & 1) * 64 + lane) * 8;
  const unsigned short* gB1 = Wp + (size_t)((w + 4) >> 1) * Nn * 8 +
                              (size_t)(n0 + ((w + 4) & 1) * 64 + lane) * 8;

  int offA[4], offB[4];
#pragma unroll
  for (int m = 0; m < 4; ++m) {
    const int rowf = wr * 64 + m * 16 + (lane & 15);
    const int sp = (lane >> 4) ^ ((rowf >> 1) & 3);
    offA[m] = rowf * 32 + sp * 8;
  }
#pragma unroll
  for (int n = 0; n < 4; ++n) {
    const int colf = wc * 64 + n * 16 + (lane & 15);
    offB[n] = (lane >> 4) * 1024 + colf * 8;
  }

  auto STAGE = [&](int buf, int t) {
    const int kt = t * 32;
    const size_t kB = (size_t)(kt >> 3) * Nn * 8;
    __builtin_amdgcn_global_load_lds(AS1(gA0 + kt), AS3(&Asm[buf][w * 512]), 16, 0, 0);
    __builtin_amdgcn_global_load_lds(AS1(gA1 + kt), AS3(&Asm[buf][(w + 4) * 512]), 16, 0, 0);
    __builtin_amdgcn_global_load_lds(AS1(gB0 + kB), AS3(&Bsm[buf][w * 512]), 16, 0, 0);
    __builtin_amdgcn_global_load_lds(AS1(gB1 + kB), AS3(&Bsm[buf][(w + 4) * 512]), 16, 0, 0);
  };

  const int NT = K >> 5;
  STAGE(0, 0);
  __syncthreads();
  int cur = 0;
  for (int t = 0; t < NT; ++t) {
    if (t + 1 < NT) STAGE(cur ^ 1, t + 1);
    bf16x8 af[4], bfr[4];
#pragma unroll
    for (int m = 0; m < 4; ++m) af[m] = *(const bf16x8*)&Asm[cur][offA[m]];
#pragma unroll
    for (int n = 0; n < 4; ++n) bfr[n] = *(const bf16x8*)&Bsm[cur][offB[n]];
#pragma unroll
    for (int m = 0; m < 4; ++m)
#pragma unroll
      for (int n = 0; n < 4; ++n)
        acc[m][n] = __builtin_amdgcn_mfma_f32_16x16x32_bf16(af[m], bfr[n], acc[m][n], 0, 0, 0);
    __syncthreads();
    cur ^= 1;
  }

  const int crow = (lane >> 4) * 4;
  const int ccol = lane & 15;
#pragma unroll
  for (int m = 0; m < 4; ++m)
#pragma unroll
    for (int n = 0; n < 4; ++n) {
#pragma unroll
      for (int r = 0; r < 4; ++r) {
        Cf[(size_t)(m0 + wr * 64 + m * 16 + crow + r) * Nn +
           n0 + wc * 64 + n * 16 + ccol] = acc[m][n][r];
      }
    }
}

// ---------- scan pass B: per-channel chunk-prefix LSE ----------
__global__ void scan_pass_b(const float* __restrict__ T, float* __restrict__ Pf) {
  const int ch = blockIdx.x * 256 + threadIdx.x;
  const float* t = &T[(size_t)ch * 32];
  float* p = &Pf[(size_t)ch * 32];
  float run = 0.f;
  for (int c = 0; c < 32; ++c) {
    p[c] = run;
    run = lseop_fast(run, t[c]);
  }
}

// ---------- GLA pass A (MFMA) with fused intra-chunk scan ----------
// Computes e=exp(k-P) -> kg (LDS, swizzled), 2-level cumsum -> G (LDS f16),
// then A=masked(qg@kg^T), o_intra=A@v, U=(v^T@kg)*e^glast.
__global__ __launch_bounds__(256) void gla_a(
    const unsigned short* __restrict__ qs, const unsigned short* __restrict__ k_h,
    const float* __restrict__ Pf, const unsigned short* __restrict__ v_bf,
    const float* __restrict__ ropeT,
    unsigned short* __restrict__ qg_p, unsigned short* __restrict__ U,
    unsigned short* __restrict__ o_bf, float* __restrict__ glast_g) {
  __shared__ unsigned short kg_l[64 * 128];   // swizzled; reused as U_l   (16 KB)
  __shared__ unsigned short kgT_l[128 * 72];  // [j][s]                     (18 KB)
  __shared__ unsigned short vT_l[64 * 72];    // [d][s]                     (9 KB)
  __shared__ unsigned short A_l[64 * 72];     // [c][s] masked              (9 KB)
  __shared__ unsigned short G_l[64 * 72];     // [r][j] f16, padded         (9 KB)
  __shared__ float tot_l[4][64];              // scan partials              (1 KB)
  __shared__ float glast_s[64];               // exp(Glast)                 (256 B)

  const int bid = blockIdx.x;
  const int bh = bid >> 5, c = bid & 31;
  const int b = bh >> 4, h = bh & 15;
  const int t0 = c * 64;
  const int tid = threadIdx.x;
  const int lane = tid & 63, w = tid >> 6;
  const int lr = lane & 15, lg = lane >> 4;

  const size_t qv_base = ((size_t)(b * N_ + t0) * H_ + h) * 64;

  // ---- pass 1: e = exp(k-P); kg -> LDS (swizzled); partial sums ----
  const int jch = tid & 63, qq = tid >> 6;
  float e[16];
  {
    const float P = Pf[((size_t)bh * 64 + jch) * 32 + c];
    float psum = 0.f;
#pragma unroll
    for (int i = 0; i < 16; ++i) {
      const int r = qq * 16 + i;
      float kv = h2f(k_h[qv_base + (size_t)r * 1024 + jch]);
      float ei = __expf(kv - P);
      e[i] = ei;
      psum += ei;
      float cv = ropeT[(size_t)(t0 + r) * 128 + jch];
      float sv = ropeT[(size_t)(t0 + r) * 128 + 64 + jch];
      kg_l[r * 128 + (((jch >> 3) ^ (r & 7)) << 3) + (jch & 7)] = f2bf(ei * cv);
      kg_l[r * 128 + ((((jch + 64) >> 3) ^ (r & 7)) << 3) + (jch & 7)] = f2bf(ei * sv);
    }
    tot_l[qq][jch] = psum;
  }
  // ---- stage vT_l ----
  {
    const int r = tid >> 2, d0 = (tid & 3) * 16;
    u16x8 a = *(const u16x8*)&v_bf[qv_base + (size_t)r * (H_ * 64) + d0];
    u16x8 b2 = *(const u16x8*)&v_bf[qv_base + (size_t)r * (H_ * 64) + d0 + 8];
#pragma unroll
    for (int ee = 0; ee < 8; ++ee) {
      vT_l[(d0 + ee) * 72 + r] = a[ee];
      vT_l[(d0 + 8 + ee) * 72 + r] = b2[ee];
    }
  }
  __syncthreads();
  // ---- pass 2: prefix combine -> G (f16 LDS), glast ----
  {
    float off = 0.f;
    for (int p = 0; p < qq; ++p) off += tot_l[p][jch];
    float S = off;
#pragma unroll
    for (int i = 0; i < 16; ++i) {
      S += e[i];
      G_l[(qq * 16 + i) * 72 + jch] = f2h(-__logf(1.f + S));
    }
    if (qq == 3) {
      glast_g[(size_t)bid * 64 + jch] = -__logf(1.f + S);
      glast_s[jch] = 1.f / (1.f + S);  // = exp(Glast)
    }
  }
  // ---- build kgT_l from kg_l ----
  {
    const int j = tid >> 1, sh = (tid & 1) * 32;
#pragma unroll
    for (int u = 0; u < 4; ++u) {
      union { unsigned short us[8]; u16x8 v; } tv;
#pragma unroll
      for (int ee = 0; ee < 8; ++ee) {
        const int s = sh + 8 * u + ee;
        tv.us[ee] = kg_l[s * 128 + (((j >> 3) ^ (s & 7)) * 8) + (j & 7)];
      }
      *(u16x8*)&kgT_l[j * 72 + sh + 8 * u] = tv.v;
    }
  }
  __syncthreads();

  // ---- qg build (in-fragment, G from LDS) + global qg_p store ----
  bf16x8 af[4];
  {
    const int r = 16 * w + lr;
#pragma unroll
    for (int ks = 0; ks < 4; ++ks) {
      const int jb = 32 * ks + 8 * lg;
      const int jq = jb & 63;
      u16x8 q8 = *(const u16x8*)&qs[qv_base + (size_t)r * (H_ * 64) + jq];
      u16x8 gh8 = *(const u16x8*)&G_l[r * 72 + jq];
      float4 r0 = *(const float4*)&ropeT[(size_t)(t0 + r) * 128 + jb];
      float4 r1 = *(const float4*)&ropeT[(size_t)(t0 + r) * 128 + jb + 4];
      float rr[8] = {r0.x, r0.y, r0.z, r0.w, r1.x, r1.y, r1.z, r1.w};
      union { unsigned short us[8]; bf16x8 v; u16x8 uv; } pk;
#pragma unroll
      for (int ee = 0; ee < 8; ++ee)
        pk.us[ee] = f2bf(bf2f(q8[ee]) * rr[ee] * __expf(h2f(gh8[ee])));
      af[ks] = pk.v;
      *(u16x8*)&qg_p[((((size_t)bid * 4 + w) * 4 + ks) * 64 + lane) * 8] = pk.uv;
    }
  }
  // ---- m1: A = qg @ kg^T ----
  f32x4 acc1[4];
#pragma unroll
  for (int n = 0; n < 4; ++n) acc1[n] = (f32x4){0.f, 0.f, 0.f, 0.f};
#pragma unroll
  for (int n = 0; n < 4; ++n) {
    const int s = 16 * n + lr;
#pragma unroll
    for (int ks = 0; ks < 4; ++ks) {
      bf16x8 bk = *(const bf16x8*)&kg_l[s * 128 + (((lg + 4 * ks) ^ (s & 7)) * 8)];
      acc1[n] = __builtin_amdgcn_mfma_f32_16x16x32_bf16(af[ks], bk, acc1[n], 0, 0, 0);
    }
  }
#pragma unroll
  for (int n = 0; n < 4; ++n) {
    const int s = 16 * n + lr;
#pragma unroll
    for (int reg = 0; reg < 4; ++reg) {
      const int cr = 16 * w + 4 * lg + reg;
      A_l[cr * 72 + s] = (s <= cr) ? f2bf(acc1[n][reg]) : (unsigned short)0;
    }
  }
  // ---- m2: Urows d = v^T @ kg ----
  f32x4 acc2[8];
#pragma unroll
  for (int n = 0; n < 8; ++n) acc2[n] = (f32x4){0.f, 0.f, 0.f, 0.f};
#pragma unroll
  for (int ks = 0; ks < 2; ++ks) {
    const int s0 = 32 * ks + 8 * lg;
    bf16x8 av = *(const bf16x8*)&vT_l[(16 * w + lr) * 72 + s0];
#pragma unroll
    for (int n = 0; n < 8; ++n) {
      bf16x8 bk = *(const bf16x8*)&kgT_l[(16 * n + lr) * 72 + s0];
      acc2[n] = __builtin_amdgcn_mfma_f32_16x16x32_bf16(av, bk, acc2[n], 0, 0, 0);
    }
  }
  __syncthreads();
  // ---- phase D: U_l writes (scaled by exp(glast) from LDS); m3 = A @ v; o write ----
  float es[4];
#pragma unroll
  for (int n = 0; n < 4; ++n) es[n] = glast_s[16 * n + lr];
#pragma unroll
  for (int n = 0; n < 8; ++n) {
    const int j = 16 * n + lr;
    const float ee = es[n & 3];
#pragma unroll
    for (int reg = 0; reg < 4; ++reg)
      kg_l[(16 * w + 4 * lg + reg) * 128 + j] = f2bf(acc2[n][reg] * ee);
  }
  f32x4 acc3[4];
#pragma unroll
  for (int n = 0; n < 4; ++n) acc3[n] = (f32x4){0.f, 0.f, 0.f, 0.f};
#pragma unroll
  for (int ks = 0; ks < 2; ++ks) {
    const int s0 = 32 * ks + 8 * lg;
    bf16x8 aA = *(const bf16x8*)&A_l[(16 * w + lr) * 72 + s0];
#pragma unroll
    for (int n = 0; n < 4; ++n) {
      bf16x8 bV = *(const bf16x8*)&vT_l[(16 * n + lr) * 72 + s0];
      acc3[n] = __builtin_amdgcn_mfma_f32_16x16x32_bf16(aA, bV, acc3[n], 0, 0, 0);
    }
  }
#pragma unroll
  for (int n = 0; n < 4; ++n)
#pragma unroll
    for (int reg = 0; reg < 4; ++reg)
      o_bf[qv_base + (size_t)(16 * w + 4 * lg + reg) * (H_ * 64) + 16 * n + lr] =
          f2bf(acc3[n][reg]);
  __syncthreads();
#pragma unroll
  for (int u = 0; u < 4; ++u) {
    const int flat = u * 256 + tid;
    const int d = flat >> 4, sl = flat & 15;
    *(u16x8*)&U[((size_t)bid * 64 + d) * 128 + sl * 8] =
        *(const u16x8*)&kg_l[d * 128 + sl * 8];
  }
}

// ---------- GLA pass B: exclusive chunk scan (in place) ----------
__global__ __launch_bounds__(256) void gla_b(unsigned short* __restrict__ U,
                                             const float* __restrict__ glast_g) {
  const int t = blockIdx.x * 256 + threadIdx.x;
  const int j4 = t & 31;
  const int d = (t >> 5) & 63;
  const int bh = t >> 11;
  const int jj0 = (4 * j4) & 63;
  float s0 = 0.f, s1 = 0.f, s2 = 0.f, s3 = 0.f;
  for (int c = 0; c < 32; ++c) {
    const size_t ub = ((size_t)((bh * 32 + c) * 64 + d)) * 128 + 4 * j4;
    ushort4 uv = *(const ushort4*)&U[ub];
    float4 g4 = *(const float4*)&glast_g[(size_t)(bh * 32 + c) * 64 + jj0];
    ushort4 pv;
    pv.x = f2bf(s0); pv.y = f2bf(s1); pv.z = f2bf(s2); pv.w = f2bf(s3);
    *(ushort4*)&U[ub] = pv;
    s0 = s0 * __expf(g4.x) + bf2f(uv.x);
    s1 = s1 * __expf(g4.y) + bf2f(uv.y);
    s2 = s2 * __expf(g4.z) + bf2f(uv.z);
    s3 = s3 * __expf(g4.w) + bf2f(uv.w);
  }
}

// ---------- GLA pass C (MFMA): o += qg @ S_{c-1} (bf16 RMW) ----------
__global__ __launch_bounds__(256) void gla_c(
    const unsigned short* __restrict__ qg_p, const unsigned short* __restrict__ S,
    unsigned short* __restrict__ o_bf) {
  __shared__ unsigned short S_l[64 * 128];
  const int bid = blockIdx.x;
  const int bh = bid >> 5, c = bid & 31;
  const int b = bh >> 4, h = bh & 15;
  const int t0 = c * 64;
  const int tid = threadIdx.x;
  const int lane = tid & 63, w = tid >> 6;
  const int lr = lane & 15, lg = lane >> 4;
  const size_t s_base = (size_t)bid * 64 * 128;
  const size_t o_base = ((size_t)(b * N_ + t0) * H_ + h) * 64;

#pragma unroll
  for (int u = 0; u < 4; ++u) {
    const int flat = u * 256 + tid;
    const int d = flat >> 4, sl = flat & 15;
    u16x8 src = *(const u16x8*)&S[s_base + (size_t)d * 128 + sl * 8];
    *(u16x8*)&S_l[d * 128 + ((sl ^ (d & 7)) * 8)] = src;
  }
  __syncthreads();
  bf16x8 af[4];
#pragma unroll
  for (int ks = 0; ks < 4; ++ks)
    af[ks] = *(const bf16x8*)&qg_p[((((size_t)bid * 4 + w) * 4 + ks) * 64 + lane) * 8];
  f32x4 acc[4];
#pragma unroll
  for (int n = 0; n < 4; ++n) acc[n] = (f32x4){0.f, 0.f, 0.f, 0.f};
#pragma unroll
  for (int n = 0; n < 4; ++n) {
    const int d = 16 * n + lr;
#pragma unroll
    for (int ks = 0; ks < 4; ++ks) {
      bf16x8 bk = *(const bf16x8*)&S_l[d * 128 + (((lg + 4 * ks) ^ (d & 7)) * 8)];
      acc[n] = __builtin_amdgcn_mfma_f32_16x16x32_bf16(af[ks], bk, acc[n], 0, 0, 0);
    }
  }
#pragma unroll
  for (int n = 0; n < 4; ++n)
#pragma unroll
    for (int reg = 0; reg < 4; ++reg) {
      const size_t idx = o_base + (size_t)(16 * w + 4 * lg + reg) * (H_ * 64) + 16 * n + lr;
      o_bf[idx] = f2bf(bf2f(o_bf[idx]) + acc[n][reg]);
    }
}

// ---------- gate+norm: one wave per row, reduction-free gate; o in bf16 ----------
__global__ __launch_bounds__(256) void gate_norm2(
    const float* __restrict__ tg, const float* __restrict__ Wg2,
    const float* __restrict__ nw, const unsigned short* __restrict__ o_bf,
    unsigned short* __restrict__ og) {
  const int w = threadIdx.x >> 6, lane = threadIdx.x & 63;
  const int row = blockIdx.x * 4 + w;
  float tgv[16];
  const float* tp = &tg[(size_t)row * 16];
#pragma unroll
  for (int hh = 0; hh < 16; ++hh) tgv[hh] = tp[hh];
  float ogr[4][4];
  float ssq = 0.f;
#pragma unroll
  for (int u = 0; u < 4; ++u) {
    const int d0 = u * 256 + lane * 4;
    ushort4 o4 = *(const ushort4*)&o_bf[(size_t)row * 1024 + d0];
    float oa[4] = {bf2f(o4.x), bf2f(o4.y), bf2f(o4.z), bf2f(o4.w)};
    float sgx = 0.f, sgy = 0.f, sgz = 0.f, sgw = 0.f;
#pragma unroll
    for (int hh = 0; hh < 16; ++hh) {
      float4 w4 = *(const float4*)&Wg2[hh * 1024 + d0];
      sgx += tgv[hh] * w4.x; sgy += tgv[hh] * w4.y;
      sgz += tgv[hh] * w4.z; sgw += tgv[hh] * w4.w;
    }
    ogr[u][0] = oa[0] / (1.f + __expf(-sgx));
    ogr[u][1] = oa[1] / (1.f + __expf(-sgy));
    ogr[u][2] = oa[2] / (1.f + __expf(-sgz));
    ogr[u][3] = oa[3] / (1.f + __expf(-sgw));
    ssq += ogr[u][0] * ogr[u][0] + ogr[u][1] * ogr[u][1] +
           ogr[u][2] * ogr[u][2] + ogr[u][3] * ogr[u][3];
  }
#pragma unroll
  for (int off = 32; off > 0; off >>= 1) ssq += __shfl_xor(ssq, off);
  const float rinv = rsqrtf(ssq * (1.f / 1024.f) + 1e-6f);
#pragma unroll
  for (int u = 0; u < 4; ++u) {
    const int d0 = u * 256 + lane * 4;
    float4 nw4 = *(const float4*)&nw[d0];
    ushort4 st;
    st.x = f2bf(ogr[u][0] * rinv * nw4.x);
    st.y = f2bf(ogr[u][1] * rinv * nw4.y);
    st.z = f2bf(ogr[u][2] * rinv * nw4.z);
    st.w = f2bf(ogr[u][3] * rinv * nw4.w);
    *(ushort4*)&og[(size_t)row * 1024 + d0] = st;
  }
}

extern "C" void kernel_launch(void* const* d_in, const int* in_sizes, int n_in,
                              void* d_out, int out_size, void* d_ws, size_t ws_size,
                              hipStream_t stream) {
  const float* x   = (const float*)d_in[0];
  const float* Wq  = (const float*)d_in[1];
  const float* Wk  = (const float*)d_in[2];
  const float* Wv  = (const float*)d_in[3];
  const float* Wo  = (const float*)d_in[4];
  const float* Wg1 = (const float*)d_in[5];
  const float* Wg2 = (const float*)d_in[6];
  const float* nw  = (const float*)d_in[7];
  float* out = (float*)d_out;
  float* ws  = (float*)d_ws;

  const size_t P = (size_t)B_ * N_ * D_;  // 8,388,608
  unsigned short* k_h = (unsigned short*)ws;              // P u16 = [0, P/2) floats
  unsigned short* o_bf = (unsigned short*)(ws + P);       // P u16
  unsigned short* qg_p = (unsigned short*)(ws + 3 * P);   // 2P u16 = [3P, 4P)
  unsigned short* U_buf = (unsigned short*)(ws + 4 * P);  // 2P u16 = [4P, 5P)
  unsigned short* v_bf = (unsigned short*)(ws + 5 * P);            // P u16
  unsigned short* q_bf = (unsigned short*)(ws + 5 * P + P / 2);    // P u16
  float* ropeT = ws + 6 * P;                                       // 262144
  float* T_buf = ws + 6 * P + 524288;                              // 131072
  float* P_buf = T_buf + 131072;                                   // 131072
  unsigned short* Wg1p = (unsigned short*)(ws + 6 * P + 786432);   // 16384 u16
  float* tg_buf = ws + 6 * P + 794624;                             // 131072
  unsigned short* x_bf = (unsigned short*)(ws + 13 * P / 2);       // P u16
  unsigned short* og_bf = x_bf;  // x_bf dead before gate_norm2 writes og
  unsigned short* Wqkv_p = (unsigned short*)(ws + 7 * P);          // 3145728 u16
  unsigned short* Wo_p = (unsigned short*)(ws + 7 * P + 1572864);  // 1048576 u16
  float* glast_g = ws + 7 * P + 2097152;                           // 131072

  const int M = B_ * N_;
  const int ggrid = (M / 128) * (D_ / 128);       // 512 (Wo)
  const int qkvgrid = (M / 128) * (3 * D_ / 128); // 1536

  cast_x_bf16<<<(int)(P / 2048), 256, 0, stream>>>(x, x_bf);
  rope_fill<<<512, 256, 0, stream>>>(ropeT);
  cast_w_all<<<2048, 256, 0, stream>>>(Wq, Wk, Wv, Wo, Wqkv_p, Wo_p);
  pack_wg1<<<8, 256, 0, stream>>>(Wg1, Wg1p);
  gate_logits<<<M / 64, 256, 0, stream>>>(x_bf, Wg1p, tg_buf);
  gemm_qkv<<<qkvgrid, 256, 0, stream>>>(x_bf, Wqkv_p, q_bf, k_h, v_bf, T_buf, M, D_);
  scan_pass_b<<<16, 256, 0, stream>>>(T_buf, P_buf);
  gla_a<<<2048, 256, 0, stream>>>(q_bf, k_h, P_buf, v_bf, ropeT, qg_p, U_buf, o_bf, glast_g);
  gla_b<<<512, 256, 0, stream>>>(U_buf, glast_g);
  gla_c<<<2048, 256, 0, stream>>>(qg_p, U_buf, o_bf);
  gate_norm2<<<M / 4, 256, 0, stream>>>(tg_buf, Wg2, nw, o_bf, og_bf);
  gemm_bf16<<<ggrid, 256, 0, stream>>>(og_bf, Wo_p, out, M, D_, D_);
}